// Round 1
// baseline (615.050 us; speedup 1.0000x reference)
//
#include <hip/hip_runtime.h>
#include <hip/hip_bf16.h>
#include <math.h>

#define D 128
#define GR 32            // rows per GEMM block
#define SCAN_T 256
#define SCAN_ELEMS 1024  // 4 per thread

// ---------------- edge pass 1: weighted in-degree + counts ----------------
__global__ void k_edge_deg(const int* __restrict__ col, const float* __restrict__ ew,
                           float* __restrict__ deg, int* __restrict__ cnt, int E) {
  int e = blockIdx.x * blockDim.x + threadIdx.x;
  if (e >= E) return;
  int c = col[e];
  atomicAdd(&deg[c], ew[e]);
  atomicAdd(&cnt[c], 1);
}

// dinv = rsqrt(deg + 1)   (in-place over deg)
__global__ void k_dinv(float* __restrict__ deg, int n) {
  int i = blockIdx.x * blockDim.x + threadIdx.x;
  if (i < n) deg[i] = rsqrtf(deg[i] + 1.0f);
}

// ---------------- block exclusive scan helper (256 threads) ----------------
__device__ __forceinline__ int block_excl_scan(int v, int t, int* wsum, int* total) {
  int lane = t & 63, wid = t >> 6;
  int x = v;
  #pragma unroll
  for (int d = 1; d < 64; d <<= 1) {
    int y = __shfl_up(x, d, 64);
    if (lane >= d) x += y;
  }
  if (lane == 63) wsum[wid] = x;
  __syncthreads();
  int woff = 0;
  for (int w = 0; w < wid; ++w) woff += wsum[w];
  if (total) { int tot = 0; for (int w = 0; w < 4; ++w) tot += wsum[w]; *total = tot; }
  return woff + x - v;   // exclusive prefix for this thread's chunk
}

__global__ __launch_bounds__(SCAN_T) void k_scan1(const int* __restrict__ cnt, int* __restrict__ offs,
                                                  int* __restrict__ bsums, int n) {
  __shared__ int wsum[4];
  int t = threadIdx.x;
  int base = blockIdx.x * SCAN_ELEMS + t * 4;
  int v[4]; int s = 0;
  #pragma unroll
  for (int u = 0; u < 4; ++u) { v[u] = (base + u < n) ? cnt[base + u] : 0; s += v[u]; }
  int tot;
  int excl = block_excl_scan(s, t, wsum, &tot);
  int run = excl;
  #pragma unroll
  for (int u = 0; u < 4; ++u) { if (base + u < n) offs[base + u] = run; run += v[u]; }
  if (t == 0) bsums[blockIdx.x] = tot;
}

__global__ __launch_bounds__(SCAN_T) void k_scan2(int* __restrict__ bsums, int nb) {
  __shared__ int wsum[4];
  int t = threadIdx.x;
  int v = (t < nb) ? bsums[t] : 0;
  int excl = block_excl_scan(v, t, wsum, nullptr);
  if (t < nb) bsums[t] = excl;
}

__global__ void k_scan3(int* __restrict__ offs, int* __restrict__ cursor,
                        const int* __restrict__ bsums, int n) {
  int i = blockIdx.x * blockDim.x + threadIdx.x;
  if (i >= n) return;
  int o = offs[i] + bsums[i >> 10];
  offs[i] = o;
  cursor[i] = o;
}

// ---------------- fill CSR-by-destination edge list ----------------
__global__ void k_fill(const int* __restrict__ row, const int* __restrict__ col,
                       const float* __restrict__ ew, const float* __restrict__ dinv,
                       int* __restrict__ cursor, float2* __restrict__ elist, int E) {
  int e = blockIdx.x * blockDim.x + threadIdx.x;
  if (e >= E) return;
  int r = row[e], c = col[e];
  float nrm = dinv[r] * ew[e] * dinv[c];
  int p = atomicAdd(&cursor[c], 1);
  elist[p] = make_float2(__int_as_float(r), nrm);
}

// ---------------- GEMM: H = X @ W^T  (f32, W staged swizzled in LDS) ----------------
// Wt float4 slot for (k, jg): k*32 + (jg ^ (k & 31))  -> holds W[jg*4+u][k], u=0..3
__global__ __launch_bounds__(256) void k_gemm(const float* __restrict__ X, const float* __restrict__ W,
                                              float* __restrict__ H, int n) {
  __shared__ float Wt[D * D];
  __shared__ float xs[GR][D];
  int t = threadIdx.x;
  // stage W transposed+swizzled (coalesced global reads; ~8-way LDS write conflict, one-time)
  #pragma unroll
  for (int m = 0; m < (D * D) / 256; ++m) {
    int flat = m * 256 + t;
    int j = flat >> 7, k = flat & 127;
    Wt[(k * 32 + ((j >> 2) ^ (k & 31))) * 4 + (j & 3)] = W[flat];
  }
  int r0base = blockIdx.x * GR;
  int rmax = n - r0base;   // rows valid in this block
  const float4* X4 = (const float4*)(X + (size_t)r0base * D);
  float4* xs4 = (float4*)&xs[0][0];
  for (int i = t; i < GR * (D / 4); i += 256) {
    int r = i >> 5;
    if (r < rmax) xs4[i] = X4[i];
  }
  __syncthreads();

  int jg = t & 31;        // output col group: j = jg*4 .. jg*4+3
  int r0 = t >> 5;        // 0..7, rows r0, r0+8, r0+16, r0+24
  float acc[4][4];
  #pragma unroll
  for (int a = 0; a < 4; ++a)
    #pragma unroll
    for (int b = 0; b < 4; ++b) acc[a][b] = 0.f;

  const float4* Wt4 = (const float4*)Wt;
  for (int k4 = 0; k4 < 32; ++k4) {
    float4 wv[4];
    #pragma unroll
    for (int kk = 0; kk < 4; ++kk) {
      int k = k4 * 4 + kk;
      wv[kk] = Wt4[k * 32 + (jg ^ (k & 31))];
    }
    float4 xv[4];
    #pragma unroll
    for (int rr = 0; rr < 4; ++rr) xv[rr] = *(const float4*)&xs[r0 + 8 * rr][k4 * 4];
    #pragma unroll
    for (int rr = 0; rr < 4; ++rr) {
      float xk[4] = {xv[rr].x, xv[rr].y, xv[rr].z, xv[rr].w};
      #pragma unroll
      for (int kk = 0; kk < 4; ++kk) {
        acc[rr][0] += xk[kk] * wv[kk].x;
        acc[rr][1] += xk[kk] * wv[kk].y;
        acc[rr][2] += xk[kk] * wv[kk].z;
        acc[rr][3] += xk[kk] * wv[kk].w;
      }
    }
  }
  #pragma unroll
  for (int rr = 0; rr < 4; ++rr) {
    int rloc = r0 + 8 * rr;
    if (rloc < rmax) {
      float4 o = make_float4(acc[rr][0], acc[rr][1], acc[rr][2], acc[rr][3]);
      *(float4*)&H[(size_t)(r0base + rloc) * D + jg * 4] = o;
    }
  }
}

// ---------------- aggregation: out[c] = sum_e norm*H[row] + dinv^2*H[c] + b (+tanh / +skip) ----------------
template<int ACT, int SKIP>
__global__ __launch_bounds__(128) void k_agg(const float* __restrict__ H, const float2* __restrict__ elist,
                                             const int* __restrict__ offs, const int* __restrict__ cnt,
                                             const float* __restrict__ dinv, const float* __restrict__ bias,
                                             const float* __restrict__ skip, float* __restrict__ out) {
  int c = blockIdx.x;
  int f = threadIdx.x;           // 0..127
  __shared__ float2 recs[64];
  int start = offs[c];
  int m = cnt[c];
  float acc = 0.f;
  for (int base = 0; base < m; base += 64) {
    int chunk = min(64, m - base);
    __syncthreads();
    if (f < chunk) recs[f] = elist[start + base + f];
    __syncthreads();
    for (int i = 0; i < chunk; ++i) {
      float2 rc = recs[i];
      int r = __float_as_int(rc.x);
      acc += rc.y * H[(size_t)r * D + f];
    }
  }
  float dv = dinv[c];
  acc += dv * dv * H[(size_t)c * D + f] + bias[f];
  if (ACT) acc = tanhf(acc);
  if (SKIP) acc += skip[(size_t)c * D + f];
  out[(size_t)c * D + f] = acc;
}

// ---------------- launch ----------------
extern "C" void kernel_launch(void* const* d_in, const int* in_sizes, int n_in,
                              void* d_out, int out_size, void* d_ws, size_t ws_size,
                              hipStream_t stream) {
  const int*   et = (const int*)d_in[0];
  const float* ef = (const float*)d_in[1];
  const float* x  = (const float*)d_in[2];
  const float* W1 = (const float*)d_in[3];
  const float* b1 = (const float*)d_in[4];
  const float* W2 = (const float*)d_in[5];
  const float* b2 = (const float*)d_in[6];
  float* out = (float*)d_out;

  int E = in_sizes[1];            // edge_feats flat count == n_edges
  int N = in_sizes[2] / D;
  const int* row = et;
  const int* col = et + E;

  // workspace carve (256B aligned chunks)
  char* p = (char*)d_ws;
  auto alloc = [&](size_t bytes) { char* q = p; p += (bytes + 255) & ~(size_t)255; return q; };
  float*  deg    = (float*) alloc((size_t)N * 4);   // becomes dinv after k_dinv
  int*    cnt    = (int*)   alloc((size_t)N * 4);
  int*    offs   = (int*)   alloc((size_t)N * 4);
  int*    cursor = (int*)   alloc((size_t)N * 4);
  int*    bsums  = (int*)   alloc(4096);
  float2* elist  = (float2*)alloc((size_t)E * 8);
  float*  h      = (float*) alloc((size_t)N * D * 4);
  float*  tbuf   = out;  // layer-1 activations live in d_out (dead before final overwrite)

  hipMemsetAsync(deg, 0, (size_t)N * 4, stream);
  hipMemsetAsync(cnt, 0, (size_t)N * 4, stream);

  int eb = (E + 255) / 256;
  int nb256 = (N + 255) / 256;
  k_edge_deg<<<eb, 256, 0, stream>>>(col, ef, deg, cnt, E);
  k_dinv<<<nb256, 256, 0, stream>>>(deg, N);

  int nb = (N + SCAN_ELEMS - 1) / SCAN_ELEMS;   // 98 for N=100000 (must be <= 256)
  k_scan1<<<nb, SCAN_T, 0, stream>>>(cnt, offs, bsums, N);
  k_scan2<<<1, SCAN_T, 0, stream>>>(bsums, nb);
  k_scan3<<<nb256, 256, 0, stream>>>(offs, cursor, bsums, N);
  k_fill<<<eb, 256, 0, stream>>>(row, col, ef, deg, cursor, elist, E);

  int gb = (N + GR - 1) / GR;
  // layer 1: h1 = x@W1^T ; a1 = tanh(agg1 + b1) -> tbuf (=d_out, scratch for now)
  k_gemm<<<gb, 256, 0, stream>>>(x, W1, h, N);
  k_agg<1, 0><<<N, 128, 0, stream>>>(h, elist, offs, cnt, deg, b1, nullptr, tbuf);
  // layer 2: h2 = a1@W2^T ; out = agg2 + b2 + x
  k_gemm<<<gb, 256, 0, stream>>>(tbuf, W2, h, N);
  k_agg<0, 1><<<N, 128, 0, stream>>>(h, elist, offs, cnt, deg, b2, x, out);
}

// Round 2
// 481.798 us; speedup vs baseline: 1.2766x; 1.2766x over previous
//
#include <hip/hip_runtime.h>
#include <hip/hip_bf16.h>
#include <math.h>

#define D 128
#define GR 32            // rows per GEMM block
#define SCAN_T 256
#define SCAN_ELEMS 1024  // 4 per thread

typedef unsigned long long ull;

__device__ __forceinline__ float bf_lo(unsigned u) { return __uint_as_float(u << 16); }
__device__ __forceinline__ float bf_hi(unsigned u) { return __uint_as_float(u & 0xffff0000u); }
__device__ __forceinline__ unsigned bpack(float a, float b) {  // RNE bf16x2
  unsigned ua = __float_as_uint(a), ub = __float_as_uint(b);
  ua += 0x7fff + ((ua >> 16) & 1);
  ub += 0x7fff + ((ub >> 16) & 1);
  return (ua >> 16) | (ub & 0xffff0000u);
}

// ---- edge pass 1: packed (fixed-point deg | count) atomic; returns rank ----
__global__ void k_pass1(const int* __restrict__ col, const float* __restrict__ ew,
                        ull* __restrict__ packed, unsigned* __restrict__ rank, int E) {
  int e = blockIdx.x * blockDim.x + threadIdx.x;
  if (e >= E) return;
  unsigned fx = __float2uint_rn(ew[e] * 16777216.0f);     // ew in [0,1): fx < 2^24
  ull old = atomicAdd(&packed[col[e]], ((ull)fx << 32) | 1ull);
  rank[e] = (unsigned)old;   // low 32 bits = # edges already placed at this node
}

// ---- unpack: cnt + dinv = rsqrt(deg+1) ----
__global__ void k_unpack(const ull* __restrict__ packed, int* __restrict__ cnt,
                         float* __restrict__ dinv, int n) {
  int i = blockIdx.x * blockDim.x + threadIdx.x;
  if (i >= n) return;
  ull p = packed[i];
  cnt[i] = (int)(p & 0xffffffffull);
  float deg = (float)(p >> 32) * (1.0f / 16777216.0f);
  dinv[i] = rsqrtf(deg + 1.0f);
}

// ---------------- block exclusive scan helper (256 threads) ----------------
__device__ __forceinline__ int block_excl_scan(int v, int t, int* wsum, int* total) {
  int lane = t & 63, wid = t >> 6;
  int x = v;
  #pragma unroll
  for (int d = 1; d < 64; d <<= 1) {
    int y = __shfl_up(x, d, 64);
    if (lane >= d) x += y;
  }
  if (lane == 63) wsum[wid] = x;
  __syncthreads();
  int woff = 0;
  for (int w = 0; w < wid; ++w) woff += wsum[w];
  if (total) { int tot = 0; for (int w = 0; w < 4; ++w) tot += wsum[w]; *total = tot; }
  return woff + x - v;
}

__global__ __launch_bounds__(SCAN_T) void k_scan1(const int* __restrict__ cnt, int* __restrict__ offs,
                                                  int* __restrict__ bsums, int n) {
  __shared__ int wsum[4];
  int t = threadIdx.x;
  int base = blockIdx.x * SCAN_ELEMS + t * 4;
  int v[4]; int s = 0;
  #pragma unroll
  for (int u = 0; u < 4; ++u) { v[u] = (base + u < n) ? cnt[base + u] : 0; s += v[u]; }
  int tot;
  int excl = block_excl_scan(s, t, wsum, &tot);
  int run = excl;
  #pragma unroll
  for (int u = 0; u < 4; ++u) { if (base + u < n) offs[base + u] = run; run += v[u]; }
  if (t == 0) bsums[blockIdx.x] = tot;
}

__global__ __launch_bounds__(SCAN_T) void k_scan2(int* __restrict__ bsums, int nb) {
  __shared__ int wsum[4];
  int t = threadIdx.x;
  int v = (t < nb) ? bsums[t] : 0;
  int excl = block_excl_scan(v, t, wsum, nullptr);
  if (t < nb) bsums[t] = excl;
}

__global__ void k_scan3(int* __restrict__ offs, const int* __restrict__ bsums, int n) {
  int i = blockIdx.x * blockDim.x + threadIdx.x;
  if (i >= n) return;
  offs[i] += bsums[i >> 10];
}

// ---- fill CSR-by-destination edge list: NO atomics (rank from pass1) ----
__global__ void k_fill2(const int* __restrict__ row, const int* __restrict__ col,
                        const float* __restrict__ ew, const unsigned* __restrict__ rank,
                        const int* __restrict__ offs, const float* __restrict__ dinv,
                        float2* __restrict__ elist, int E) {
  int e = blockIdx.x * blockDim.x + threadIdx.x;
  if (e >= E) return;
  int r = row[e], c = col[e];
  float nrm = dinv[r] * ew[e] * dinv[c];
  elist[offs[c] + rank[e]] = make_float2(__int_as_float(r), nrm);
}

// ---------------- GEMM: H = X @ W^T  (f32 math, bf16 output; X f32 or bf16) ----------------
// Wt float4 slot for (k, jg): k*32 + (jg ^ (k & 31))  -> holds W[jg*4+u][k], u=0..3
template<int XBF>
__global__ __launch_bounds__(256) void k_gemm(const void* __restrict__ Xv, const float* __restrict__ W,
                                              unsigned* __restrict__ H2, int n) {
  __shared__ float Wt[D * D];
  __shared__ float xs[GR][D];
  int t = threadIdx.x;
  #pragma unroll
  for (int m = 0; m < (D * D) / 256; ++m) {
    int flat = m * 256 + t;
    int j = flat >> 7, k = flat & 127;
    Wt[(k * 32 + ((j >> 2) ^ (k & 31))) * 4 + (j & 3)] = W[flat];
  }
  int r0base = blockIdx.x * GR;
  int rmax = n - r0base;
  float4* xs4 = (float4*)&xs[0][0];
  if (XBF) {
    const uint4* X4 = (const uint4*)((const unsigned short*)Xv + (size_t)r0base * D);
    for (int i = t; i < GR * (D / 8); i += 256) {   // 512 uint4 loads, 8 bf16 each
      int r = i >> 4;
      if (r < rmax) {
        uint4 u = X4[i];
        xs4[i * 2 + 0] = make_float4(bf_lo(u.x), bf_hi(u.x), bf_lo(u.y), bf_hi(u.y));
        xs4[i * 2 + 1] = make_float4(bf_lo(u.z), bf_hi(u.z), bf_lo(u.w), bf_hi(u.w));
      }
    }
  } else {
    const float4* X4 = (const float4*)((const float*)Xv + (size_t)r0base * D);
    for (int i = t; i < GR * (D / 4); i += 256) {
      int r = i >> 5;
      if (r < rmax) xs4[i] = X4[i];
    }
  }
  __syncthreads();

  int jg = t & 31;
  int r0 = t >> 5;
  float acc[4][4];
  #pragma unroll
  for (int a = 0; a < 4; ++a)
    #pragma unroll
    for (int b = 0; b < 4; ++b) acc[a][b] = 0.f;

  const float4* Wt4 = (const float4*)Wt;
  for (int k4 = 0; k4 < 32; ++k4) {
    float4 wv[4];
    #pragma unroll
    for (int kk = 0; kk < 4; ++kk) {
      int k = k4 * 4 + kk;
      wv[kk] = Wt4[k * 32 + (jg ^ (k & 31))];
    }
    float4 xv[4];
    #pragma unroll
    for (int rr = 0; rr < 4; ++rr) xv[rr] = *(const float4*)&xs[r0 + 8 * rr][k4 * 4];
    #pragma unroll
    for (int rr = 0; rr < 4; ++rr) {
      float xk[4] = {xv[rr].x, xv[rr].y, xv[rr].z, xv[rr].w};
      #pragma unroll
      for (int kk = 0; kk < 4; ++kk) {
        acc[rr][0] += xk[kk] * wv[kk].x;
        acc[rr][1] += xk[kk] * wv[kk].y;
        acc[rr][2] += xk[kk] * wv[kk].z;
        acc[rr][3] += xk[kk] * wv[kk].w;
      }
    }
  }
  #pragma unroll
  for (int rr = 0; rr < 4; ++rr) {
    int rloc = r0 + 8 * rr;
    if (rloc < rmax) {
      uint2 o = make_uint2(bpack(acc[rr][0], acc[rr][1]), bpack(acc[rr][2], acc[rr][3]));
      *(uint2*)&H2[(size_t)(r0base + rloc) * 64 + jg * 2] = o;
    }
  }
}

// ---- aggregation: wave per node, shfl edge broadcast, bf16 H gather ----
// out[c] = sum_e norm*H[row] + dinv^2*H[c] + b   (+tanh / +skip)
template<int ACT, int SKIP, int OUTBF>
__global__ __launch_bounds__(256) void k_agg(const unsigned* __restrict__ H2,
                                             const float2* __restrict__ elist,
                                             const int* __restrict__ offs, const int* __restrict__ cnt,
                                             const float* __restrict__ dinv, const float* __restrict__ bias,
                                             const float* __restrict__ skip, void* __restrict__ outv, int N) {
  int lane = threadIdx.x & 63;
  int c = blockIdx.x * 4 + (threadIdx.x >> 6);
  if (c >= N) return;
  int start = offs[c], m = cnt[c];
  float a0 = 0.f, a1 = 0.f;
  for (int base = 0; base < m; base += 64) {
    int chunk = min(64, m - base);
    float2 rec = make_float2(0.f, 0.f);
    if (lane < chunk) rec = elist[start + base + lane];
    int rI = __float_as_int(rec.x);
    for (int i = 0; i < chunk; ++i) {
      int r = __shfl(rI, i, 64);
      float w = __shfl(rec.y, i, 64);
      unsigned u = H2[(size_t)r * 64 + lane];
      a0 += w * bf_lo(u);
      a1 += w * bf_hi(u);
    }
  }
  float dv = dinv[c];
  unsigned us = H2[(size_t)c * 64 + lane];
  float sw = dv * dv;
  a0 += sw * bf_lo(us) + bias[lane * 2];
  a1 += sw * bf_hi(us) + bias[lane * 2 + 1];
  if (ACT) { a0 = tanhf(a0); a1 = tanhf(a1); }
  if (SKIP) {
    const float2 s2 = *(const float2*)&skip[(size_t)c * D + lane * 2];
    a0 += s2.x; a1 += s2.y;
  }
  if (OUTBF) {
    ((unsigned*)outv)[(size_t)c * 64 + lane] = bpack(a0, a1);
  } else {
    ((float2*)outv)[(size_t)c * 64 + lane] = make_float2(a0, a1);
  }
}

// ---------------- launch ----------------
extern "C" void kernel_launch(void* const* d_in, const int* in_sizes, int n_in,
                              void* d_out, int out_size, void* d_ws, size_t ws_size,
                              hipStream_t stream) {
  const int*   et = (const int*)d_in[0];
  const float* ef = (const float*)d_in[1];
  const float* x  = (const float*)d_in[2];
  const float* W1 = (const float*)d_in[3];
  const float* b1 = (const float*)d_in[4];
  const float* W2 = (const float*)d_in[5];
  const float* b2 = (const float*)d_in[6];
  float* out = (float*)d_out;

  int E = in_sizes[1];
  int N = in_sizes[2] / D;
  const int* row = et;
  const int* col = et + E;

  char* p = (char*)d_ws;
  auto alloc = [&](size_t bytes) { char* q = p; p += (bytes + 255) & ~(size_t)255; return q; };
  ull*      packed = (ull*)     alloc((size_t)N * 8);
  int*      cnt    = (int*)     alloc((size_t)N * 4);
  int*      offs   = (int*)     alloc((size_t)N * 4);
  float*    dinv   = (float*)   alloc((size_t)N * 4);
  int*      bsums  = (int*)     alloc(4096);
  unsigned* rank   = (unsigned*)alloc((size_t)E * 4);
  float2*   elist  = (float2*)  alloc((size_t)E * 8);
  unsigned* hb     = (unsigned*)alloc((size_t)N * 64 * 4);   // bf16x2 activations [N,64]
  unsigned* abuf   = (unsigned*)d_out;  // layer-1 tanh output (bf16) lives in d_out (dead before final write)

  hipMemsetAsync(packed, 0, (size_t)N * 8, stream);

  int eb = (E + 255) / 256;
  int nb256 = (N + 255) / 256;
  k_pass1<<<eb, 256, 0, stream>>>(col, ef, packed, rank, E);
  k_unpack<<<nb256, 256, 0, stream>>>(packed, cnt, dinv, N);

  int nb = (N + SCAN_ELEMS - 1) / SCAN_ELEMS;   // 98 for N=100000 (<= 256)
  k_scan1<<<nb, SCAN_T, 0, stream>>>(cnt, offs, bsums, N);
  k_scan2<<<1, SCAN_T, 0, stream>>>(bsums, nb);
  k_scan3<<<nb256, 256, 0, stream>>>(offs, bsums, N);
  k_fill2<<<eb, 256, 0, stream>>>(row, col, ef, rank, offs, dinv, elist, E);

  int gb = (N + GR - 1) / GR;
  int ab = (N + 3) / 4;
  // layer 1: h1 = x@W1^T (bf16) ; a1 = tanh(agg + b1) -> abuf (bf16, in d_out)
  k_gemm<0><<<gb, 256, 0, stream>>>(x, W1, hb, N);
  k_agg<1, 0, 1><<<ab, 256, 0, stream>>>(hb, elist, offs, cnt, dinv, b1, nullptr, abuf, N);
  // layer 2: h2 = a1@W2^T (bf16) ; out = agg + b2 + x (f32)
  k_gemm<1><<<gb, 256, 0, stream>>>(abuf, W2, hb, N);
  k_agg<0, 1, 0><<<ab, 256, 0, stream>>>(hb, elist, offs, cnt, dinv, b2, x, out, N);
}

// Round 3
// 425.975 us; speedup vs baseline: 1.4439x; 1.1310x over previous
//
#include <hip/hip_runtime.h>
#include <hip/hip_bf16.h>
#include <math.h>

#define D 128
#define GR 32            // rows per GEMM block
#define SCAN_T 256
#define SCAN_ELEMS 1024  // 4 per thread

typedef unsigned long long ull;

__device__ __forceinline__ float bf_lo(unsigned u) { return __uint_as_float(u << 16); }
__device__ __forceinline__ float bf_hi(unsigned u) { return __uint_as_float(u & 0xffff0000u); }
__device__ __forceinline__ unsigned bpack(float a, float b) {  // RNE bf16x2
  unsigned ua = __float_as_uint(a), ub = __float_as_uint(b);
  ua += 0x7fff + ((ua >> 16) & 1);
  ub += 0x7fff + ((ub >> 16) & 1);
  return (ua >> 16) | (ub & 0xffff0000u);
}

// ---- edge pass 1: packed (fixed-point deg | count) atomic; returns rank ----
__global__ void k_pass1(const int* __restrict__ col, const float* __restrict__ ew,
                        ull* __restrict__ packed, unsigned* __restrict__ rank, int E) {
  int e = blockIdx.x * blockDim.x + threadIdx.x;
  if (e >= E) return;
  unsigned fx = __float2uint_rn(ew[e] * 16777216.0f);     // ew in [0,1): fx < 2^24
  ull old = atomicAdd(&packed[col[e]], ((ull)fx << 32) | 1ull);
  rank[e] = (unsigned)old;   // low 32 = # edges already placed at this node
}

// ---- cast x f32 -> bf16x2 ----
__global__ void k_cast(const float2* __restrict__ x2, unsigned* __restrict__ xb, int n64) {
  int i = blockIdx.x * blockDim.x + threadIdx.x;
  if (i >= n64) return;
  float2 v = x2[i];
  xb[i] = bpack(v.x, v.y);
}

// ---------------- block exclusive scan helper (256 threads) ----------------
__device__ __forceinline__ int block_excl_scan(int v, int t, int* wsum, int* total) {
  int lane = t & 63, wid = t >> 6;
  int x = v;
  #pragma unroll
  for (int d = 1; d < 64; d <<= 1) {
    int y = __shfl_up(x, d, 64);
    if (lane >= d) x += y;
  }
  if (lane == 63) wsum[wid] = x;
  __syncthreads();
  int woff = 0;
  for (int w = 0; w < wid; ++w) woff += wsum[w];
  if (total) { int tot = 0; for (int w = 0; w < 4; ++w) tot += wsum[w]; *total = tot; }
  return woff + x - v;
}

// scan of counts (from packed lo32) + dinv = rsqrt(deg+1) (from packed hi32)
__global__ __launch_bounds__(SCAN_T) void k_scan1(const ull* __restrict__ packed, int* __restrict__ offs,
                                                  int* __restrict__ bsums, float* __restrict__ dinv, int n) {
  __shared__ int wsum[4];
  int t = threadIdx.x;
  int base = blockIdx.x * SCAN_ELEMS + t * 4;
  int v[4]; int s = 0;
  #pragma unroll
  for (int u = 0; u < 4; ++u) {
    int ok = (base + u < n);
    ull p = ok ? packed[base + u] : 0ull;
    v[u] = (int)(p & 0xffffffffull);
    if (ok) dinv[base + u] = rsqrtf((float)(p >> 32) * (1.0f / 16777216.0f) + 1.0f);
    s += v[u];
  }
  int tot;
  int excl = block_excl_scan(s, t, wsum, &tot);
  int run = excl;
  #pragma unroll
  for (int u = 0; u < 4; ++u) { if (base + u < n) offs[base + u] = run; run += v[u]; }
  if (t == 0) bsums[blockIdx.x] = tot;
}

__global__ __launch_bounds__(SCAN_T) void k_scan2(int* __restrict__ bsums, int nb) {
  __shared__ int wsum[4];
  int t = threadIdx.x;
  int v = (t < nb) ? bsums[t] : 0;
  int excl = block_excl_scan(v, t, wsum, nullptr);
  if (t < nb) bsums[t] = excl;
}

// ---- fill CSR-by-destination edge list: NO atomics (rank from pass1) ----
__global__ void k_fill3(const int* __restrict__ row, const int* __restrict__ col,
                        const float* __restrict__ ew, const unsigned* __restrict__ rank,
                        const int* __restrict__ offs, const int* __restrict__ bsums,
                        const float* __restrict__ dinv, float2* __restrict__ elist, int E) {
  int e = blockIdx.x * blockDim.x + threadIdx.x;
  if (e >= E) return;
  int r = row[e], c = col[e];
  float nrm = dinv[r] * ew[e] * dinv[c];
  elist[offs[c] + bsums[c >> 10] + rank[e]] = make_float2(__int_as_float(r), nrm);
}

// ---- gather-aggregate: s[c] = sum_e norm*src[row] + dinv^2*src[c]  (bf16 in/out) ----
// wave per node; 2 edges in flight per wave (32 lanes x uint2 each = 256B row)
__global__ __launch_bounds__(256) void k_agg(const unsigned* __restrict__ H2,
                                             const float2* __restrict__ elist,
                                             const int* __restrict__ offs, const int* __restrict__ bsums,
                                             const ull* __restrict__ packed, const float* __restrict__ dinv,
                                             unsigned* __restrict__ outb, int N) {
  int lane = threadIdx.x & 63;
  int c = blockIdx.x * 4 + (threadIdx.x >> 6);
  if (c >= N) return;
  int start = offs[c] + bsums[c >> 10];
  int m = (int)(packed[c] & 0xffffffffull);
  int half = lane >> 5;
  int fi = (lane & 31) * 2;           // uint index within row (features fi*2..fi*2+3)
  float a0 = 0.f, a1 = 0.f, a2 = 0.f, a3 = 0.f;
  for (int base = 0; base < m; base += 64) {
    int chunk = min(64, m - base);
    float2 rec = make_float2(0.f, 0.f);   // pad: row 0, weight 0
    if (lane < chunk) rec = elist[start + base + lane];
    int rI = __float_as_int(rec.x);
    int iters = (chunk + 1) >> 1;
    for (int i = 0; i < iters; ++i) {
      int src = 2 * i + half;
      int r = __shfl(rI, src, 64);
      float w = __shfl(rec.y, src, 64);
      uint2 u = *(const uint2*)&H2[(size_t)r * 64 + fi];
      a0 += w * bf_lo(u.x); a1 += w * bf_hi(u.x);
      a2 += w * bf_lo(u.y); a3 += w * bf_hi(u.y);
    }
  }
  a0 += __shfl_xor(a0, 32, 64); a1 += __shfl_xor(a1, 32, 64);
  a2 += __shfl_xor(a2, 32, 64); a3 += __shfl_xor(a3, 32, 64);
  float dv = dinv[c], sw = dv * dv;
  uint2 us = *(const uint2*)&H2[(size_t)c * 64 + fi];
  a0 += sw * bf_lo(us.x); a1 += sw * bf_hi(us.x);
  a2 += sw * bf_lo(us.y); a3 += sw * bf_hi(us.y);
  if (half == 0) {
    *(uint2*)&outb[(size_t)c * 64 + fi] = make_uint2(bpack(a0, a1), bpack(a2, a3));
  }
}

// ---- GEMM + epilogue: out = S @ W^T + bias  [+tanh -> bf16]  [+skip -> f32] ----
// Wt float4 slot for (k, jg): k*32 + (jg ^ (k & 31)) holds W[jg*4+u][k]
template<int TANH, int SKIP>
__global__ __launch_bounds__(256) void k_gemm(const unsigned* __restrict__ Xb, const float* __restrict__ W,
                                              const float* __restrict__ bias, const float* __restrict__ skip,
                                              void* __restrict__ outv, int n) {
  __shared__ float Wt[D * D];
  __shared__ float xs[GR][D];
  int t = threadIdx.x;
  #pragma unroll
  for (int m = 0; m < (D * D) / 256; ++m) {
    int flat = m * 256 + t;
    int j = flat >> 7, k = flat & 127;
    Wt[(k * 32 + ((j >> 2) ^ (k & 31))) * 4 + (j & 3)] = W[flat];
  }
  int r0base = blockIdx.x * GR;
  int rmax = n - r0base;
  float4* xs4 = (float4*)&xs[0][0];
  const uint4* X4 = (const uint4*)(Xb + (size_t)r0base * 64);
  for (int i = t; i < GR * (D / 8); i += 256) {
    int r = i >> 4;
    if (r < rmax) {
      uint4 u = X4[i];
      xs4[i * 2 + 0] = make_float4(bf_lo(u.x), bf_hi(u.x), bf_lo(u.y), bf_hi(u.y));
      xs4[i * 2 + 1] = make_float4(bf_lo(u.z), bf_hi(u.z), bf_lo(u.w), bf_hi(u.w));
    }
  }
  __syncthreads();

  int jg = t & 31;
  int r0 = t >> 5;
  float acc[4][4];
  #pragma unroll
  for (int a = 0; a < 4; ++a)
    #pragma unroll
    for (int b = 0; b < 4; ++b) acc[a][b] = 0.f;

  const float4* Wt4 = (const float4*)Wt;
  for (int k4 = 0; k4 < 32; ++k4) {
    float4 wv[4];
    #pragma unroll
    for (int kk = 0; kk < 4; ++kk) {
      int k = k4 * 4 + kk;
      wv[kk] = Wt4[k * 32 + (jg ^ (k & 31))];
    }
    float4 xv[4];
    #pragma unroll
    for (int rr = 0; rr < 4; ++rr) xv[rr] = *(const float4*)&xs[r0 + 8 * rr][k4 * 4];
    #pragma unroll
    for (int rr = 0; rr < 4; ++rr) {
      float xk[4] = {xv[rr].x, xv[rr].y, xv[rr].z, xv[rr].w};
      #pragma unroll
      for (int kk = 0; kk < 4; ++kk) {
        acc[rr][0] += xk[kk] * wv[kk].x;
        acc[rr][1] += xk[kk] * wv[kk].y;
        acc[rr][2] += xk[kk] * wv[kk].z;
        acc[rr][3] += xk[kk] * wv[kk].w;
      }
    }
  }
  float b0 = bias[jg * 4], b1 = bias[jg * 4 + 1], b2 = bias[jg * 4 + 2], b3 = bias[jg * 4 + 3];
  #pragma unroll
  for (int rr = 0; rr < 4; ++rr) {
    int rloc = r0 + 8 * rr;
    if (rloc < rmax) {
      int r = r0base + rloc;
      float o0 = acc[rr][0] + b0, o1 = acc[rr][1] + b1;
      float o2 = acc[rr][2] + b2, o3 = acc[rr][3] + b3;
      if (TANH) {
        o0 = tanhf(o0); o1 = tanhf(o1); o2 = tanhf(o2); o3 = tanhf(o3);
        *(uint2*)&((unsigned*)outv)[(size_t)r * 64 + jg * 2] = make_uint2(bpack(o0, o1), bpack(o2, o3));
      } else {
        if (SKIP) {
          float4 s = *(const float4*)&skip[(size_t)r * D + jg * 4];
          o0 += s.x; o1 += s.y; o2 += s.z; o3 += s.w;
        }
        *(float4*)&((float*)outv)[(size_t)r * D + jg * 4] = make_float4(o0, o1, o2, o3);
      }
    }
  }
}

// ---------------- launch ----------------
extern "C" void kernel_launch(void* const* d_in, const int* in_sizes, int n_in,
                              void* d_out, int out_size, void* d_ws, size_t ws_size,
                              hipStream_t stream) {
  const int*   et = (const int*)d_in[0];
  const float* ef = (const float*)d_in[1];
  const float* x  = (const float*)d_in[2];
  const float* W1 = (const float*)d_in[3];
  const float* b1 = (const float*)d_in[4];
  const float* W2 = (const float*)d_in[5];
  const float* b2 = (const float*)d_in[6];

  int E = in_sizes[1];
  int N = in_sizes[2] / D;
  const int* row = et;
  const int* col = et + E;

  char* p = (char*)d_ws;
  auto alloc = [&](size_t bytes) { char* q = p; p += (bytes + 255) & ~(size_t)255; return q; };
  ull*      packed = (ull*)     alloc((size_t)N * 8);
  int*      offs   = (int*)     alloc((size_t)N * 4);
  float*    dinv   = (float*)   alloc((size_t)N * 4);
  int*      bsums  = (int*)     alloc(4096);
  unsigned* rank   = (unsigned*)alloc((size_t)E * 4);
  float2*   elist  = (float2*)  alloc((size_t)E * 8);
  unsigned* xb     = (unsigned*)alloc((size_t)N * 64 * 4);  // bf16x2 [N,64]; later reused for s2
  unsigned* doutb  = (unsigned*)d_out;  // s1 / a1 (bf16) live in d_out, dead before final write

  hipMemsetAsync(packed, 0, (size_t)N * 8, stream);

  int eb = (E + 255) / 256;
  k_pass1<<<eb, 256, 0, stream>>>(col, ef, packed, rank, E);
  k_cast<<<(N * 64 + 255) / 256, 256, 0, stream>>>((const float2*)x, xb, N * 64);

  int nb = (N + SCAN_ELEMS - 1) / SCAN_ELEMS;   // 98 for N=100000 (<= 256)
  k_scan1<<<nb, SCAN_T, 0, stream>>>(packed, offs, bsums, dinv, N);
  k_scan2<<<1, SCAN_T, 0, stream>>>(bsums, nb);
  k_fill3<<<eb, 256, 0, stream>>>(row, col, ef, rank, offs, bsums, dinv, elist, E);

  int ab = (N + 3) / 4;
  int gb = (N + GR - 1) / GR;
  // layer 1: s1 = A~ @ xb  -> d_out(bf16) ; a1 = tanh(s1@W1^T + b1) in-place
  k_agg<<<ab, 256, 0, stream>>>(xb, elist, offs, bsums, packed, dinv, doutb, N);
  k_gemm<1, 0><<<gb, 256, 0, stream>>>(doutb, W1, b1, nullptr, doutb, N);
  // layer 2: s2 = A~ @ a1 -> xb(reused) ; out = s2@W2^T + b2 + x -> d_out f32
  k_agg<<<ab, 256, 0, stream>>>(doutb, elist, offs, bsums, packed, dinv, xb, N);
  k_gemm<0, 1><<<gb, 256, 0, stream>>>(xb, W2, b2, x, d_out, N);
}

// Round 4
// 407.244 us; speedup vs baseline: 1.5103x; 1.0460x over previous
//
#include <hip/hip_runtime.h>
#include <hip/hip_bf16.h>
#include <math.h>

#define D 128
#define SCAN_T 256
#define SCAN_ELEMS 1024  // 4 per thread

typedef unsigned long long ull;
typedef __attribute__((ext_vector_type(8))) short bf16x8;
typedef __attribute__((ext_vector_type(4))) float f32x4;

__device__ __forceinline__ float bf_lo(unsigned u) { return __uint_as_float(u << 16); }
__device__ __forceinline__ float bf_hi(unsigned u) { return __uint_as_float(u & 0xffff0000u); }
__device__ __forceinline__ unsigned bpack(float a, float b) {  // RNE bf16x2
  unsigned ua = __float_as_uint(a), ub = __float_as_uint(b);
  ua += 0x7fff + ((ua >> 16) & 1);
  ub += 0x7fff + ((ub >> 16) & 1);
  return (ua >> 16) | (ub & 0xffff0000u);
}
__device__ __forceinline__ unsigned short bh16(float a) {  // RNE bf16
  unsigned ua = __float_as_uint(a);
  ua += 0x7fff + ((ua >> 16) & 1);
  return (unsigned short)(ua >> 16);
}

// ---- edge pass 1: packed (fixed-point deg | count) atomic; returns rank ----
__global__ void k_pass1(const int* __restrict__ col, const float* __restrict__ ew,
                        ull* __restrict__ packed, unsigned* __restrict__ rank, int E) {
  int e = blockIdx.x * blockDim.x + threadIdx.x;
  if (e >= E) return;
  unsigned fx = __float2uint_rn(ew[e] * 16777216.0f);     // ew in [0,1): fx < 2^24
  ull old = atomicAdd(&packed[col[e]], ((ull)fx << 32) | 1ull);
  rank[e] = (unsigned)old;   // low 32 = # edges already placed at this node
}

// ---- cast x f32 -> bf16x2 ----
__global__ void k_cast(const float2* __restrict__ x2, unsigned* __restrict__ xb, int n64) {
  int i = blockIdx.x * blockDim.x + threadIdx.x;
  if (i >= n64) return;
  float2 v = x2[i];
  xb[i] = bpack(v.x, v.y);
}

// ---- split W1,W2 (f32 [128][128]) into bf16 hi + lo, row-major ----
__global__ void k_wcast(const float* __restrict__ W1, const float* __restrict__ W2,
                        unsigned short* __restrict__ Whi1, unsigned short* __restrict__ Wlo1,
                        unsigned short* __restrict__ Whi2, unsigned short* __restrict__ Wlo2) {
  int i = blockIdx.x * blockDim.x + threadIdx.x;
  int n = D * D;
  const float* W = (i < n) ? W1 : W2;
  unsigned short* Hh = (i < n) ? Whi1 : Whi2;
  unsigned short* Hl = (i < n) ? Wlo1 : Wlo2;
  int j = (i < n) ? i : i - n;
  if (i >= 2 * n) return;
  float w = W[j];
  unsigned short h = bh16(w);
  float fh = __uint_as_float((unsigned)h << 16);
  Hh[j] = h;
  Hl[j] = bh16(w - fh);
}

// ---------------- block exclusive scan helper (256 threads) ----------------
__device__ __forceinline__ int block_excl_scan(int v, int t, int* wsum, int* total) {
  int lane = t & 63, wid = t >> 6;
  int x = v;
  #pragma unroll
  for (int d = 1; d < 64; d <<= 1) {
    int y = __shfl_up(x, d, 64);
    if (lane >= d) x += y;
  }
  if (lane == 63) wsum[wid] = x;
  __syncthreads();
  int woff = 0;
  for (int w = 0; w < wid; ++w) woff += wsum[w];
  if (total) { int tot = 0; for (int w = 0; w < 4; ++w) tot += wsum[w]; *total = tot; }
  return woff + x - v;
}

// scan of counts (packed lo32) + dinv = rsqrt(deg+1) (packed hi32)
__global__ __launch_bounds__(SCAN_T) void k_scan1(const ull* __restrict__ packed, int* __restrict__ offs,
                                                  int* __restrict__ bsums, float* __restrict__ dinv, int n) {
  __shared__ int wsum[4];
  int t = threadIdx.x;
  int base = blockIdx.x * SCAN_ELEMS + t * 4;
  int v[4]; int s = 0;
  #pragma unroll
  for (int u = 0; u < 4; ++u) {
    int ok = (base + u < n);
    ull p = ok ? packed[base + u] : 0ull;
    v[u] = (int)(p & 0xffffffffull);
    if (ok) dinv[base + u] = rsqrtf((float)(p >> 32) * (1.0f / 16777216.0f) + 1.0f);
    s += v[u];
  }
  int tot;
  int excl = block_excl_scan(s, t, wsum, &tot);
  int run = excl;
  #pragma unroll
  for (int u = 0; u < 4; ++u) { if (base + u < n) offs[base + u] = run; run += v[u]; }
  if (t == 0) bsums[blockIdx.x] = tot;
}

__global__ __launch_bounds__(SCAN_T) void k_scan2(int* __restrict__ bsums, int nb) {
  __shared__ int wsum[4];
  int t = threadIdx.x;
  int v = (t < nb) ? bsums[t] : 0;
  int excl = block_excl_scan(v, t, wsum, nullptr);
  if (t < nb) bsums[t] = excl;
}

// ---- fill CSR-by-destination edge list: NO atomics (rank from pass1) ----
__global__ void k_fill3(const int* __restrict__ row, const int* __restrict__ col,
                        const float* __restrict__ ew, const unsigned* __restrict__ rank,
                        const int* __restrict__ offs, const int* __restrict__ bsums,
                        const float* __restrict__ dinv, float2* __restrict__ elist, int E) {
  int e = blockIdx.x * blockDim.x + threadIdx.x;
  if (e >= E) return;
  int r = row[e], c = col[e];
  float nrm = dinv[r] * ew[e] * dinv[c];
  elist[offs[c] + bsums[c >> 10] + rank[e]] = make_float2(__int_as_float(r), nrm);
}

// ---- gather-aggregate: s[c] = sum_e norm*src[row] + dinv^2*src[c]  (bf16 in/out) ----
// wave per node; 2 edges in flight per wave (32 lanes x uint2 each = 256B row)
__global__ __launch_bounds__(256) void k_agg(const unsigned* __restrict__ H2,
                                             const float2* __restrict__ elist,
                                             const int* __restrict__ offs, const int* __restrict__ bsums,
                                             const ull* __restrict__ packed, const float* __restrict__ dinv,
                                             unsigned* __restrict__ outb, int N) {
  int lane = threadIdx.x & 63;
  int c = blockIdx.x * 4 + (threadIdx.x >> 6);
  if (c >= N) return;
  int start = offs[c] + bsums[c >> 10];
  int m = (int)(packed[c] & 0xffffffffull);
  int half = lane >> 5;
  int fi = (lane & 31) * 2;           // uint index within row
  float a0 = 0.f, a1 = 0.f, a2 = 0.f, a3 = 0.f;
  for (int base = 0; base < m; base += 64) {
    int chunk = min(64, m - base);
    float2 rec = make_float2(0.f, 0.f);   // pad: row 0, weight 0
    if (lane < chunk) rec = elist[start + base + lane];
    int rI = __float_as_int(rec.x);
    int iters = (chunk + 1) >> 1;
    for (int i = 0; i < iters; ++i) {
      int src = 2 * i + half;
      int r = __shfl(rI, src, 64);
      float w = __shfl(rec.y, src, 64);
      uint2 u = *(const uint2*)&H2[(size_t)r * 64 + fi];
      a0 += w * bf_lo(u.x); a1 += w * bf_hi(u.x);
      a2 += w * bf_lo(u.y); a3 += w * bf_hi(u.y);
    }
  }
  a0 += __shfl_xor(a0, 32, 64); a1 += __shfl_xor(a1, 32, 64);
  a2 += __shfl_xor(a2, 32, 64); a3 += __shfl_xor(a3, 32, 64);
  float dv = dinv[c], sw = dv * dv;
  uint2 us = *(const uint2*)&H2[(size_t)c * 64 + fi];
  a0 += sw * bf_lo(us.x); a1 += sw * bf_hi(us.x);
  a2 += sw * bf_lo(us.y); a3 += sw * bf_hi(us.y);
  if (half == 0) {
    *(uint2*)&outb[(size_t)c * 64 + fi] = make_uint2(bpack(a0, a1), bpack(a2, a3));
  }
}

// ---- MFMA GEMM + epilogue: out = S @ (Whi+Wlo)^T + bias [+tanh->bf16] [+skip->f32] ----
// S row-major bf16 [n][128]. Wave computes 16 rows x 128 cols; no LDS.
// A frag (16x32): lane holds S[r0+(l&15)][kt*32+(l>>4)*8 + 0..7]  (16B load)
// B frag: B[k][j]=W[j][k] -> lane holds W[j0*16+(l&15)][kt*32+(l>>4)*8 + 0..7] (16B load)
// D frag: col=lane&15, row=(lane>>4)*4+i
template<int TANH, int SKIP>
__global__ __launch_bounds__(256) void k_mgemm(const unsigned short* __restrict__ S,
                                               const unsigned short* __restrict__ Whi,
                                               const unsigned short* __restrict__ Wlo,
                                               const float* __restrict__ bias,
                                               const float* __restrict__ skip,
                                               void* __restrict__ outv, int n) {
  int wave = threadIdx.x >> 6, lane = threadIdx.x & 63;
  int r0 = blockIdx.x * 64 + wave * 16;
  if (r0 >= n) return;
  int cl = lane & 15;       // A-row offset / B-col offset / D-col offset
  int kg = lane >> 4;       // k-group 0..3
  int arow = r0 + cl; if (arow >= n) arow = n - 1;
  const unsigned short* srow = S + (size_t)arow * D + kg * 8;
  bf16x8 a[4];
  #pragma unroll
  for (int kt = 0; kt < 4; ++kt) a[kt] = *(const bf16x8*)(srow + kt * 32);

  #pragma unroll
  for (int j0 = 0; j0 < 8; ++j0) {
    int col = j0 * 16 + cl;
    const unsigned short* wh = Whi + (size_t)col * D + kg * 8;
    const unsigned short* wl = Wlo + (size_t)col * D + kg * 8;
    f32x4 acc = {0.f, 0.f, 0.f, 0.f};
    #pragma unroll
    for (int kt = 0; kt < 4; ++kt)
      acc = __builtin_amdgcn_mfma_f32_16x16x32_bf16(a[kt], *(const bf16x8*)(wh + kt * 32), acc, 0, 0, 0);
    #pragma unroll
    for (int kt = 0; kt < 4; ++kt)
      acc = __builtin_amdgcn_mfma_f32_16x16x32_bf16(a[kt], *(const bf16x8*)(wl + kt * 32), acc, 0, 0, 0);
    float bv = bias[col];
    #pragma unroll
    for (int i = 0; i < 4; ++i) {
      int r = r0 + kg * 4 + i;
      if (r < n) {
        float o = acc[i] + bv;
        if (TANH) {
          o = tanhf(o);
          ((unsigned short*)outv)[(size_t)r * D + col] = bh16(o);
        } else {
          if (SKIP) o += skip[(size_t)r * D + col];
          ((float*)outv)[(size_t)r * D + col] = o;
        }
      }
    }
  }
}

// ---------------- launch ----------------
extern "C" void kernel_launch(void* const* d_in, const int* in_sizes, int n_in,
                              void* d_out, int out_size, void* d_ws, size_t ws_size,
                              hipStream_t stream) {
  const int*   et = (const int*)d_in[0];
  const float* ef = (const float*)d_in[1];
  const float* x  = (const float*)d_in[2];
  const float* W1 = (const float*)d_in[3];
  const float* b1 = (const float*)d_in[4];
  const float* W2 = (const float*)d_in[5];
  const float* b2 = (const float*)d_in[6];

  int E = in_sizes[1];
  int N = in_sizes[2] / D;
  const int* row = et;
  const int* col = et + E;

  char* p = (char*)d_ws;
  auto alloc = [&](size_t bytes) { char* q = p; p += (bytes + 255) & ~(size_t)255; return q; };
  ull*      packed = (ull*)     alloc((size_t)N * 8);
  int*      offs   = (int*)     alloc((size_t)N * 4);
  float*    dinv   = (float*)   alloc((size_t)N * 4);
  int*      bsums  = (int*)     alloc(4096);
  unsigned* rank   = (unsigned*)alloc((size_t)E * 4);
  float2*   elist  = (float2*)  alloc((size_t)E * 8);
  unsigned* xb     = (unsigned*)alloc((size_t)N * 64 * 4);  // bf16x2 [N,64]; reused for s2
  unsigned short* whi1 = (unsigned short*)alloc(D * D * 2);
  unsigned short* wlo1 = (unsigned short*)alloc(D * D * 2);
  unsigned short* whi2 = (unsigned short*)alloc(D * D * 2);
  unsigned short* wlo2 = (unsigned short*)alloc(D * D * 2);
  unsigned* doutb = (unsigned*)d_out;  // s1 / a1 (bf16) live in d_out, dead before final write

  hipMemsetAsync(packed, 0, (size_t)N * 8, stream);

  int eb = (E + 255) / 256;
  k_pass1<<<eb, 256, 0, stream>>>(col, ef, packed, rank, E);
  k_cast<<<(N * 64 + 255) / 256, 256, 0, stream>>>((const float2*)x, xb, N * 64);
  k_wcast<<<(2 * D * D + 255) / 256, 256, 0, stream>>>(W1, W2, whi1, wlo1, whi2, wlo2);

  int nb = (N + SCAN_ELEMS - 1) / SCAN_ELEMS;   // 98 for N=100000 (<= 256)
  k_scan1<<<nb, SCAN_T, 0, stream>>>(packed, offs, bsums, dinv, N);
  k_scan2<<<1, SCAN_T, 0, stream>>>(bsums, nb);
  k_fill3<<<eb, 256, 0, stream>>>(row, col, ef, rank, offs, bsums, dinv, elist, E);

  int ab = (N + 3) / 4;
  int gb = (N + 63) / 64;
  // layer 1: s1 = A~ @ xb -> d_out(bf16) ; a1 = tanh(s1@W1^T + b1) in-place (waves own their rows)
  k_agg<<<ab, 256, 0, stream>>>(xb, elist, offs, bsums, packed, dinv, doutb, N);
  k_mgemm<1, 0><<<gb, 256, 0, stream>>>((const unsigned short*)doutb, whi1, wlo1, b1, nullptr, doutb, N);
  // layer 2: s2 = A~ @ a1 -> xb(reused) ; out = s2@W2^T + b2 + x -> d_out f32
  k_agg<<<ab, 256, 0, stream>>>(doutb, elist, offs, bsums, packed, dinv, xb, N);
  k_mgemm<0, 1><<<gb, 256, 0, stream>>>((const unsigned short*)xb, whi2, wlo2, b2, x, d_out, N);
}

// Round 5
// 372.231 us; speedup vs baseline: 1.6523x; 1.0941x over previous
//
#include <hip/hip_runtime.h>
#include <hip/hip_bf16.h>
#include <math.h>

#define D 128
#define SCAN_T 256
#define SCAN_ELEMS 1024  // 4 per thread
#define PSTRIDE 8        // ull stride per node for packed[] (64B sector padding)

typedef unsigned long long ull;
typedef __attribute__((ext_vector_type(8))) short bf16x8;
typedef __attribute__((ext_vector_type(4))) float f32x4;

__device__ __forceinline__ float bf_lo(unsigned u) { return __uint_as_float(u << 16); }
__device__ __forceinline__ float bf_hi(unsigned u) { return __uint_as_float(u & 0xffff0000u); }
__device__ __forceinline__ unsigned bpack(float a, float b) {  // RNE bf16x2
  unsigned ua = __float_as_uint(a), ub = __float_as_uint(b);
  ua += 0x7fff + ((ua >> 16) & 1);
  ub += 0x7fff + ((ub >> 16) & 1);
  return (ua >> 16) | (ub & 0xffff0000u);
}
__device__ __forceinline__ unsigned short bh16(float a) {  // RNE bf16
  unsigned ua = __float_as_uint(a);
  ua += 0x7fff + ((ua >> 16) & 1);
  return (unsigned short)(ua >> 16);
}

// ---- edge pass 1: packed (fixed-point deg | count) atomic; returns rank ----
__global__ void k_pass1(const int* __restrict__ col, const float* __restrict__ ew,
                        ull* __restrict__ packed, unsigned* __restrict__ rank, int E) {
  int e = blockIdx.x * blockDim.x + threadIdx.x;
  if (e >= E) return;
  unsigned fx = __float2uint_rn(ew[e] * 16777216.0f);     // ew in [0,1): fx < 2^24
  ull old = atomicAdd(&packed[(size_t)col[e] * PSTRIDE], ((ull)fx << 32) | 1ull);
  rank[e] = (unsigned)old;   // low 32 = # edges already placed at this node
}

// ---- prep: cast x f32->bf16x2  +  split W1,W2 into bf16 hi+lo ----
__global__ void k_prep(const float2* __restrict__ x2, unsigned* __restrict__ xb, int n64,
                       const float* __restrict__ W1, const float* __restrict__ W2,
                       unsigned short* __restrict__ Whi1, unsigned short* __restrict__ Wlo1,
                       unsigned short* __restrict__ Whi2, unsigned short* __restrict__ Wlo2) {
  int i = blockIdx.x * blockDim.x + threadIdx.x;
  if (i < n64) { float2 v = x2[i]; xb[i] = bpack(v.x, v.y); return; }
  int j = i - n64;
  if (j >= 2 * D * D) return;
  const float* W = (j < D * D) ? W1 : W2;
  unsigned short* Hh = (j < D * D) ? Whi1 : Whi2;
  unsigned short* Hl = (j < D * D) ? Wlo1 : Wlo2;
  int k = j & (D * D - 1);
  float w = W[k];
  unsigned short h = bh16(w);
  Hh[k] = h;
  Hl[k] = bh16(w - __uint_as_float((unsigned)h << 16));
}

// ---------------- block exclusive scan helper (256 threads) ----------------
__device__ __forceinline__ int block_excl_scan(int v, int t, int* wsum, int* total) {
  int lane = t & 63, wid = t >> 6;
  int x = v;
  #pragma unroll
  for (int d = 1; d < 64; d <<= 1) {
    int y = __shfl_up(x, d, 64);
    if (lane >= d) x += y;
  }
  if (lane == 63) wsum[wid] = x;
  __syncthreads();
  int woff = 0;
  for (int w = 0; w < wid; ++w) woff += wsum[w];
  if (total) { int tot = 0; for (int w = 0; w < 4; ++w) tot += wsum[w]; *total = tot; }
  return woff + x - v;
}

// scan of counts (packed lo32) + dinv = rsqrt(deg+1) (packed hi32)
__global__ __launch_bounds__(SCAN_T) void k_scan1(const ull* __restrict__ packed, int* __restrict__ offs,
                                                  int* __restrict__ bsums, float* __restrict__ dinv, int n) {
  __shared__ int wsum[4];
  int t = threadIdx.x;
  int base = blockIdx.x * SCAN_ELEMS + t * 4;
  int v[4]; int s = 0;
  #pragma unroll
  for (int u = 0; u < 4; ++u) {
    int ok = (base + u < n);
    ull p = ok ? packed[(size_t)(base + u) * PSTRIDE] : 0ull;
    v[u] = (int)(p & 0xffffffffull);
    if (ok) dinv[base + u] = rsqrtf((float)(p >> 32) * (1.0f / 16777216.0f) + 1.0f);
    s += v[u];
  }
  int tot;
  int excl = block_excl_scan(s, t, wsum, &tot);
  int run = excl;
  #pragma unroll
  for (int u = 0; u < 4; ++u) { if (base + u < n) offs[base + u] = run; run += v[u]; }
  if (t == 0) bsums[blockIdx.x] = tot;
}

__global__ __launch_bounds__(SCAN_T) void k_scan2(int* __restrict__ bsums, int nb) {
  __shared__ int wsum[4];
  int t = threadIdx.x;
  int v = (t < nb) ? bsums[t] : 0;
  int excl = block_excl_scan(v, t, wsum, nullptr);
  if (t < nb) bsums[t] = excl;
}

// ---- fill CSR-by-destination edge list: u32 (row<<15 | norm q15), NO atomics ----
__global__ void k_fill3(const int* __restrict__ row, const int* __restrict__ col,
                        const float* __restrict__ ew, const unsigned* __restrict__ rank,
                        const int* __restrict__ offs, const int* __restrict__ bsums,
                        const float* __restrict__ dinv, unsigned* __restrict__ elist, int E) {
  int e = blockIdx.x * blockDim.x + threadIdx.x;
  if (e >= E) return;
  int r = row[e], c = col[e];
  float nrm = dinv[r] * ew[e] * dinv[c];     // in (0,1)
  unsigned q = __float2uint_rn(nrm * 32767.0f);
  if (q > 32767u) q = 32767u;
  elist[offs[c] + bsums[c >> 10] + rank[e]] = ((unsigned)r << 15) | q;
}

// ---- gather-aggregate: s[c] = sum_e norm*src[row] + dinv^2*src[c]  (bf16 in/out) ----
// wave per node; 4 edges in flight (16 lanes x uint4 = 256B row), inner unroll x2
__global__ __launch_bounds__(256) void k_agg(const unsigned* __restrict__ H2,
                                             const unsigned* __restrict__ elist,
                                             const int* __restrict__ offs, const int* __restrict__ bsums,
                                             const ull* __restrict__ packed, const float* __restrict__ dinv,
                                             unsigned* __restrict__ outb, int N) {
  int lane = threadIdx.x & 63;
  int c = blockIdx.x * 4 + (threadIdx.x >> 6);
  if (c >= N) return;
  int start = offs[c] + bsums[c >> 10];
  int m = (int)(packed[(size_t)c * PSTRIDE] & 0xffffffffull);
  int q = lane >> 4;            // edge slot 0..3
  int fi = lane & 15;           // uint4 index within row (features fi*8..fi*8+7)
  float a0 = 0.f, a1 = 0.f, a2 = 0.f, a3 = 0.f, a4 = 0.f, a5 = 0.f, a6 = 0.f, a7 = 0.f;
  for (int base = 0; base < m; base += 64) {
    int chunk = min(64, m - base);
    unsigned rec = (lane < chunk) ? elist[start + base + lane] : 0u;  // pad: row0, w=0
    int iters = (chunk + 3) >> 2;
    int i = 0;
    for (; i + 2 <= iters; i += 2) {
      unsigned e0 = __shfl(rec, 4 * i + q, 64);
      unsigned e1 = __shfl(rec, 4 * i + 4 + q, 64);
      float w0 = (float)(e0 & 0x7fffu) * (1.0f / 32767.0f);
      float w1 = (float)(e1 & 0x7fffu) * (1.0f / 32767.0f);
      uint4 u0 = *(const uint4*)&H2[(size_t)(e0 >> 15) * 64 + fi * 4];
      uint4 u1 = *(const uint4*)&H2[(size_t)(e1 >> 15) * 64 + fi * 4];
      a0 += w0 * bf_lo(u0.x); a1 += w0 * bf_hi(u0.x);
      a2 += w0 * bf_lo(u0.y); a3 += w0 * bf_hi(u0.y);
      a4 += w0 * bf_lo(u0.z); a5 += w0 * bf_hi(u0.z);
      a6 += w0 * bf_lo(u0.w); a7 += w0 * bf_hi(u0.w);
      a0 += w1 * bf_lo(u1.x); a1 += w1 * bf_hi(u1.x);
      a2 += w1 * bf_lo(u1.y); a3 += w1 * bf_hi(u1.y);
      a4 += w1 * bf_lo(u1.z); a5 += w1 * bf_hi(u1.z);
      a6 += w1 * bf_lo(u1.w); a7 += w1 * bf_hi(u1.w);
    }
    if (i < iters) {
      unsigned e0 = __shfl(rec, 4 * i + q, 64);
      float w0 = (float)(e0 & 0x7fffu) * (1.0f / 32767.0f);
      uint4 u0 = *(const uint4*)&H2[(size_t)(e0 >> 15) * 64 + fi * 4];
      a0 += w0 * bf_lo(u0.x); a1 += w0 * bf_hi(u0.x);
      a2 += w0 * bf_lo(u0.y); a3 += w0 * bf_hi(u0.y);
      a4 += w0 * bf_lo(u0.z); a5 += w0 * bf_hi(u0.z);
      a6 += w0 * bf_lo(u0.w); a7 += w0 * bf_hi(u0.w);
    }
  }
  a0 += __shfl_xor(a0, 16, 64); a0 += __shfl_xor(a0, 32, 64);
  a1 += __shfl_xor(a1, 16, 64); a1 += __shfl_xor(a1, 32, 64);
  a2 += __shfl_xor(a2, 16, 64); a2 += __shfl_xor(a2, 32, 64);
  a3 += __shfl_xor(a3, 16, 64); a3 += __shfl_xor(a3, 32, 64);
  a4 += __shfl_xor(a4, 16, 64); a4 += __shfl_xor(a4, 32, 64);
  a5 += __shfl_xor(a5, 16, 64); a5 += __shfl_xor(a5, 32, 64);
  a6 += __shfl_xor(a6, 16, 64); a6 += __shfl_xor(a6, 32, 64);
  a7 += __shfl_xor(a7, 16, 64); a7 += __shfl_xor(a7, 32, 64);
  if (q == 0) {
    float dv = dinv[c], sw = dv * dv;
    uint4 us = *(const uint4*)&H2[(size_t)c * 64 + fi * 4];
    a0 += sw * bf_lo(us.x); a1 += sw * bf_hi(us.x);
    a2 += sw * bf_lo(us.y); a3 += sw * bf_hi(us.y);
    a4 += sw * bf_lo(us.z); a5 += sw * bf_hi(us.z);
    a6 += sw * bf_lo(us.w); a7 += sw * bf_hi(us.w);
    uint4 o;
    o.x = bpack(a0, a1); o.y = bpack(a2, a3); o.z = bpack(a4, a5); o.w = bpack(a6, a7);
    *(uint4*)&outb[(size_t)c * 64 + fi * 4] = o;
  }
}

// ---- MFMA GEMM + epilogue: out = S @ (Whi+Wlo)^T + bias [+tanh->bf16] [+skip(bf16)->f32] ----
// S row-major bf16 [n][128]. Wave computes 16 rows x 128 cols; no LDS.
template<int TANH, int SKIP>
__global__ __launch_bounds__(256) void k_mgemm(const unsigned short* __restrict__ S,
                                               const unsigned short* __restrict__ Whi,
                                               const unsigned short* __restrict__ Wlo,
                                               const float* __restrict__ bias,
                                               const unsigned short* __restrict__ skipb,
                                               void* __restrict__ outv, int n) {
  int wave = threadIdx.x >> 6, lane = threadIdx.x & 63;
  int r0 = blockIdx.x * 64 + wave * 16;
  if (r0 >= n) return;
  int cl = lane & 15;       // A-row offset / B-col offset / D-col offset
  int kg = lane >> 4;       // k-group 0..3
  int arow = r0 + cl; if (arow >= n) arow = n - 1;
  const unsigned short* srow = S + (size_t)arow * D + kg * 8;
  bf16x8 a[4];
  #pragma unroll
  for (int kt = 0; kt < 4; ++kt) a[kt] = *(const bf16x8*)(srow + kt * 32);

  #pragma unroll
  for (int j0 = 0; j0 < 8; ++j0) {
    int col = j0 * 16 + cl;
    const unsigned short* wh = Whi + (size_t)col * D + kg * 8;
    const unsigned short* wl = Wlo + (size_t)col * D + kg * 8;
    f32x4 acc = {0.f, 0.f, 0.f, 0.f};
    #pragma unroll
    for (int kt = 0; kt < 4; ++kt)
      acc = __builtin_amdgcn_mfma_f32_16x16x32_bf16(a[kt], *(const bf16x8*)(wh + kt * 32), acc, 0, 0, 0);
    #pragma unroll
    for (int kt = 0; kt < 4; ++kt)
      acc = __builtin_amdgcn_mfma_f32_16x16x32_bf16(a[kt], *(const bf16x8*)(wl + kt * 32), acc, 0, 0, 0);
    float bv = bias[col];
    #pragma unroll
    for (int i = 0; i < 4; ++i) {
      int r = r0 + kg * 4 + i;
      if (r < n) {
        float o = acc[i] + bv;
        if (TANH) {
          o = tanhf(o);
          ((unsigned short*)outv)[(size_t)r * D + col] = bh16(o);
        } else {
          if (SKIP) o += __uint_as_float((unsigned)skipb[(size_t)r * D + col] << 16);
          ((float*)outv)[(size_t)r * D + col] = o;
        }
      }
    }
  }
}

// ---------------- launch ----------------
extern "C" void kernel_launch(void* const* d_in, const int* in_sizes, int n_in,
                              void* d_out, int out_size, void* d_ws, size_t ws_size,
                              hipStream_t stream) {
  const int*   et = (const int*)d_in[0];
  const float* ef = (const float*)d_in[1];
  const float* x  = (const float*)d_in[2];
  const float* W1 = (const float*)d_in[3];
  const float* b1 = (const float*)d_in[4];
  const float* W2 = (const float*)d_in[5];
  const float* b2 = (const float*)d_in[6];

  int E = in_sizes[1];
  int N = in_sizes[2] / D;
  const int* row = et;
  const int* col = et + E;

  char* p = (char*)d_ws;
  auto alloc = [&](size_t bytes) { char* q = p; p += (bytes + 255) & ~(size_t)255; return q; };
  ull*      packed = (ull*)     alloc((size_t)N * 8 * PSTRIDE);   // 6.4MB padded
  int*      offs   = (int*)     alloc((size_t)N * 4);
  float*    dinv   = (float*)   alloc((size_t)N * 4);
  int*      bsums  = (int*)     alloc(4096);
  unsigned* rank   = (unsigned*)alloc((size_t)E * 4);
  unsigned* elist  = (unsigned*)alloc((size_t)E * 4);             // u32: row<<15 | q15
  unsigned* xb     = (unsigned*)alloc((size_t)N * 64 * 4);        // bf16x2 [N,64], stays live (skip)
  unsigned* s2b    = (unsigned*)alloc((size_t)N * 64 * 4);        // s2 bf16x2
  unsigned short* whi1 = (unsigned short*)alloc(D * D * 2);
  unsigned short* wlo1 = (unsigned short*)alloc(D * D * 2);
  unsigned short* whi2 = (unsigned short*)alloc(D * D * 2);
  unsigned short* wlo2 = (unsigned short*)alloc(D * D * 2);
  unsigned* doutb = (unsigned*)d_out;  // s1 / a1 (bf16) live in d_out, dead before final write

  hipMemsetAsync(packed, 0, (size_t)N * 8 * PSTRIDE, stream);

  int eb = (E + 255) / 256;
  k_pass1<<<eb, 256, 0, stream>>>(col, ef, packed, rank, E);
  int prep_items = N * 64 + 2 * D * D;
  k_prep<<<(prep_items + 255) / 256, 256, 0, stream>>>((const float2*)x, xb, N * 64,
                                                       W1, W2, whi1, wlo1, whi2, wlo2);

  int nb = (N + SCAN_ELEMS - 1) / SCAN_ELEMS;   // 98 for N=100000 (<= 256)
  k_scan1<<<nb, SCAN_T, 0, stream>>>(packed, offs, bsums, dinv, N);
  k_scan2<<<1, SCAN_T, 0, stream>>>(bsums, nb);
  k_fill3<<<eb, 256, 0, stream>>>(row, col, ef, rank, offs, bsums, dinv, elist, E);

  int ab = (N + 3) / 4;
  int gb = (N + 63) / 64;
  // layer 1: s1 = A~ @ xb -> d_out(bf16) ; a1 = tanh(s1@W1^T + b1) in-place
  k_agg<<<ab, 256, 0, stream>>>(xb, elist, offs, bsums, packed, dinv, doutb, N);
  k_mgemm<1, 0><<<gb, 256, 0, stream>>>((const unsigned short*)doutb, whi1, wlo1, b1, nullptr, doutb, N);
  // layer 2: s2 = A~ @ a1 -> s2b ; out = s2@W2^T + b2 + xb(skip) -> d_out f32
  k_agg<<<ab, 256, 0, stream>>>(doutb, elist, offs, bsums, packed, dinv, s2b, N);
  k_mgemm<0, 1><<<gb, 256, 0, stream>>>((const unsigned short*)s2b, whi2, wlo2, b2,
                                        (const unsigned short*)xb, d_out, N);
}

// Round 6
// 367.225 us; speedup vs baseline: 1.6749x; 1.0136x over previous
//
#include <hip/hip_runtime.h>
#include <hip/hip_bf16.h>
#include <math.h>

#define D 128
#define SCAN_T 256
#define SCAN_ELEMS 1024  // 4 per thread
#define PSTRIDE 8        // ull stride per node for packed[] (64B sector padding)

typedef unsigned long long ull;
typedef __attribute__((ext_vector_type(8))) short bf16x8;
typedef __attribute__((ext_vector_type(4))) float f32x4;

__device__ __forceinline__ float bf_lo(unsigned u) { return __uint_as_float(u << 16); }
__device__ __forceinline__ float bf_hi(unsigned u) { return __uint_as_float(u & 0xffff0000u); }
__device__ __forceinline__ unsigned bpack(float a, float b) {  // RNE bf16x2
  unsigned ua = __float_as_uint(a), ub = __float_as_uint(b);
  ua += 0x7fff + ((ua >> 16) & 1);
  ub += 0x7fff + ((ub >> 16) & 1);
  return (ua >> 16) | (ub & 0xffff0000u);
}
__device__ __forceinline__ unsigned short bh16(float a) {  // RNE bf16
  unsigned ua = __float_as_uint(a);
  ua += 0x7fff + ((ua >> 16) & 1);
  return (unsigned short)(ua >> 16);
}

// ---- fused: edge atomics (blocks first) + x cast + W hi/lo split ----
__global__ void k_pass1(const int* __restrict__ col, const float* __restrict__ ew,
                        ull* __restrict__ packed, unsigned* __restrict__ rank, int E,
                        const float2* __restrict__ x2, unsigned* __restrict__ xb, int n64,
                        const float* __restrict__ W1, const float* __restrict__ W2,
                        unsigned short* __restrict__ Whi1, unsigned short* __restrict__ Wlo1,
                        unsigned short* __restrict__ Whi2, unsigned short* __restrict__ Wlo2) {
  int gid = blockIdx.x * blockDim.x + threadIdx.x;
  if (gid < E) {
    unsigned fx = __float2uint_rn(ew[gid] * 16777216.0f);   // ew in [0,1): fx < 2^24
    ull old = atomicAdd(&packed[(size_t)col[gid] * PSTRIDE], ((ull)fx << 32) | 1ull);
    rank[gid] = (unsigned)old;   // low 32 = # edges already placed at this node
    return;
  }
  int i = gid - E;
  if (i < n64) { float2 v = x2[i]; xb[i] = bpack(v.x, v.y); return; }
  int j = i - n64;
  if (j >= 2 * D * D) return;
  const float* W = (j < D * D) ? W1 : W2;
  unsigned short* Hh = (j < D * D) ? Whi1 : Whi2;
  unsigned short* Hl = (j < D * D) ? Wlo1 : Wlo2;
  int k = j & (D * D - 1);
  float w = W[k];
  unsigned short h = bh16(w);
  Hh[k] = h;
  Hl[k] = bh16(w - __uint_as_float((unsigned)h << 16));
}

// ---------------- block exclusive scan helper (256 threads) ----------------
__device__ __forceinline__ int block_excl_scan(int v, int t, int* wsum, int* total) {
  int lane = t & 63, wid = t >> 6;
  int x = v;
  #pragma unroll
  for (int d = 1; d < 64; d <<= 1) {
    int y = __shfl_up(x, d, 64);
    if (lane >= d) x += y;
  }
  if (lane == 63) wsum[wid] = x;
  __syncthreads();
  int woff = 0;
  for (int w = 0; w < wid; ++w) woff += wsum[w];
  if (total) { int tot = 0; for (int w = 0; w < 4; ++w) tot += wsum[w]; *total = tot; }
  return woff + x - v;
}

// scan of counts (packed lo32) + dinv = rsqrt(deg+1) (packed hi32)
__global__ __launch_bounds__(SCAN_T) void k_scan1(const ull* __restrict__ packed, int* __restrict__ offs,
                                                  int* __restrict__ bsums, float* __restrict__ dinv, int n) {
  __shared__ int wsum[4];
  int t = threadIdx.x;
  int base = blockIdx.x * SCAN_ELEMS + t * 4;
  int v[4]; int s = 0;
  #pragma unroll
  for (int u = 0; u < 4; ++u) {
    int ok = (base + u < n);
    ull p = ok ? packed[(size_t)(base + u) * PSTRIDE] : 0ull;
    v[u] = (int)(p & 0xffffffffull);
    if (ok) dinv[base + u] = rsqrtf((float)(p >> 32) * (1.0f / 16777216.0f) + 1.0f);
    s += v[u];
  }
  int tot;
  int excl = block_excl_scan(s, t, wsum, &tot);
  int run = excl;
  #pragma unroll
  for (int u = 0; u < 4; ++u) { if (base + u < n) offs[base + u] = run; run += v[u]; }
  if (t == 0) bsums[blockIdx.x] = tot;
}

__global__ __launch_bounds__(SCAN_T) void k_scan2(int* __restrict__ bsums, int nb) {
  __shared__ int wsum[4];
  int t = threadIdx.x;
  int v = (t < nb) ? bsums[t] : 0;
  int excl = block_excl_scan(v, t, wsum, nullptr);
  if (t < nb) bsums[t] = excl;
}

// ---- fill CSR-by-destination edge list: u32 (row<<15 | norm q15), NO atomics ----
__global__ void k_fill3(const int* __restrict__ row, const int* __restrict__ col,
                        const float* __restrict__ ew, const unsigned* __restrict__ rank,
                        const int* __restrict__ offs, const int* __restrict__ bsums,
                        const float* __restrict__ dinv, unsigned* __restrict__ elist, int E) {
  int e = blockIdx.x * blockDim.x + threadIdx.x;
  if (e >= E) return;
  int r = row[e], c = col[e];
  float nrm = dinv[r] * ew[e] * dinv[c];     // in (0,1)
  unsigned q = __float2uint_rn(nrm * 32767.0f);
  if (q > 32767u) q = 32767u;
  elist[offs[c] + bsums[c >> 10] + rank[e]] = ((unsigned)r << 15) | q;
}

// ---- gather-aggregate: s[c] = sum_e norm*src[row] + dinv^2*src[c]  (bf16 in/out) ----
// wave per node; 4 edges in flight (16 lanes x uint4 = 256B row), 4-deep pipeline
__global__ __launch_bounds__(256) void k_agg(const unsigned* __restrict__ H2,
                                             const unsigned* __restrict__ elist,
                                             const int* __restrict__ offs, const int* __restrict__ bsums,
                                             const ull* __restrict__ packed, const float* __restrict__ dinv,
                                             unsigned* __restrict__ outb, int N) {
  int lane = threadIdx.x & 63;
  int c = blockIdx.x * 4 + (threadIdx.x >> 6);
  if (c >= N) return;
  int start = offs[c] + bsums[c >> 10];
  int m = (int)(packed[(size_t)c * PSTRIDE] & 0xffffffffull);
  int q = lane >> 4;            // edge slot 0..3
  int fi = lane & 15;           // uint4 index within row (features fi*8..fi*8+7)
  float a0 = 0.f, a1 = 0.f, a2 = 0.f, a3 = 0.f, a4 = 0.f, a5 = 0.f, a6 = 0.f, a7 = 0.f;
  for (int base = 0; base < m; base += 64) {
    int chunk = min(64, m - base);
    unsigned rec = (lane < chunk) ? elist[start + base + lane] : 0u;  // pad: row0, w=0
    int iters = (chunk + 3) >> 2;
    int i = 0;
    for (; i + 4 <= iters; i += 4) {
      unsigned e0 = __shfl(rec, 4 * i + q, 64);
      unsigned e1 = __shfl(rec, 4 * i + 4 + q, 64);
      unsigned e2 = __shfl(rec, 4 * i + 8 + q, 64);
      unsigned e3 = __shfl(rec, 4 * i + 12 + q, 64);
      uint4 u0 = *(const uint4*)&H2[(size_t)(e0 >> 15) * 64 + fi * 4];
      uint4 u1 = *(const uint4*)&H2[(size_t)(e1 >> 15) * 64 + fi * 4];
      uint4 u2 = *(const uint4*)&H2[(size_t)(e2 >> 15) * 64 + fi * 4];
      uint4 u3 = *(const uint4*)&H2[(size_t)(e3 >> 15) * 64 + fi * 4];
      float w0 = (float)(e0 & 0x7fffu) * (1.0f / 32767.0f);
      float w1 = (float)(e1 & 0x7fffu) * (1.0f / 32767.0f);
      float w2 = (float)(e2 & 0x7fffu) * (1.0f / 32767.0f);
      float w3 = (float)(e3 & 0x7fffu) * (1.0f / 32767.0f);
      a0 += w0 * bf_lo(u0.x); a1 += w0 * bf_hi(u0.x);
      a2 += w0 * bf_lo(u0.y); a3 += w0 * bf_hi(u0.y);
      a4 += w0 * bf_lo(u0.z); a5 += w0 * bf_hi(u0.z);
      a6 += w0 * bf_lo(u0.w); a7 += w0 * bf_hi(u0.w);
      a0 += w1 * bf_lo(u1.x); a1 += w1 * bf_hi(u1.x);
      a2 += w1 * bf_lo(u1.y); a3 += w1 * bf_hi(u1.y);
      a4 += w1 * bf_lo(u1.z); a5 += w1 * bf_hi(u1.z);
      a6 += w1 * bf_lo(u1.w); a7 += w1 * bf_hi(u1.w);
      a0 += w2 * bf_lo(u2.x); a1 += w2 * bf_hi(u2.x);
      a2 += w2 * bf_lo(u2.y); a3 += w2 * bf_hi(u2.y);
      a4 += w2 * bf_lo(u2.z); a5 += w2 * bf_hi(u2.z);
      a6 += w2 * bf_lo(u2.w); a7 += w2 * bf_hi(u2.w);
      a0 += w3 * bf_lo(u3.x); a1 += w3 * bf_hi(u3.x);
      a2 += w3 * bf_lo(u3.y); a3 += w3 * bf_hi(u3.y);
      a4 += w3 * bf_lo(u3.z); a5 += w3 * bf_hi(u3.z);
      a6 += w3 * bf_lo(u3.w); a7 += w3 * bf_hi(u3.w);
    }
    for (; i < iters; ++i) {
      unsigned e0 = __shfl(rec, 4 * i + q, 64);
      float w0 = (float)(e0 & 0x7fffu) * (1.0f / 32767.0f);
      uint4 u0 = *(const uint4*)&H2[(size_t)(e0 >> 15) * 64 + fi * 4];
      a0 += w0 * bf_lo(u0.x); a1 += w0 * bf_hi(u0.x);
      a2 += w0 * bf_lo(u0.y); a3 += w0 * bf_hi(u0.y);
      a4 += w0 * bf_lo(u0.z); a5 += w0 * bf_hi(u0.z);
      a6 += w0 * bf_lo(u0.w); a7 += w0 * bf_hi(u0.w);
    }
  }
  a0 += __shfl_xor(a0, 16, 64); a0 += __shfl_xor(a0, 32, 64);
  a1 += __shfl_xor(a1, 16, 64); a1 += __shfl_xor(a1, 32, 64);
  a2 += __shfl_xor(a2, 16, 64); a2 += __shfl_xor(a2, 32, 64);
  a3 += __shfl_xor(a3, 16, 64); a3 += __shfl_xor(a3, 32, 64);
  a4 += __shfl_xor(a4, 16, 64); a4 += __shfl_xor(a4, 32, 64);
  a5 += __shfl_xor(a5, 16, 64); a5 += __shfl_xor(a5, 32, 64);
  a6 += __shfl_xor(a6, 16, 64); a6 += __shfl_xor(a6, 32, 64);
  a7 += __shfl_xor(a7, 16, 64); a7 += __shfl_xor(a7, 32, 64);
  if (q == 0) {
    float dv = dinv[c], sw = dv * dv;
    uint4 us = *(const uint4*)&H2[(size_t)c * 64 + fi * 4];
    a0 += sw * bf_lo(us.x); a1 += sw * bf_hi(us.x);
    a2 += sw * bf_lo(us.y); a3 += sw * bf_hi(us.y);
    a4 += sw * bf_lo(us.z); a5 += sw * bf_hi(us.z);
    a6 += sw * bf_lo(us.w); a7 += sw * bf_hi(us.w);
    uint4 o;
    o.x = bpack(a0, a1); o.y = bpack(a2, a3); o.z = bpack(a4, a5); o.w = bpack(a6, a7);
    *(uint4*)&outb[(size_t)c * 64 + fi * 4] = o;
  }
}

// ---- MFMA GEMM + epilogue: out = S @ (Whi+Wlo)^T + bias [+tanh->bf16] [+skip(bf16)->f32] ----
// S row-major bf16 [n][128]. Wave computes 16 rows x 128 cols; no LDS.
template<int TANH, int SKIP>
__global__ __launch_bounds__(256) void k_mgemm(const unsigned short* __restrict__ S,
                                               const unsigned short* __restrict__ Whi,
                                               const unsigned short* __restrict__ Wlo,
                                               const float* __restrict__ bias,
                                               const unsigned short* __restrict__ skipb,
                                               void* __restrict__ outv, int n) {
  int wave = threadIdx.x >> 6, lane = threadIdx.x & 63;
  int r0 = blockIdx.x * 64 + wave * 16;
  if (r0 >= n) return;
  int cl = lane & 15;       // A-row offset / B-col offset / D-col offset
  int kg = lane >> 4;       // k-group 0..3
  int arow = r0 + cl; if (arow >= n) arow = n - 1;
  const unsigned short* srow = S + (size_t)arow * D + kg * 8;
  bf16x8 a[4];
  #pragma unroll
  for (int kt = 0; kt < 4; ++kt) a[kt] = *(const bf16x8*)(srow + kt * 32);

  #pragma unroll
  for (int j0 = 0; j0 < 8; ++j0) {
    int col = j0 * 16 + cl;
    const unsigned short* wh = Whi + (size_t)col * D + kg * 8;
    const unsigned short* wl = Wlo + (size_t)col * D + kg * 8;
    f32x4 acc = {0.f, 0.f, 0.f, 0.f};
    #pragma unroll
    for (int kt = 0; kt < 4; ++kt)
      acc = __builtin_amdgcn_mfma_f32_16x16x32_bf16(a[kt], *(const bf16x8*)(wh + kt * 32), acc, 0, 0, 0);
    #pragma unroll
    for (int kt = 0; kt < 4; ++kt)
      acc = __builtin_amdgcn_mfma_f32_16x16x32_bf16(a[kt], *(const bf16x8*)(wl + kt * 32), acc, 0, 0, 0);
    float bv = bias[col];
    #pragma unroll
    for (int i = 0; i < 4; ++i) {
      int r = r0 + kg * 4 + i;
      if (r < n) {
        float o = acc[i] + bv;
        if (TANH) {
          o = tanhf(o);
          ((unsigned short*)outv)[(size_t)r * D + col] = bh16(o);
        } else {
          if (SKIP) o += __uint_as_float((unsigned)skipb[(size_t)r * D + col] << 16);
          ((float*)outv)[(size_t)r * D + col] = o;
        }
      }
    }
  }
}

// ---------------- launch ----------------
extern "C" void kernel_launch(void* const* d_in, const int* in_sizes, int n_in,
                              void* d_out, int out_size, void* d_ws, size_t ws_size,
                              hipStream_t stream) {
  const int*   et = (const int*)d_in[0];
  const float* ef = (const float*)d_in[1];
  const float* x  = (const float*)d_in[2];
  const float* W1 = (const float*)d_in[3];
  const float* b1 = (const float*)d_in[4];
  const float* W2 = (const float*)d_in[5];
  const float* b2 = (const float*)d_in[6];

  int E = in_sizes[1];
  int N = in_sizes[2] / D;
  const int* row = et;
  const int* col = et + E;

  char* p = (char*)d_ws;
  auto alloc = [&](size_t bytes) { char* q = p; p += (bytes + 255) & ~(size_t)255; return q; };
  ull*      packed = (ull*)     alloc((size_t)N * 8 * PSTRIDE);   // 6.4MB padded
  int*      offs   = (int*)     alloc((size_t)N * 4);
  float*    dinv   = (float*)   alloc((size_t)N * 4);
  int*      bsums  = (int*)     alloc(4096);
  unsigned* rank   = (unsigned*)alloc((size_t)E * 4);
  unsigned* elist  = (unsigned*)alloc((size_t)E * 4);             // u32: row<<15 | q15
  unsigned* xb     = (unsigned*)alloc((size_t)N * 64 * 4);        // bf16x2 [N,64], stays live (skip)
  unsigned* s2b    = (unsigned*)alloc((size_t)N * 64 * 4);        // s2 bf16x2
  unsigned short* whi1 = (unsigned short*)alloc(D * D * 2);
  unsigned short* wlo1 = (unsigned short*)alloc(D * D * 2);
  unsigned short* whi2 = (unsigned short*)alloc(D * D * 2);
  unsigned short* wlo2 = (unsigned short*)alloc(D * D * 2);
  unsigned* doutb = (unsigned*)d_out;  // s1 / a1 (bf16) live in d_out, dead before final write

  hipMemsetAsync(packed, 0, (size_t)N * 8 * PSTRIDE, stream);

  int items = E + N * 64 + 2 * D * D;
  k_pass1<<<(items + 255) / 256, 256, 0, stream>>>(col, ef, packed, rank, E,
                                                   (const float2*)x, xb, N * 64,
                                                   W1, W2, whi1, wlo1, whi2, wlo2);

  int nb = (N + SCAN_ELEMS - 1) / SCAN_ELEMS;   // 98 for N=100000 (<= 256)
  k_scan1<<<nb, SCAN_T, 0, stream>>>(packed, offs, bsums, dinv, N);
  k_scan2<<<1, SCAN_T, 0, stream>>>(bsums, nb);
  int eb = (E + 255) / 256;
  k_fill3<<<eb, 256, 0, stream>>>(row, col, ef, rank, offs, bsums, dinv, elist, E);

  int ab = (N + 3) / 4;
  int gb = (N + 63) / 64;
  // layer 1: s1 = A~ @ xb -> d_out(bf16) ; a1 = tanh(s1@W1^T + b1) in-place
  k_agg<<<ab, 256, 0, stream>>>(xb, elist, offs, bsums, packed, dinv, doutb, N);
  k_mgemm<1, 0><<<gb, 256, 0, stream>>>((const unsigned short*)doutb, whi1, wlo1, b1, nullptr, doutb, N);
  // layer 2: s2 = A~ @ a1 -> s2b ; out = s2@W2^T + b2 + xb(skip) -> d_out f32
  k_agg<<<ab, 256, 0, stream>>>(doutb, elist, offs, bsums, packed, dinv, s2b, N);
  k_mgemm<0, 1><<<gb, 256, 0, stream>>>((const unsigned short*)s2b, whi2, wlo2, b2,
                                        (const unsigned short*)xb, d_out, N);
}

// Round 7
// 341.961 us; speedup vs baseline: 1.7986x; 1.0739x over previous
//
#include <hip/hip_runtime.h>
#include <hip/hip_bf16.h>
#include <math.h>

#define D 128
#define SCAN_T 256
#define EPB 4096          // edges per block for hist/scatter
#define MAXNB 800         // LDS histogram capacity (NB = ceil(N/128) = 782)

typedef unsigned long long ull;
typedef unsigned short ushort_t;
typedef __attribute__((ext_vector_type(8))) short bf16x8;
typedef __attribute__((ext_vector_type(4))) float f32x4;

__device__ __forceinline__ float bf_lo(unsigned u) { return __uint_as_float(u << 16); }
__device__ __forceinline__ float bf_hi(unsigned u) { return __uint_as_float(u & 0xffff0000u); }
__device__ __forceinline__ unsigned bpack(float a, float b) {  // RNE bf16x2
  unsigned ua = __float_as_uint(a), ub = __float_as_uint(b);
  ua += 0x7fff + ((ua >> 16) & 1);
  ub += 0x7fff + ((ub >> 16) & 1);
  return (ua >> 16) | (ub & 0xffff0000u);
}
__device__ __forceinline__ ushort_t bh16(float a) {  // RNE bf16
  unsigned ua = __float_as_uint(a);
  ua += 0x7fff + ((ua >> 16) & 1);
  return (ushort_t)(ua >> 16);
}

// ---- hist level-1 (col>>7) with LDS atomics; prep (x cast + W split) in tail blocks ----
__global__ __launch_bounds__(256) void k_h1(const int* __restrict__ col, int E, int B1, int B1pad,
                                            int* __restrict__ gh, int NB,
                                            const float2* __restrict__ x2, unsigned* __restrict__ xb, int n64,
                                            const float* __restrict__ W1, const float* __restrict__ W2,
                                            ushort_t* __restrict__ Whi1, ushort_t* __restrict__ Wlo1,
                                            ushort_t* __restrict__ Whi2, ushort_t* __restrict__ Wlo2) {
  int b = blockIdx.x, t = threadIdx.x;
  if (b < B1) {
    __shared__ int h[MAXNB];
    for (int i = t; i < NB; i += 256) h[i] = 0;
    __syncthreads();
    int e0 = b * EPB, e1 = min(E, e0 + EPB);
    for (int e = e0 + t; e < e1; e += 256) atomicAdd(&h[col[e] >> 7], 1);
    __syncthreads();
    for (int i = t; i < NB; i += 256) gh[i * B1pad + b] = h[i];
    return;
  }
  int idx = (b - B1) * 256 + t;
  if (idx < n64) { float2 v = x2[idx]; xb[idx] = bpack(v.x, v.y); return; }
  int j = idx - n64;
  if (j >= 2 * D * D) return;
  const float* W = (j < D * D) ? W1 : W2;
  ushort_t* Hh = (j < D * D) ? Whi1 : Whi2;
  ushort_t* Hl = (j < D * D) ? Wlo1 : Wlo2;
  int k = j & (D * D - 1);
  float w = W[k];
  ushort_t hh = bh16(w);
  Hh[k] = hh;
  Hl[k] = bh16(w - __uint_as_float((unsigned)hh << 16));
}

// ---- per-bin scan across blocks: gh[bin][b] -> exclusive prefix; binTotal[bin] = sum ----
__global__ __launch_bounds__(512) void k_hscan(int* __restrict__ gh, int* __restrict__ binTotal,
                                               int B1, int B1pad) {
  __shared__ int wsum[8];
  int bin = blockIdx.x, t = threadIdx.x;
  int v = (t < B1) ? gh[bin * B1pad + t] : 0;
  int lane = t & 63, wid = t >> 6;
  int x = v;
  #pragma unroll
  for (int d = 1; d < 64; d <<= 1) { int y = __shfl_up(x, d, 64); if (lane >= d) x += y; }
  if (lane == 63) wsum[wid] = x;
  __syncthreads();
  int woff = 0;
  for (int w = 0; w < wid; ++w) woff += wsum[w];
  if (t < B1) gh[bin * B1pad + t] = woff + x - v;
  if (t == 511) binTotal[bin] = woff + x;   // last lane of last wave: inclusive total
}

// ---------------- block exclusive scan helper (256 threads) ----------------
__device__ __forceinline__ int block_excl_scan(int v, int t, int* wsum, int* total) {
  int lane = t & 63, wid = t >> 6;
  int x = v;
  #pragma unroll
  for (int d = 1; d < 64; d <<= 1) {
    int y = __shfl_up(x, d, 64);
    if (lane >= d) x += y;
  }
  if (lane == 63) wsum[wid] = x;
  __syncthreads();
  int woff = 0;
  for (int w = 0; w < wid; ++w) woff += wsum[w];
  if (total) { int tot = 0; for (int w = 0; w < 4; ++w) tot += wsum[w]; *total = tot; }
  return woff + x - v;
}

// ---- scan binTotal -> binBase (+ sentinel) ----
__global__ __launch_bounds__(SCAN_T) void k_hscan2(const int* __restrict__ binTotal,
                                                   int* __restrict__ binBase, int NB) {
  __shared__ int wsum[4];
  int t = threadIdx.x;
  int base = t * 4;
  int v[4]; int s = 0;
  #pragma unroll
  for (int u = 0; u < 4; ++u) { v[u] = (base + u < NB) ? binTotal[base + u] : 0; s += v[u]; }
  int tot;
  int excl = block_excl_scan(s, t, wsum, &tot);
  int run = excl;
  #pragma unroll
  for (int u = 0; u < 4; ++u) { if (base + u < NB) binBase[base + u] = run; run += v[u]; }
  if (t == 0) binBase[NB] = tot;
}

// ---- scatter edges into level-1 buckets (LDS cursors, no global atomics) ----
__global__ __launch_bounds__(256) void k_scatter(const int* __restrict__ row, const int* __restrict__ col,
                                                 const float* __restrict__ ew,
                                                 const int* __restrict__ gh, const int* __restrict__ binBase,
                                                 int B1pad, int NB,
                                                 unsigned* __restrict__ a_cr, unsigned* __restrict__ a_r, int E) {
  __shared__ int cur[MAXNB];
  int b = blockIdx.x, t = threadIdx.x;
  for (int i = t; i < NB; i += 256) cur[i] = binBase[i] + gh[i * B1pad + b];
  __syncthreads();
  int e0 = b * EPB, e1 = min(E, e0 + EPB);
  for (int e = e0 + t; e < e1; e += 256) {
    int c = col[e], r = row[e];
    unsigned q = __float2uint_rn(ew[e] * 32767.0f);
    if (q > 32767u) q = 32767u;
    int pos = atomicAdd(&cur[c >> 7], 1);
    a_cr[pos] = ((unsigned)c << 15) | q;
    a_r[pos] = (unsigned)r;
  }
}

// ---- level-2: per-bucket 128-bin counting sort; emits offs, deg, dest-sorted (r|ew) ----
__global__ __launch_bounds__(256) void k_bucket(const unsigned* __restrict__ a_cr,
                                                const unsigned* __restrict__ a_r,
                                                const int* __restrict__ binBase,
                                                int* __restrict__ offs, float* __restrict__ deg,
                                                unsigned* __restrict__ sorted2, int N) {
  __shared__ int hist[128];
  __shared__ float wdeg[128];
  __shared__ int pfx[128];
  __shared__ int cur[128];
  int bin = blockIdx.x, t = threadIdx.x;
  if (t < 128) { hist[t] = 0; wdeg[t] = 0.f; cur[t] = 0; }
  __syncthreads();
  int s0 = binBase[bin], s1 = binBase[bin + 1];
  for (int i = s0 + t; i < s1; i += 256) {
    unsigned v = a_cr[i];
    int lc = (v >> 15) & 127;
    atomicAdd(&hist[lc], 1);
    atomicAdd(&wdeg[lc], (float)(v & 32767u) * (1.0f / 32767.0f));
  }
  __syncthreads();
  if (t == 0) { int run = 0; for (int i = 0; i < 128; ++i) { pfx[i] = run; run += hist[i]; } }
  __syncthreads();
  int c0 = bin << 7;
  if (t < 128 && c0 + t < N) { offs[c0 + t] = s0 + pfx[t]; deg[c0 + t] = wdeg[t]; }
  for (int i = s0 + t; i < s1; i += 256) {
    unsigned v = a_cr[i];
    int lc = (v >> 15) & 127;
    int pos = s0 + pfx[lc] + atomicAdd(&cur[lc], 1);
    sorted2[pos] = (a_r[i] << 15) | (v & 32767u);
  }
}

// ---- dinv = rsqrt(deg+1); offs sentinel ----
__global__ void k_dinv(const float* __restrict__ deg, float* __restrict__ dinv,
                       int* __restrict__ offs, int N, int E) {
  int i = blockIdx.x * blockDim.x + threadIdx.x;
  if (i == 0) offs[N] = E;
  if (i < N) dinv[i] = rsqrtf(deg[i] + 1.0f);
}

// ---- rewrite ew -> norm = dinv[r]*ew*dinv[c] in place (q15) ----
__global__ void k_norm(unsigned* __restrict__ el, const int* __restrict__ offs,
                       const float* __restrict__ dinv, int N) {
  int c = blockIdx.x * blockDim.x + threadIdx.x;
  if (c >= N) return;
  int s0 = offs[c], s1 = offs[c + 1];
  float dc = dinv[c] * (1.0f / 32767.0f);
  for (int i = s0; i < s1; ++i) {
    unsigned v = el[i];
    unsigned r = v >> 15;
    float nrm = dinv[r] * (float)(v & 32767u) * dc;
    unsigned q = __float2uint_rn(nrm * 32767.0f);
    if (q > 32767u) q = 32767u;
    el[i] = (r << 15) | q;
  }
}

// ---- gather-aggregate: s[c] = sum_e norm*src[row] + dinv^2*src[c]  (bf16 in/out) ----
// wave per node; 4 edges in flight (16 lanes x uint4 = 256B row), 4-deep pipeline
__global__ __launch_bounds__(256) void k_agg(const unsigned* __restrict__ H2,
                                             const unsigned* __restrict__ elist,
                                             const int* __restrict__ offs, const float* __restrict__ dinv,
                                             unsigned* __restrict__ outb, int N) {
  int lane = threadIdx.x & 63;
  int c = blockIdx.x * 4 + (threadIdx.x >> 6);
  if (c >= N) return;
  int start = offs[c];
  int m = offs[c + 1] - start;
  int q = lane >> 4;            // edge slot 0..3
  int fi = lane & 15;           // uint4 index within row (features fi*8..fi*8+7)
  float a0 = 0.f, a1 = 0.f, a2 = 0.f, a3 = 0.f, a4 = 0.f, a5 = 0.f, a6 = 0.f, a7 = 0.f;
  for (int base = 0; base < m; base += 64) {
    int chunk = min(64, m - base);
    unsigned rec = (lane < chunk) ? elist[start + base + lane] : 0u;  // pad: row0, w=0
    int iters = (chunk + 3) >> 2;
    int i = 0;
    for (; i + 4 <= iters; i += 4) {
      unsigned e0 = __shfl(rec, 4 * i + q, 64);
      unsigned e1 = __shfl(rec, 4 * i + 4 + q, 64);
      unsigned e2 = __shfl(rec, 4 * i + 8 + q, 64);
      unsigned e3 = __shfl(rec, 4 * i + 12 + q, 64);
      uint4 u0 = *(const uint4*)&H2[(size_t)(e0 >> 15) * 64 + fi * 4];
      uint4 u1 = *(const uint4*)&H2[(size_t)(e1 >> 15) * 64 + fi * 4];
      uint4 u2 = *(const uint4*)&H2[(size_t)(e2 >> 15) * 64 + fi * 4];
      uint4 u3 = *(const uint4*)&H2[(size_t)(e3 >> 15) * 64 + fi * 4];
      float w0 = (float)(e0 & 0x7fffu) * (1.0f / 32767.0f);
      float w1 = (float)(e1 & 0x7fffu) * (1.0f / 32767.0f);
      float w2 = (float)(e2 & 0x7fffu) * (1.0f / 32767.0f);
      float w3 = (float)(e3 & 0x7fffu) * (1.0f / 32767.0f);
      a0 += w0 * bf_lo(u0.x); a1 += w0 * bf_hi(u0.x);
      a2 += w0 * bf_lo(u0.y); a3 += w0 * bf_hi(u0.y);
      a4 += w0 * bf_lo(u0.z); a5 += w0 * bf_hi(u0.z);
      a6 += w0 * bf_lo(u0.w); a7 += w0 * bf_hi(u0.w);
      a0 += w1 * bf_lo(u1.x); a1 += w1 * bf_hi(u1.x);
      a2 += w1 * bf_lo(u1.y); a3 += w1 * bf_hi(u1.y);
      a4 += w1 * bf_lo(u1.z); a5 += w1 * bf_hi(u1.z);
      a6 += w1 * bf_lo(u1.w); a7 += w1 * bf_hi(u1.w);
      a0 += w2 * bf_lo(u2.x); a1 += w2 * bf_hi(u2.x);
      a2 += w2 * bf_lo(u2.y); a3 += w2 * bf_hi(u2.y);
      a4 += w2 * bf_lo(u2.z); a5 += w2 * bf_hi(u2.z);
      a6 += w2 * bf_lo(u2.w); a7 += w2 * bf_hi(u2.w);
      a0 += w3 * bf_lo(u3.x); a1 += w3 * bf_hi(u3.x);
      a2 += w3 * bf_lo(u3.y); a3 += w3 * bf_hi(u3.y);
      a4 += w3 * bf_lo(u3.z); a5 += w3 * bf_hi(u3.z);
      a6 += w3 * bf_lo(u3.w); a7 += w3 * bf_hi(u3.w);
    }
    for (; i < iters; ++i) {
      unsigned e0 = __shfl(rec, 4 * i + q, 64);
      float w0 = (float)(e0 & 0x7fffu) * (1.0f / 32767.0f);
      uint4 u0 = *(const uint4*)&H2[(size_t)(e0 >> 15) * 64 + fi * 4];
      a0 += w0 * bf_lo(u0.x); a1 += w0 * bf_hi(u0.x);
      a2 += w0 * bf_lo(u0.y); a3 += w0 * bf_hi(u0.y);
      a4 += w0 * bf_lo(u0.z); a5 += w0 * bf_hi(u0.z);
      a6 += w0 * bf_lo(u0.w); a7 += w0 * bf_hi(u0.w);
    }
  }
  a0 += __shfl_xor(a0, 16, 64); a0 += __shfl_xor(a0, 32, 64);
  a1 += __shfl_xor(a1, 16, 64); a1 += __shfl_xor(a1, 32, 64);
  a2 += __shfl_xor(a2, 16, 64); a2 += __shfl_xor(a2, 32, 64);
  a3 += __shfl_xor(a3, 16, 64); a3 += __shfl_xor(a3, 32, 64);
  a4 += __shfl_xor(a4, 16, 64); a4 += __shfl_xor(a4, 32, 64);
  a5 += __shfl_xor(a5, 16, 64); a5 += __shfl_xor(a5, 32, 64);
  a6 += __shfl_xor(a6, 16, 64); a6 += __shfl_xor(a6, 32, 64);
  a7 += __shfl_xor(a7, 16, 64); a7 += __shfl_xor(a7, 32, 64);
  if (q == 0) {
    float dv = dinv[c], sw = dv * dv;
    uint4 us = *(const uint4*)&H2[(size_t)c * 64 + fi * 4];
    a0 += sw * bf_lo(us.x); a1 += sw * bf_hi(us.x);
    a2 += sw * bf_lo(us.y); a3 += sw * bf_hi(us.y);
    a4 += sw * bf_lo(us.z); a5 += sw * bf_hi(us.z);
    a6 += sw * bf_lo(us.w); a7 += sw * bf_hi(us.w);
    uint4 o;
    o.x = bpack(a0, a1); o.y = bpack(a2, a3); o.z = bpack(a4, a5); o.w = bpack(a6, a7);
    *(uint4*)&outb[(size_t)c * 64 + fi * 4] = o;
  }
}

// ---- MFMA GEMM + epilogue: out = S @ (Whi+Wlo)^T + bias [+tanh->bf16] [+skip(bf16)->f32] ----
// S row-major bf16 [n][128]. Wave computes 16 rows x 128 cols; no LDS.
template<int TANH, int SKIP>
__global__ __launch_bounds__(256) void k_mgemm(const ushort_t* __restrict__ S,
                                               const ushort_t* __restrict__ Whi,
                                               const ushort_t* __restrict__ Wlo,
                                               const float* __restrict__ bias,
                                               const ushort_t* __restrict__ skipb,
                                               void* __restrict__ outv, int n) {
  int wave = threadIdx.x >> 6, lane = threadIdx.x & 63;
  int r0 = blockIdx.x * 64 + wave * 16;
  if (r0 >= n) return;
  int cl = lane & 15;       // A-row offset / B-col offset / D-col offset
  int kg = lane >> 4;       // k-group 0..3
  int arow = r0 + cl; if (arow >= n) arow = n - 1;
  const ushort_t* srow = S + (size_t)arow * D + kg * 8;
  bf16x8 a[4];
  #pragma unroll
  for (int kt = 0; kt < 4; ++kt) a[kt] = *(const bf16x8*)(srow + kt * 32);

  #pragma unroll
  for (int j0 = 0; j0 < 8; ++j0) {
    int col = j0 * 16 + cl;
    const ushort_t* wh = Whi + (size_t)col * D + kg * 8;
    const ushort_t* wl = Wlo + (size_t)col * D + kg * 8;
    f32x4 acc = {0.f, 0.f, 0.f, 0.f};
    #pragma unroll
    for (int kt = 0; kt < 4; ++kt)
      acc = __builtin_amdgcn_mfma_f32_16x16x32_bf16(a[kt], *(const bf16x8*)(wh + kt * 32), acc, 0, 0, 0);
    #pragma unroll
    for (int kt = 0; kt < 4; ++kt)
      acc = __builtin_amdgcn_mfma_f32_16x16x32_bf16(a[kt], *(const bf16x8*)(wl + kt * 32), acc, 0, 0, 0);
    float bv = bias[col];
    #pragma unroll
    for (int i = 0; i < 4; ++i) {
      int r = r0 + kg * 4 + i;
      if (r < n) {
        float o = acc[i] + bv;
        if (TANH) {
          o = tanhf(o);
          ((ushort_t*)outv)[(size_t)r * D + col] = bh16(o);
        } else {
          if (SKIP) o += __uint_as_float((unsigned)skipb[(size_t)r * D + col] << 16);
          ((float*)outv)[(size_t)r * D + col] = o;
        }
      }
    }
  }
}

// ---------------- launch ----------------
extern "C" void kernel_launch(void* const* d_in, const int* in_sizes, int n_in,
                              void* d_out, int out_size, void* d_ws, size_t ws_size,
                              hipStream_t stream) {
  const int*   et = (const int*)d_in[0];
  const float* ef = (const float*)d_in[1];
  const float* x  = (const float*)d_in[2];
  const float* W1 = (const float*)d_in[3];
  const float* b1 = (const float*)d_in[4];
  const float* W2 = (const float*)d_in[5];
  const float* b2 = (const float*)d_in[6];

  int E = in_sizes[1];
  int N = in_sizes[2] / D;
  const int* row = et;
  const int* col = et + E;

  int NB = (N + 127) >> 7;            // 782 buckets of 128 nodes
  int B1 = (E + EPB - 1) / EPB;       // 391 edge blocks (must be <= 512 for k_hscan)
  int B1pad = (B1 + 7) & ~7;

  char* p = (char*)d_ws;
  auto alloc = [&](size_t bytes) { char* q = p; p += (bytes + 255) & ~(size_t)255; return q; };
  int*      gh       = (int*)     alloc((size_t)NB * B1pad * 4);  // ~1.25MB
  int*      binTotal = (int*)     alloc((size_t)NB * 4);
  int*      binBase  = (int*)     alloc((size_t)(NB + 1) * 4);
  unsigned* a_cr     = (unsigned*)alloc((size_t)E * 4);
  unsigned* a_r      = (unsigned*)alloc((size_t)E * 4);
  unsigned* elist    = (unsigned*)alloc((size_t)E * 4);           // sorted2, rewritten in place
  int*      offs     = (int*)     alloc((size_t)(N + 1) * 4);
  float*    deg      = (float*)   alloc((size_t)N * 4);
  float*    dinv     = (float*)   alloc((size_t)N * 4);
  unsigned* xb       = (unsigned*)alloc((size_t)N * 64 * 4);      // bf16x2 x, live till end (skip)
  unsigned* s2b      = (unsigned*)alloc((size_t)N * 64 * 4);      // s2 bf16x2
  ushort_t* whi1 = (ushort_t*)alloc(D * D * 2);
  ushort_t* wlo1 = (ushort_t*)alloc(D * D * 2);
  ushort_t* whi2 = (ushort_t*)alloc(D * D * 2);
  ushort_t* wlo2 = (ushort_t*)alloc(D * D * 2);
  unsigned* doutb = (unsigned*)d_out;  // s1 / a1 (bf16) live in d_out, dead before final write

  int prepBlocks = (N * 64 + 2 * D * D + 255) / 256;
  k_h1<<<B1 + prepBlocks, 256, 0, stream>>>(col, E, B1, B1pad, gh, NB,
                                            (const float2*)x, xb, N * 64,
                                            W1, W2, whi1, wlo1, whi2, wlo2);
  k_hscan<<<NB, 512, 0, stream>>>(gh, binTotal, B1, B1pad);
  k_hscan2<<<1, SCAN_T, 0, stream>>>(binTotal, binBase, NB);
  k_scatter<<<B1, 256, 0, stream>>>(row, col, ef, gh, binBase, B1pad, NB, a_cr, a_r, E);
  k_bucket<<<NB, 256, 0, stream>>>(a_cr, a_r, binBase, offs, deg, elist, N);
  k_dinv<<<(N + 255) / 256, 256, 0, stream>>>(deg, dinv, offs, N, E);
  k_norm<<<(N + 255) / 256, 256, 0, stream>>>(elist, offs, dinv, N);

  int ab = (N + 3) / 4;
  int gb = (N + 63) / 64;
  // layer 1: s1 = A~ @ xb -> d_out(bf16) ; a1 = tanh(s1@W1^T + b1) in-place
  k_agg<<<ab, 256, 0, stream>>>(xb, elist, offs, dinv, doutb, N);
  k_mgemm<1, 0><<<gb, 256, 0, stream>>>((const ushort_t*)doutb, whi1, wlo1, b1, nullptr, doutb, N);
  // layer 2: s2 = A~ @ a1 -> s2b ; out = s2@W2^T + b2 + xb(skip) -> d_out f32
  k_agg<<<ab, 256, 0, stream>>>(doutb, elist, offs, dinv, s2b, N);
  k_mgemm<0, 1><<<gb, 256, 0, stream>>>((const ushort_t*)s2b, whi2, wlo2, b2,
                                        (const ushort_t*)xb, d_out, N);
}

// Round 8
// 316.319 us; speedup vs baseline: 1.9444x; 1.0811x over previous
//
#include <hip/hip_runtime.h>
#include <hip/hip_bf16.h>
#include <math.h>

#define D 128
#define SCAN_T 256
#define EPB 4096          // edges per block for hist/scatter
#define MAXNB 800         // LDS histogram capacity (NB = ceil(N/128) = 782)

typedef unsigned long long ull;
typedef unsigned short ushort_t;
typedef __attribute__((ext_vector_type(8))) short bf16x8;
typedef __attribute__((ext_vector_type(4))) float f32x4;

__device__ __forceinline__ float bf_lo(unsigned u) { return __uint_as_float(u << 16); }
__device__ __forceinline__ float bf_hi(unsigned u) { return __uint_as_float(u & 0xffff0000u); }
__device__ __forceinline__ unsigned bpack(float a, float b) {  // RNE bf16x2
  unsigned ua = __float_as_uint(a), ub = __float_as_uint(b);
  ua += 0x7fff + ((ua >> 16) & 1);
  ub += 0x7fff + ((ub >> 16) & 1);
  return (ua >> 16) | (ub & 0xffff0000u);
}
__device__ __forceinline__ ushort_t bh16(float a) {  // RNE bf16
  unsigned ua = __float_as_uint(a);
  ua += 0x7fff + ((ua >> 16) & 1);
  return (ushort_t)(ua >> 16);
}

// ---- hist level-1 (col>>7) with LDS atomics; prep (x cast + W split) in tail blocks ----
__global__ __launch_bounds__(256) void k_h1(const int* __restrict__ col, int E, int B1, int B1pad,
                                            int* __restrict__ gh, int NB,
                                            const float2* __restrict__ x2, unsigned* __restrict__ xb, int n64,
                                            const float* __restrict__ W1, const float* __restrict__ W2,
                                            ushort_t* __restrict__ Whi1, ushort_t* __restrict__ Wlo1,
                                            ushort_t* __restrict__ Whi2, ushort_t* __restrict__ Wlo2) {
  int b = blockIdx.x, t = threadIdx.x;
  if (b < B1) {
    __shared__ int h[MAXNB];
    for (int i = t; i < NB; i += 256) h[i] = 0;
    __syncthreads();
    int e0 = b * EPB, e1 = min(E, e0 + EPB);
    for (int e = e0 + t; e < e1; e += 256) atomicAdd(&h[col[e] >> 7], 1);
    __syncthreads();
    for (int i = t; i < NB; i += 256) gh[i * B1pad + b] = h[i];
    return;
  }
  int idx = (b - B1) * 256 + t;
  if (idx < n64) { float2 v = x2[idx]; xb[idx] = bpack(v.x, v.y); return; }
  int j = idx - n64;
  if (j >= 2 * D * D) return;
  const float* W = (j < D * D) ? W1 : W2;
  ushort_t* Hh = (j < D * D) ? Whi1 : Whi2;
  ushort_t* Hl = (j < D * D) ? Wlo1 : Wlo2;
  int k = j & (D * D - 1);
  float w = W[k];
  ushort_t hh = bh16(w);
  Hh[k] = hh;
  Hl[k] = bh16(w - __uint_as_float((unsigned)hh << 16));
}

// ---- per-bin scan across blocks: gh[bin][b] -> exclusive prefix; binTotal[bin] = sum ----
__global__ __launch_bounds__(512) void k_hscan(int* __restrict__ gh, int* __restrict__ binTotal,
                                               int B1, int B1pad) {
  __shared__ int wsum[8];
  int bin = blockIdx.x, t = threadIdx.x;
  int v = (t < B1) ? gh[bin * B1pad + t] : 0;
  int lane = t & 63, wid = t >> 6;
  int x = v;
  #pragma unroll
  for (int d = 1; d < 64; d <<= 1) { int y = __shfl_up(x, d, 64); if (lane >= d) x += y; }
  if (lane == 63) wsum[wid] = x;
  __syncthreads();
  int woff = 0;
  for (int w = 0; w < wid; ++w) woff += wsum[w];
  if (t < B1) gh[bin * B1pad + t] = woff + x - v;
  if (t == 511) binTotal[bin] = woff + x;   // last lane of last wave: inclusive total
}

// ---------------- block exclusive scan helper (256 threads) ----------------
__device__ __forceinline__ int block_excl_scan(int v, int t, int* wsum, int* total) {
  int lane = t & 63, wid = t >> 6;
  int x = v;
  #pragma unroll
  for (int d = 1; d < 64; d <<= 1) {
    int y = __shfl_up(x, d, 64);
    if (lane >= d) x += y;
  }
  if (lane == 63) wsum[wid] = x;
  __syncthreads();
  int woff = 0;
  for (int w = 0; w < wid; ++w) woff += wsum[w];
  if (total) { int tot = 0; for (int w = 0; w < 4; ++w) tot += wsum[w]; *total = tot; }
  return woff + x - v;
}

// ---- scan binTotal -> binBase (+ sentinel) ----
__global__ __launch_bounds__(SCAN_T) void k_hscan2(const int* __restrict__ binTotal,
                                                   int* __restrict__ binBase, int NB) {
  __shared__ int wsum[4];
  int t = threadIdx.x;
  int base = t * 4;
  int v[4]; int s = 0;
  #pragma unroll
  for (int u = 0; u < 4; ++u) { v[u] = (base + u < NB) ? binTotal[base + u] : 0; s += v[u]; }
  int tot;
  int excl = block_excl_scan(s, t, wsum, &tot);
  int run = excl;
  #pragma unroll
  for (int u = 0; u < 4; ++u) { if (base + u < NB) binBase[base + u] = run; run += v[u]; }
  if (t == 0) binBase[NB] = tot;
}

// ---- scatter v2: LDS counting-sort per block, coalesced packed-ull output ----
// a_e[pos] = ((c<<15|q) << 32) | r, grouped by bucket within each block window
__global__ __launch_bounds__(256) void k_scatter(const int* __restrict__ row, const int* __restrict__ col,
                                                 const float* __restrict__ ew,
                                                 const int* __restrict__ gh, const int* __restrict__ binBase,
                                                 int B1pad, int NB,
                                                 ull* __restrict__ a_e, int E) {
  __shared__ ull recs[EPB];
  __shared__ int hist[MAXNB];   // becomes exclusive pfx in place
  __shared__ int cur[MAXNB];
  __shared__ int wb[MAXNB];
  __shared__ int wsum[4];
  int b = blockIdx.x, t = threadIdx.x;
  for (int i = t; i < NB; i += 256) { hist[i] = 0; cur[i] = 0; }
  __syncthreads();
  int e0 = b * EPB;
  int cnt = min(E - e0, EPB);
  ull v[16];
  #pragma unroll
  for (int k = 0; k < 16; ++k) {
    int idx = t + k * 256;
    v[k] = 0;
    if (idx < cnt) {
      int e = e0 + idx;
      int c = col[e];
      unsigned q = __float2uint_rn(ew[e] * 32767.0f);
      if (q > 32767u) q = 32767u;
      unsigned hi = ((unsigned)c << 15) | q;
      v[k] = ((ull)hi << 32) | (unsigned)row[e];
      atomicAdd(&hist[hi >> 22], 1);
    }
  }
  __syncthreads();
  // block scan of hist (NB <= 1024 = 256 threads x 4), in place -> exclusive pfx
  int base = t * 4;
  int hv[4];
  #pragma unroll
  for (int u = 0; u < 4; ++u) hv[u] = (base + u < NB) ? hist[base + u] : 0;
  int s = hv[0] + hv[1] + hv[2] + hv[3];
  int excl = block_excl_scan(s, t, wsum, nullptr);   // helper's barrier orders reads/writes
  int run = excl;
  #pragma unroll
  for (int u = 0; u < 4; ++u) {
    if (base + u < NB) {
      hist[base + u] = run;
      wb[base + u] = binBase[base + u] + gh[(base + u) * B1pad + b] - run;
    }
    run += hv[u];
  }
  __syncthreads();
  #pragma unroll
  for (int k = 0; k < 16; ++k) {
    if (t + k * 256 < cnt) {
      unsigned bkt = (unsigned)(v[k] >> 54);          // (c<<15|q)>>22 = c>>7
      int idx = hist[bkt] + atomicAdd(&cur[bkt], 1);
      recs[idx] = v[k];
    }
  }
  __syncthreads();
  for (int i = t; i < cnt; i += 256) {
    ull r = recs[i];
    a_e[wb[(unsigned)(r >> 54)] + i] = r;             // consecutive i -> consecutive addr per run
  }
}

// ---- level-2: per-bucket 128-bin counting sort; emits offs, deg, dest-sorted (r|ew) ----
__global__ __launch_bounds__(256) void k_bucket(const ull* __restrict__ a_e,
                                                const int* __restrict__ binBase,
                                                int* __restrict__ offs, float* __restrict__ deg,
                                                unsigned* __restrict__ sorted2, int N) {
  __shared__ int hist[128];
  __shared__ float wdeg[128];
  __shared__ int pfx[128];
  __shared__ int cur[128];
  int bin = blockIdx.x, t = threadIdx.x;
  if (t < 128) { hist[t] = 0; wdeg[t] = 0.f; cur[t] = 0; }
  __syncthreads();
  int s0 = binBase[bin], s1 = binBase[bin + 1];
  for (int i = s0 + t; i < s1; i += 256) {
    unsigned hi = (unsigned)(a_e[i] >> 32);
    int lc = (hi >> 15) & 127;
    atomicAdd(&hist[lc], 1);
    atomicAdd(&wdeg[lc], (float)(hi & 32767u) * (1.0f / 32767.0f));
  }
  __syncthreads();
  if (t == 0) { int run = 0; for (int i = 0; i < 128; ++i) { pfx[i] = run; run += hist[i]; } }
  __syncthreads();
  int c0 = bin << 7;
  if (t < 128 && c0 + t < N) { offs[c0 + t] = s0 + pfx[t]; deg[c0 + t] = wdeg[t]; }
  for (int i = s0 + t; i < s1; i += 256) {
    ull v = a_e[i];
    unsigned hi = (unsigned)(v >> 32);
    int lc = (hi >> 15) & 127;
    int pos = s0 + pfx[lc] + atomicAdd(&cur[lc], 1);
    sorted2[pos] = ((unsigned)v << 15) | (hi & 32767u);   // r<<15 | ew_q15
  }
}

// ---- dinv = rsqrt(deg+1); offs sentinel ----
__global__ void k_dinv(const float* __restrict__ deg, float* __restrict__ dinv,
                       int* __restrict__ offs, int N, int E) {
  int i = blockIdx.x * blockDim.x + threadIdx.x;
  if (i == 0) offs[N] = E;
  if (i < N) dinv[i] = rsqrtf(deg[i] + 1.0f);
}

// ---- rewrite ew -> norm = dinv[r]*ew*dinv[c] in place (q15) ----
__global__ void k_norm(unsigned* __restrict__ el, const int* __restrict__ offs,
                       const float* __restrict__ dinv, int N) {
  int c = blockIdx.x * blockDim.x + threadIdx.x;
  if (c >= N) return;
  int s0 = offs[c], s1 = offs[c + 1];
  float dc = dinv[c] * (1.0f / 32767.0f);
  for (int i = s0; i < s1; ++i) {
    unsigned v = el[i];
    unsigned r = v >> 15;
    float nrm = dinv[r] * (float)(v & 32767u) * dc;
    unsigned q = __float2uint_rn(nrm * 32767.0f);
    if (q > 32767u) q = 32767u;
    el[i] = (r << 15) | q;
  }
}

// ---- gather-aggregate: s[c] = sum_e norm*src[row] + dinv^2*src[c]  (bf16 in/out) ----
// wave per node; 4 edges in flight (16 lanes x uint4 = 256B row), 4-deep pipeline
__global__ __launch_bounds__(256) void k_agg(const unsigned* __restrict__ H2,
                                             const unsigned* __restrict__ elist,
                                             const int* __restrict__ offs, const float* __restrict__ dinv,
                                             unsigned* __restrict__ outb, int N) {
  int lane = threadIdx.x & 63;
  int c = blockIdx.x * 4 + (threadIdx.x >> 6);
  if (c >= N) return;
  int start = offs[c];
  int m = offs[c + 1] - start;
  int q = lane >> 4;            // edge slot 0..3
  int fi = lane & 15;           // uint4 index within row (features fi*8..fi*8+7)
  float a0 = 0.f, a1 = 0.f, a2 = 0.f, a3 = 0.f, a4 = 0.f, a5 = 0.f, a6 = 0.f, a7 = 0.f;
  for (int base = 0; base < m; base += 64) {
    int chunk = min(64, m - base);
    unsigned rec = (lane < chunk) ? elist[start + base + lane] : 0u;  // pad: row0, w=0
    int iters = (chunk + 3) >> 2;
    int i = 0;
    for (; i + 4 <= iters; i += 4) {
      unsigned e0 = __shfl(rec, 4 * i + q, 64);
      unsigned e1 = __shfl(rec, 4 * i + 4 + q, 64);
      unsigned e2 = __shfl(rec, 4 * i + 8 + q, 64);
      unsigned e3 = __shfl(rec, 4 * i + 12 + q, 64);
      uint4 u0 = *(const uint4*)&H2[(size_t)(e0 >> 15) * 64 + fi * 4];
      uint4 u1 = *(const uint4*)&H2[(size_t)(e1 >> 15) * 64 + fi * 4];
      uint4 u2 = *(const uint4*)&H2[(size_t)(e2 >> 15) * 64 + fi * 4];
      uint4 u3 = *(const uint4*)&H2[(size_t)(e3 >> 15) * 64 + fi * 4];
      float w0 = (float)(e0 & 0x7fffu) * (1.0f / 32767.0f);
      float w1 = (float)(e1 & 0x7fffu) * (1.0f / 32767.0f);
      float w2 = (float)(e2 & 0x7fffu) * (1.0f / 32767.0f);
      float w3 = (float)(e3 & 0x7fffu) * (1.0f / 32767.0f);
      a0 += w0 * bf_lo(u0.x); a1 += w0 * bf_hi(u0.x);
      a2 += w0 * bf_lo(u0.y); a3 += w0 * bf_hi(u0.y);
      a4 += w0 * bf_lo(u0.z); a5 += w0 * bf_hi(u0.z);
      a6 += w0 * bf_lo(u0.w); a7 += w0 * bf_hi(u0.w);
      a0 += w1 * bf_lo(u1.x); a1 += w1 * bf_hi(u1.x);
      a2 += w1 * bf_lo(u1.y); a3 += w1 * bf_hi(u1.y);
      a4 += w1 * bf_lo(u1.z); a5 += w1 * bf_hi(u1.z);
      a6 += w1 * bf_lo(u1.w); a7 += w1 * bf_hi(u1.w);
      a0 += w2 * bf_lo(u2.x); a1 += w2 * bf_hi(u2.x);
      a2 += w2 * bf_lo(u2.y); a3 += w2 * bf_hi(u2.y);
      a4 += w2 * bf_lo(u2.z); a5 += w2 * bf_hi(u2.z);
      a6 += w2 * bf_lo(u2.w); a7 += w2 * bf_hi(u2.w);
      a0 += w3 * bf_lo(u3.x); a1 += w3 * bf_hi(u3.x);
      a2 += w3 * bf_lo(u3.y); a3 += w3 * bf_hi(u3.y);
      a4 += w3 * bf_lo(u3.z); a5 += w3 * bf_hi(u3.z);
      a6 += w3 * bf_lo(u3.w); a7 += w3 * bf_hi(u3.w);
    }
    for (; i < iters; ++i) {
      unsigned e0 = __shfl(rec, 4 * i + q, 64);
      float w0 = (float)(e0 & 0x7fffu) * (1.0f / 32767.0f);
      uint4 u0 = *(const uint4*)&H2[(size_t)(e0 >> 15) * 64 + fi * 4];
      a0 += w0 * bf_lo(u0.x); a1 += w0 * bf_hi(u0.x);
      a2 += w0 * bf_lo(u0.y); a3 += w0 * bf_hi(u0.y);
      a4 += w0 * bf_lo(u0.z); a5 += w0 * bf_hi(u0.z);
      a6 += w0 * bf_lo(u0.w); a7 += w0 * bf_hi(u0.w);
    }
  }
  a0 += __shfl_xor(a0, 16, 64); a0 += __shfl_xor(a0, 32, 64);
  a1 += __shfl_xor(a1, 16, 64); a1 += __shfl_xor(a1, 32, 64);
  a2 += __shfl_xor(a2, 16, 64); a2 += __shfl_xor(a2, 32, 64);
  a3 += __shfl_xor(a3, 16, 64); a3 += __shfl_xor(a3, 32, 64);
  a4 += __shfl_xor(a4, 16, 64); a4 += __shfl_xor(a4, 32, 64);
  a5 += __shfl_xor(a5, 16, 64); a5 += __shfl_xor(a5, 32, 64);
  a6 += __shfl_xor(a6, 16, 64); a6 += __shfl_xor(a6, 32, 64);
  a7 += __shfl_xor(a7, 16, 64); a7 += __shfl_xor(a7, 32, 64);
  if (q == 0) {
    float dv = dinv[c], sw = dv * dv;
    uint4 us = *(const uint4*)&H2[(size_t)c * 64 + fi * 4];
    a0 += sw * bf_lo(us.x); a1 += sw * bf_hi(us.x);
    a2 += sw * bf_lo(us.y); a3 += sw * bf_hi(us.y);
    a4 += sw * bf_lo(us.z); a5 += sw * bf_hi(us.z);
    a6 += sw * bf_lo(us.w); a7 += sw * bf_hi(us.w);
    uint4 o;
    o.x = bpack(a0, a1); o.y = bpack(a2, a3); o.z = bpack(a4, a5); o.w = bpack(a6, a7);
    *(uint4*)&outb[(size_t)c * 64 + fi * 4] = o;
  }
}

// ---- MFMA GEMM + epilogue: out = S @ (Whi+Wlo)^T + bias [+tanh->bf16] [+skip(bf16)->f32] ----
// S row-major bf16 [n][128]. Wave computes 16 rows x 128 cols; no LDS.
template<int TANH, int SKIP>
__global__ __launch_bounds__(256) void k_mgemm(const ushort_t* __restrict__ S,
                                               const ushort_t* __restrict__ Whi,
                                               const ushort_t* __restrict__ Wlo,
                                               const float* __restrict__ bias,
                                               const ushort_t* __restrict__ skipb,
                                               void* __restrict__ outv, int n) {
  int wave = threadIdx.x >> 6, lane = threadIdx.x & 63;
  int r0 = blockIdx.x * 64 + wave * 16;
  if (r0 >= n) return;
  int cl = lane & 15;       // A-row offset / B-col offset / D-col offset
  int kg = lane >> 4;       // k-group 0..3
  int arow = r0 + cl; if (arow >= n) arow = n - 1;
  const ushort_t* srow = S + (size_t)arow * D + kg * 8;
  bf16x8 a[4];
  #pragma unroll
  for (int kt = 0; kt < 4; ++kt) a[kt] = *(const bf16x8*)(srow + kt * 32);

  #pragma unroll
  for (int j0 = 0; j0 < 8; ++j0) {
    int col = j0 * 16 + cl;
    const ushort_t* wh = Whi + (size_t)col * D + kg * 8;
    const ushort_t* wl = Wlo + (size_t)col * D + kg * 8;
    f32x4 acc = {0.f, 0.f, 0.f, 0.f};
    #pragma unroll
    for (int kt = 0; kt < 4; ++kt)
      acc = __builtin_amdgcn_mfma_f32_16x16x32_bf16(a[kt], *(const bf16x8*)(wh + kt * 32), acc, 0, 0, 0);
    #pragma unroll
    for (int kt = 0; kt < 4; ++kt)
      acc = __builtin_amdgcn_mfma_f32_16x16x32_bf16(a[kt], *(const bf16x8*)(wl + kt * 32), acc, 0, 0, 0);
    float bv = bias[col];
    #pragma unroll
    for (int i = 0; i < 4; ++i) {
      int r = r0 + kg * 4 + i;
      if (r < n) {
        float o = acc[i] + bv;
        if (TANH) {
          o = tanhf(o);
          ((ushort_t*)outv)[(size_t)r * D + col] = bh16(o);
        } else {
          if (SKIP) o += __uint_as_float((unsigned)skipb[(size_t)r * D + col] << 16);
          ((float*)outv)[(size_t)r * D + col] = o;
        }
      }
    }
  }
}

// ---------------- launch ----------------
extern "C" void kernel_launch(void* const* d_in, const int* in_sizes, int n_in,
                              void* d_out, int out_size, void* d_ws, size_t ws_size,
                              hipStream_t stream) {
  const int*   et = (const int*)d_in[0];
  const float* ef = (const float*)d_in[1];
  const float* x  = (const float*)d_in[2];
  const float* W1 = (const float*)d_in[3];
  const float* b1 = (const float*)d_in[4];
  const float* W2 = (const float*)d_in[5];
  const float* b2 = (const float*)d_in[6];

  int E = in_sizes[1];
  int N = in_sizes[2] / D;
  const int* row = et;
  const int* col = et + E;

  int NB = (N + 127) >> 7;            // 782 buckets of 128 nodes
  int B1 = (E + EPB - 1) / EPB;       // 391 edge blocks (must be <= 512 for k_hscan)
  int B1pad = (B1 + 7) & ~7;

  char* p = (char*)d_ws;
  auto alloc = [&](size_t bytes) { char* q = p; p += (bytes + 255) & ~(size_t)255; return q; };
  int*      gh       = (int*)     alloc((size_t)NB * B1pad * 4);  // ~1.25MB
  int*      binTotal = (int*)     alloc((size_t)NB * 4);
  int*      binBase  = (int*)     alloc((size_t)(NB + 1) * 4);
  ull*      a_e      = (ull*)     alloc((size_t)E * 8);           // packed (c<<15|q, r)
  unsigned* elist    = (unsigned*)alloc((size_t)E * 4);           // sorted2, rewritten in place
  int*      offs     = (int*)     alloc((size_t)(N + 1) * 4);
  float*    deg      = (float*)   alloc((size_t)N * 4);
  float*    dinv     = (float*)   alloc((size_t)N * 4);
  unsigned* xb       = (unsigned*)alloc((size_t)N * 64 * 4);      // bf16x2 x, live till end (skip)
  unsigned* s2b      = (unsigned*)alloc((size_t)N * 64 * 4);      // s2 bf16x2
  ushort_t* whi1 = (ushort_t*)alloc(D * D * 2);
  ushort_t* wlo1 = (ushort_t*)alloc(D * D * 2);
  ushort_t* whi2 = (ushort_t*)alloc(D * D * 2);
  ushort_t* wlo2 = (ushort_t*)alloc(D * D * 2);
  unsigned* doutb = (unsigned*)d_out;  // s1 / a1 (bf16) live in d_out, dead before final write

  int prepBlocks = (N * 64 + 2 * D * D + 255) / 256;
  k_h1<<<B1 + prepBlocks, 256, 0, stream>>>(col, E, B1, B1pad, gh, NB,
                                            (const float2*)x, xb, N * 64,
                                            W1, W2, whi1, wlo1, whi2, wlo2);
  k_hscan<<<NB, 512, 0, stream>>>(gh, binTotal, B1, B1pad);
  k_hscan2<<<1, SCAN_T, 0, stream>>>(binTotal, binBase, NB);
  k_scatter<<<B1, 256, 0, stream>>>(row, col, ef, gh, binBase, B1pad, NB, a_e, E);
  k_bucket<<<NB, 256, 0, stream>>>(a_e, binBase, offs, deg, elist, N);
  k_dinv<<<(N + 255) / 256, 256, 0, stream>>>(deg, dinv, offs, N, E);
  k_norm<<<(N + 255) / 256, 256, 0, stream>>>(elist, offs, dinv, N);

  int ab = (N + 3) / 4;
  int gb = (N + 63) / 64;
  // layer 1: s1 = A~ @ xb -> d_out(bf16) ; a1 = tanh(s1@W1^T + b1) in-place
  k_agg<<<ab, 256, 0, stream>>>(xb, elist, offs, dinv, doutb, N);
  k_mgemm<1, 0><<<gb, 256, 0, stream>>>((const ushort_t*)doutb, whi1, wlo1, b1, nullptr, doutb, N);
  // layer 2: s2 = A~ @ a1 -> s2b ; out = s2@W2^T + b2 + xb(skip) -> d_out f32
  k_agg<<<ab, 256, 0, stream>>>(doutb, elist, offs, dinv, s2b, N);
  k_mgemm<0, 1><<<gb, 256, 0, stream>>>((const ushort_t*)s2b, whi2, wlo2, b2,
                                        (const ushort_t*)xb, d_out, N);
}

// Round 9
// 259.504 us; speedup vs baseline: 2.3701x; 1.2189x over previous
//
#include <hip/hip_runtime.h>
#include <hip/hip_bf16.h>
#include <math.h>

#define D 128
#define SCAN_T 256
#define EPB 4096          // edges per block for hist/scatter
#define MAXNB 800         // LDS histogram capacity (NB = ceil(N/128) = 782)

typedef unsigned long long ull;
typedef unsigned short ushort_t;
typedef __attribute__((ext_vector_type(8))) short bf16x8;
typedef __attribute__((ext_vector_type(4))) float f32x4;

__device__ __forceinline__ float bf_lo(unsigned u) { return __uint_as_float(u << 16); }
__device__ __forceinline__ float bf_hi(unsigned u) { return __uint_as_float(u & 0xffff0000u); }
__device__ __forceinline__ unsigned bpack(float a, float b) {  // RNE bf16x2
  unsigned ua = __float_as_uint(a), ub = __float_as_uint(b);
  ua += 0x7fff + ((ua >> 16) & 1);
  ub += 0x7fff + ((ub >> 16) & 1);
  return (ua >> 16) | (ub & 0xffff0000u);
}
__device__ __forceinline__ ushort_t bh16(float a) {  // RNE bf16
  unsigned ua = __float_as_uint(a);
  ua += 0x7fff + ((ua >> 16) & 1);
  return (ushort_t)(ua >> 16);
}

// ---- hist level-1 (col>>7) with LDS atomics; prep (x cast + W split) in tail blocks ----
__global__ __launch_bounds__(256) void k_h1(const int* __restrict__ col, int E, int B1, int B1pad,
                                            int* __restrict__ gh, int NB,
                                            const float2* __restrict__ x2, unsigned* __restrict__ xb, int n64,
                                            const float* __restrict__ W1, const float* __restrict__ W2,
                                            ushort_t* __restrict__ Whi1, ushort_t* __restrict__ Wlo1,
                                            ushort_t* __restrict__ Whi2, ushort_t* __restrict__ Wlo2) {
  int b = blockIdx.x, t = threadIdx.x;
  if (b < B1) {
    __shared__ int h[MAXNB];
    for (int i = t; i < NB; i += 256) h[i] = 0;
    __syncthreads();
    int e0 = b * EPB, e1 = min(E, e0 + EPB);
    for (int e = e0 + t; e < e1; e += 256) atomicAdd(&h[col[e] >> 7], 1);
    __syncthreads();
    for (int i = t; i < NB; i += 256) gh[i * B1pad + b] = h[i];
    return;
  }
  int idx = (b - B1) * 256 + t;
  if (idx < n64) { float2 v = x2[idx]; xb[idx] = bpack(v.x, v.y); return; }
  int j = idx - n64;
  if (j >= 2 * D * D) return;
  const float* W = (j < D * D) ? W1 : W2;
  ushort_t* Hh = (j < D * D) ? Whi1 : Whi2;
  ushort_t* Hl = (j < D * D) ? Wlo1 : Wlo2;
  int k = j & (D * D - 1);
  float w = W[k];
  ushort_t hh = bh16(w);
  Hh[k] = hh;
  Hl[k] = bh16(w - __uint_as_float((unsigned)hh << 16));
}

// ---- per-bin scan across blocks: gh[bin][b] -> exclusive prefix; binTotal[bin] = sum ----
__global__ __launch_bounds__(512) void k_hscan(int* __restrict__ gh, int* __restrict__ binTotal,
                                               int B1, int B1pad) {
  __shared__ int wsum[8];
  int bin = blockIdx.x, t = threadIdx.x;
  int v = (t < B1) ? gh[bin * B1pad + t] : 0;
  int lane = t & 63, wid = t >> 6;
  int x = v;
  #pragma unroll
  for (int d = 1; d < 64; d <<= 1) { int y = __shfl_up(x, d, 64); if (lane >= d) x += y; }
  if (lane == 63) wsum[wid] = x;
  __syncthreads();
  int woff = 0;
  for (int w = 0; w < wid; ++w) woff += wsum[w];
  if (t < B1) gh[bin * B1pad + t] = woff + x - v;
  if (t == 511) binTotal[bin] = woff + x;   // last lane of last wave: inclusive total
}

// ---------------- block exclusive scan helper (256 threads) ----------------
__device__ __forceinline__ int block_excl_scan(int v, int t, int* wsum, int* total) {
  int lane = t & 63, wid = t >> 6;
  int x = v;
  #pragma unroll
  for (int d = 1; d < 64; d <<= 1) {
    int y = __shfl_up(x, d, 64);
    if (lane >= d) x += y;
  }
  if (lane == 63) wsum[wid] = x;
  __syncthreads();
  int woff = 0;
  for (int w = 0; w < wid; ++w) woff += wsum[w];
  if (total) { int tot = 0; for (int w = 0; w < 4; ++w) tot += wsum[w]; *total = tot; }
  return woff + x - v;
}

// ---- scan binTotal -> binBase (+ sentinel) ----
__global__ __launch_bounds__(SCAN_T) void k_hscan2(const int* __restrict__ binTotal,
                                                   int* __restrict__ binBase, int NB) {
  __shared__ int wsum[4];
  int t = threadIdx.x;
  int base = t * 4;
  int v[4]; int s = 0;
  #pragma unroll
  for (int u = 0; u < 4; ++u) { v[u] = (base + u < NB) ? binTotal[base + u] : 0; s += v[u]; }
  int tot;
  int excl = block_excl_scan(s, t, wsum, &tot);
  int run = excl;
  #pragma unroll
  for (int u = 0; u < 4; ++u) { if (base + u < NB) binBase[base + u] = run; run += v[u]; }
  if (t == 0) binBase[NB] = tot;
}

// ---- scatter v2: LDS counting-sort per block, coalesced packed-ull output ----
// a_e[pos] = ((c<<15|q) << 32) | r, grouped by bucket within each block window
__global__ __launch_bounds__(256) void k_scatter(const int* __restrict__ row, const int* __restrict__ col,
                                                 const float* __restrict__ ew,
                                                 const int* __restrict__ gh, const int* __restrict__ binBase,
                                                 int B1pad, int NB,
                                                 ull* __restrict__ a_e, int E) {
  __shared__ ull recs[EPB];
  __shared__ int hist[MAXNB];   // becomes exclusive pfx in place
  __shared__ int cur[MAXNB];
  __shared__ int wb[MAXNB];
  __shared__ int wsum[4];
  int b = blockIdx.x, t = threadIdx.x;
  for (int i = t; i < NB; i += 256) { hist[i] = 0; cur[i] = 0; }
  __syncthreads();
  int e0 = b * EPB;
  int cnt = min(E - e0, EPB);
  ull v[16];
  #pragma unroll
  for (int k = 0; k < 16; ++k) {
    int idx = t + k * 256;
    v[k] = 0;
    if (idx < cnt) {
      int e = e0 + idx;
      int c = col[e];
      unsigned q = __float2uint_rn(ew[e] * 32767.0f);
      if (q > 32767u) q = 32767u;
      unsigned hi = ((unsigned)c << 15) | q;
      v[k] = ((ull)hi << 32) | (unsigned)row[e];
      atomicAdd(&hist[hi >> 22], 1);
    }
  }
  __syncthreads();
  // block scan of hist (NB <= 1024 = 256 threads x 4), in place -> exclusive pfx
  int base = t * 4;
  int hv[4];
  #pragma unroll
  for (int u = 0; u < 4; ++u) hv[u] = (base + u < NB) ? hist[base + u] : 0;
  int s = hv[0] + hv[1] + hv[2] + hv[3];
  int excl = block_excl_scan(s, t, wsum, nullptr);   // helper's barrier orders reads/writes
  int run = excl;
  #pragma unroll
  for (int u = 0; u < 4; ++u) {
    if (base + u < NB) {
      hist[base + u] = run;
      wb[base + u] = binBase[base + u] + gh[(base + u) * B1pad + b] - run;
    }
    run += hv[u];
  }
  __syncthreads();
  #pragma unroll
  for (int k = 0; k < 16; ++k) {
    if (t + k * 256 < cnt) {
      unsigned bkt = (unsigned)(v[k] >> 54);          // (c<<15|q)>>22 = c>>7
      int idx = hist[bkt] + atomicAdd(&cur[bkt], 1);
      recs[idx] = v[k];
    }
  }
  __syncthreads();
  for (int i = t; i < cnt; i += 256) {
    ull r = recs[i];
    a_e[wb[(unsigned)(r >> 54)] + i] = r;             // consecutive i -> consecutive addr per run
  }
}

// ---- level-2: per-bucket 128-bin counting sort; emits offs, deg, dest-sorted (r|ew) ----
__global__ __launch_bounds__(256) void k_bucket(const ull* __restrict__ a_e,
                                                const int* __restrict__ binBase,
                                                int* __restrict__ offs, float* __restrict__ deg,
                                                unsigned* __restrict__ sorted2, int N) {
  __shared__ int hist[128];
  __shared__ float wdeg[128];
  __shared__ int pfx[128];
  __shared__ int cur[128];
  int bin = blockIdx.x, t = threadIdx.x;
  if (t < 128) { hist[t] = 0; wdeg[t] = 0.f; cur[t] = 0; }
  __syncthreads();
  int s0 = binBase[bin], s1 = binBase[bin + 1];
  for (int i = s0 + t; i < s1; i += 256) {
    unsigned hi = (unsigned)(a_e[i] >> 32);
    int lc = (hi >> 15) & 127;
    atomicAdd(&hist[lc], 1);
    atomicAdd(&wdeg[lc], (float)(hi & 32767u) * (1.0f / 32767.0f));
  }
  __syncthreads();
  if (t == 0) { int run = 0; for (int i = 0; i < 128; ++i) { pfx[i] = run; run += hist[i]; } }
  __syncthreads();
  int c0 = bin << 7;
  if (t < 128 && c0 + t < N) { offs[c0 + t] = s0 + pfx[t]; deg[c0 + t] = wdeg[t]; }
  for (int i = s0 + t; i < s1; i += 256) {
    ull v = a_e[i];
    unsigned hi = (unsigned)(v >> 32);
    int lc = (hi >> 15) & 127;
    int pos = s0 + pfx[lc] + atomicAdd(&cur[lc], 1);
    sorted2[pos] = ((unsigned)v << 15) | (hi & 32767u);   // r<<15 | ew_q15
  }
}

// ---- dinv = rsqrt(deg+1); offs sentinel ----
__global__ void k_dinv(const float* __restrict__ deg, float* __restrict__ dinv,
                       int* __restrict__ offs, int N, int E) {
  int i = blockIdx.x * blockDim.x + threadIdx.x;
  if (i == 0) offs[N] = E;
  if (i < N) dinv[i] = rsqrtf(deg[i] + 1.0f);
}

// ---- rewrite ew -> norm = dinv[r]*ew*dinv[c] in place (q15) ----
__global__ void k_norm(unsigned* __restrict__ el, const int* __restrict__ offs,
                       const float* __restrict__ dinv, int N) {
  int c = blockIdx.x * blockDim.x + threadIdx.x;
  if (c >= N) return;
  int s0 = offs[c], s1 = offs[c + 1];
  float dc = dinv[c] * (1.0f / 32767.0f);
  for (int i = s0; i < s1; ++i) {
    unsigned v = el[i];
    unsigned r = v >> 15;
    float nrm = dinv[r] * (float)(v & 32767u) * dc;
    unsigned q = __float2uint_rn(nrm * 32767.0f);
    if (q > 32767u) q = 32767u;
    el[i] = (r << 15) | q;
  }
}

// ---- gather-aggregate: s[c] = sum_e norm*src[row] + dinv^2*src[c]  (bf16 in/out) ----
// wave per node; 4 edges in flight (16 lanes x uint4 = 256B row), 4-deep pipeline
__global__ __launch_bounds__(256) void k_agg(const unsigned* __restrict__ H2,
                                             const unsigned* __restrict__ elist,
                                             const int* __restrict__ offs, const float* __restrict__ dinv,
                                             unsigned* __restrict__ outb, int N) {
  int lane = threadIdx.x & 63;
  int c = blockIdx.x * 4 + (threadIdx.x >> 6);
  if (c >= N) return;
  int start = offs[c];
  int m = offs[c + 1] - start;
  int q = lane >> 4;            // edge slot 0..3
  int fi = lane & 15;           // uint4 index within row (features fi*8..fi*8+7)
  float a0 = 0.f, a1 = 0.f, a2 = 0.f, a3 = 0.f, a4 = 0.f, a5 = 0.f, a6 = 0.f, a7 = 0.f;
  for (int base = 0; base < m; base += 64) {
    int chunk = min(64, m - base);
    unsigned rec = (lane < chunk) ? elist[start + base + lane] : 0u;  // pad: row0, w=0
    int iters = (chunk + 3) >> 2;
    int i = 0;
    for (; i + 4 <= iters; i += 4) {
      unsigned e0 = __shfl(rec, 4 * i + q, 64);
      unsigned e1 = __shfl(rec, 4 * i + 4 + q, 64);
      unsigned e2 = __shfl(rec, 4 * i + 8 + q, 64);
      unsigned e3 = __shfl(rec, 4 * i + 12 + q, 64);
      uint4 u0 = *(const uint4*)&H2[(size_t)(e0 >> 15) * 64 + fi * 4];
      uint4 u1 = *(const uint4*)&H2[(size_t)(e1 >> 15) * 64 + fi * 4];
      uint4 u2 = *(const uint4*)&H2[(size_t)(e2 >> 15) * 64 + fi * 4];
      uint4 u3 = *(const uint4*)&H2[(size_t)(e3 >> 15) * 64 + fi * 4];
      float w0 = (float)(e0 & 0x7fffu) * (1.0f / 32767.0f);
      float w1 = (float)(e1 & 0x7fffu) * (1.0f / 32767.0f);
      float w2 = (float)(e2 & 0x7fffu) * (1.0f / 32767.0f);
      float w3 = (float)(e3 & 0x7fffu) * (1.0f / 32767.0f);
      a0 += w0 * bf_lo(u0.x); a1 += w0 * bf_hi(u0.x);
      a2 += w0 * bf_lo(u0.y); a3 += w0 * bf_hi(u0.y);
      a4 += w0 * bf_lo(u0.z); a5 += w0 * bf_hi(u0.z);
      a6 += w0 * bf_lo(u0.w); a7 += w0 * bf_hi(u0.w);
      a0 += w1 * bf_lo(u1.x); a1 += w1 * bf_hi(u1.x);
      a2 += w1 * bf_lo(u1.y); a3 += w1 * bf_hi(u1.y);
      a4 += w1 * bf_lo(u1.z); a5 += w1 * bf_hi(u1.z);
      a6 += w1 * bf_lo(u1.w); a7 += w1 * bf_hi(u1.w);
      a0 += w2 * bf_lo(u2.x); a1 += w2 * bf_hi(u2.x);
      a2 += w2 * bf_lo(u2.y); a3 += w2 * bf_hi(u2.y);
      a4 += w2 * bf_lo(u2.z); a5 += w2 * bf_hi(u2.z);
      a6 += w2 * bf_lo(u2.w); a7 += w2 * bf_hi(u2.w);
      a0 += w3 * bf_lo(u3.x); a1 += w3 * bf_hi(u3.x);
      a2 += w3 * bf_lo(u3.y); a3 += w3 * bf_hi(u3.y);
      a4 += w3 * bf_lo(u3.z); a5 += w3 * bf_hi(u3.z);
      a6 += w3 * bf_lo(u3.w); a7 += w3 * bf_hi(u3.w);
    }
    for (; i < iters; ++i) {
      unsigned e0 = __shfl(rec, 4 * i + q, 64);
      float w0 = (float)(e0 & 0x7fffu) * (1.0f / 32767.0f);
      uint4 u0 = *(const uint4*)&H2[(size_t)(e0 >> 15) * 64 + fi * 4];
      a0 += w0 * bf_lo(u0.x); a1 += w0 * bf_hi(u0.x);
      a2 += w0 * bf_lo(u0.y); a3 += w0 * bf_hi(u0.y);
      a4 += w0 * bf_lo(u0.z); a5 += w0 * bf_hi(u0.z);
      a6 += w0 * bf_lo(u0.w); a7 += w0 * bf_hi(u0.w);
    }
  }
  a0 += __shfl_xor(a0, 16, 64); a0 += __shfl_xor(a0, 32, 64);
  a1 += __shfl_xor(a1, 16, 64); a1 += __shfl_xor(a1, 32, 64);
  a2 += __shfl_xor(a2, 16, 64); a2 += __shfl_xor(a2, 32, 64);
  a3 += __shfl_xor(a3, 16, 64); a3 += __shfl_xor(a3, 32, 64);
  a4 += __shfl_xor(a4, 16, 64); a4 += __shfl_xor(a4, 32, 64);
  a5 += __shfl_xor(a5, 16, 64); a5 += __shfl_xor(a5, 32, 64);
  a6 += __shfl_xor(a6, 16, 64); a6 += __shfl_xor(a6, 32, 64);
  a7 += __shfl_xor(a7, 16, 64); a7 += __shfl_xor(a7, 32, 64);
  if (q == 0) {
    float dv = dinv[c], sw = dv * dv;
    uint4 us = *(const uint4*)&H2[(size_t)c * 64 + fi * 4];
    a0 += sw * bf_lo(us.x); a1 += sw * bf_hi(us.x);
    a2 += sw * bf_lo(us.y); a3 += sw * bf_hi(us.y);
    a4 += sw * bf_lo(us.z); a5 += sw * bf_hi(us.z);
    a6 += sw * bf_lo(us.w); a7 += sw * bf_hi(us.w);
    uint4 o;
    o.x = bpack(a0, a1); o.y = bpack(a2, a3); o.z = bpack(a4, a5); o.w = bpack(a6, a7);
    *(uint4*)&outb[(size_t)c * 64 + fi * 4] = o;
  }
}

// ---- MFMA GEMM v2: B (hi+lo) resident in registers, rows streamed ----
// block = 4 waves; wave w owns cols [32w, 32w+32); grid-stride over 16-row tiles.
template<int TANH, int SKIP>
__global__ __launch_bounds__(256) void k_mgemm(const ushort_t* __restrict__ S,
                                               const ushort_t* __restrict__ Whi,
                                               const ushort_t* __restrict__ Wlo,
                                               const float* __restrict__ bias,
                                               const ushort_t* __restrict__ skipb,
                                               void* __restrict__ outv, int n) {
  int wave = threadIdx.x >> 6, lane = threadIdx.x & 63;
  int cl = lane & 15;       // A-row offset / B-col offset / D-col offset
  int kg = lane >> 4;       // k-group 0..3
  int cb0 = wave * 2;       // this wave's two 16-col blocks

  bf16x8 bh[2][4], bl[2][4];
  float bv[2];
  #pragma unroll
  for (int c = 0; c < 2; ++c) {
    int col = (cb0 + c) * 16 + cl;
    const ushort_t* wh = Whi + (size_t)col * D + kg * 8;
    const ushort_t* wl = Wlo + (size_t)col * D + kg * 8;
    #pragma unroll
    for (int kt = 0; kt < 4; ++kt) {
      bh[c][kt] = *(const bf16x8*)(wh + kt * 32);
      bl[c][kt] = *(const bf16x8*)(wl + kt * 32);
    }
    bv[c] = bias[col];
  }

  int ntiles = (n + 15) >> 4;
  for (int t = blockIdx.x; t < ntiles; t += gridDim.x) {
    int arow = t * 16 + cl; if (arow >= n) arow = n - 1;
    const ushort_t* srow = S + (size_t)arow * D + kg * 8;
    bf16x8 a[4];
    #pragma unroll
    for (int kt = 0; kt < 4; ++kt) a[kt] = *(const bf16x8*)(srow + kt * 32);
    #pragma unroll
    for (int c = 0; c < 2; ++c) {
      f32x4 acc = {0.f, 0.f, 0.f, 0.f};
      #pragma unroll
      for (int kt = 0; kt < 4; ++kt)
        acc = __builtin_amdgcn_mfma_f32_16x16x32_bf16(a[kt], bh[c][kt], acc, 0, 0, 0);
      #pragma unroll
      for (int kt = 0; kt < 4; ++kt)
        acc = __builtin_amdgcn_mfma_f32_16x16x32_bf16(a[kt], bl[c][kt], acc, 0, 0, 0);
      int col = (cb0 + c) * 16 + cl;
      #pragma unroll
      for (int i = 0; i < 4; ++i) {
        int r = t * 16 + kg * 4 + i;
        if (r < n) {
          float o = acc[i] + bv[c];
          if (TANH) {
            o = tanhf(o);
            ((ushort_t*)outv)[(size_t)r * D + col] = bh16(o);
          } else {
            if (SKIP) o += __uint_as_float((unsigned)skipb[(size_t)r * D + col] << 16);
            ((float*)outv)[(size_t)r * D + col] = o;
          }
        }
      }
    }
  }
}

// ---------------- launch ----------------
extern "C" void kernel_launch(void* const* d_in, const int* in_sizes, int n_in,
                              void* d_out, int out_size, void* d_ws, size_t ws_size,
                              hipStream_t stream) {
  const int*   et = (const int*)d_in[0];
  const float* ef = (const float*)d_in[1];
  const float* x  = (const float*)d_in[2];
  const float* W1 = (const float*)d_in[3];
  const float* b1 = (const float*)d_in[4];
  const float* W2 = (const float*)d_in[5];
  const float* b2 = (const float*)d_in[6];

  int E = in_sizes[1];
  int N = in_sizes[2] / D;
  const int* row = et;
  const int* col = et + E;

  int NB = (N + 127) >> 7;            // 782 buckets of 128 nodes
  int B1 = (E + EPB - 1) / EPB;       // 391 edge blocks (must be <= 512 for k_hscan)
  int B1pad = (B1 + 7) & ~7;

  char* p = (char*)d_ws;
  auto alloc = [&](size_t bytes) { char* q = p; p += (bytes + 255) & ~(size_t)255; return q; };
  int*      gh       = (int*)     alloc((size_t)NB * B1pad * 4);  // ~1.25MB
  int*      binTotal = (int*)     alloc((size_t)NB * 4);
  int*      binBase  = (int*)     alloc((size_t)(NB + 1) * 4);
  ull*      a_e      = (ull*)     alloc((size_t)E * 8);           // packed (c<<15|q, r)
  unsigned* elist    = (unsigned*)alloc((size_t)E * 4);           // sorted2, rewritten in place
  int*      offs     = (int*)     alloc((size_t)(N + 1) * 4);
  float*    deg      = (float*)   alloc((size_t)N * 4);
  float*    dinv     = (float*)   alloc((size_t)N * 4);
  unsigned* xb       = (unsigned*)alloc((size_t)N * 64 * 4);      // bf16x2 x, live till end (skip)
  unsigned* s2b      = (unsigned*)alloc((size_t)N * 64 * 4);      // s2 bf16x2
  ushort_t* whi1 = (ushort_t*)alloc(D * D * 2);
  ushort_t* wlo1 = (ushort_t*)alloc(D * D * 2);
  ushort_t* whi2 = (ushort_t*)alloc(D * D * 2);
  ushort_t* wlo2 = (ushort_t*)alloc(D * D * 2);
  unsigned* doutb = (unsigned*)d_out;  // s1 / a1 (bf16) live in d_out, dead before final write

  int prepBlocks = (N * 64 + 2 * D * D + 255) / 256;
  k_h1<<<B1 + prepBlocks, 256, 0, stream>>>(col, E, B1, B1pad, gh, NB,
                                            (const float2*)x, xb, N * 64,
                                            W1, W2, whi1, wlo1, whi2, wlo2);
  k_hscan<<<NB, 512, 0, stream>>>(gh, binTotal, B1, B1pad);
  k_hscan2<<<1, SCAN_T, 0, stream>>>(binTotal, binBase, NB);
  k_scatter<<<B1, 256, 0, stream>>>(row, col, ef, gh, binBase, B1pad, NB, a_e, E);
  k_bucket<<<NB, 256, 0, stream>>>(a_e, binBase, offs, deg, elist, N);
  k_dinv<<<(N + 255) / 256, 256, 0, stream>>>(deg, dinv, offs, N, E);
  k_norm<<<(N + 255) / 256, 256, 0, stream>>>(elist, offs, dinv, N);

  int ab = (N + 3) / 4;
  int gb = 1024;   // grid-stride row tiles; ~6 tiles/block amortizes B-frag load
  // layer 1: s1 = A~ @ xb -> d_out(bf16) ; a1 = tanh(s1@W1^T + b1) in-place
  k_agg<<<ab, 256, 0, stream>>>(xb, elist, offs, dinv, doutb, N);
  k_mgemm<1, 0><<<gb, 256, 0, stream>>>((const ushort_t*)doutb, whi1, wlo1, b1, nullptr, doutb, N);
  // layer 2: s2 = A~ @ a1 -> s2b ; out = s2@W2^T + b2 + xb(skip) -> d_out f32
  k_agg<<<ab, 256, 0, stream>>>(doutb, elist, offs, dinv, s2b, N);
  k_mgemm<0, 1><<<gb, 256, 0, stream>>>((const ushort_t*)s2b, whi2, wlo2, b2,
                                        (const ushort_t*)xb, d_out, N);
}

// Round 10
// 258.031 us; speedup vs baseline: 2.3836x; 1.0057x over previous
//
#include <hip/hip_runtime.h>
#include <math.h>

#define D 128
#define SCAN_T 256
#define EPB 4096          // edges per block for hist/scatter
#define MAXNB 800         // LDS histogram capacity (NB = ceil(N/128) = 782)

typedef unsigned long long ull;
typedef unsigned short ushort_t;
typedef _Float16 f16;
typedef __attribute__((ext_vector_type(2))) _Float16 f16x2;
typedef __attribute__((ext_vector_type(8))) _Float16 f16x8;
typedef __attribute__((ext_vector_type(4))) float f32x4;

__device__ __forceinline__ ushort_t f16b(float x) { f16 h = (f16)x; return __builtin_bit_cast(ushort_t, h); }
__device__ __forceinline__ unsigned packh2(float a, float b) {
  f16x2 v = {(f16)a, (f16)b};
  return __builtin_bit_cast(unsigned, v);
}
__device__ __forceinline__ f16x2 bch2(unsigned u) { return __builtin_bit_cast(f16x2, u); }

// ---- hist level-1 (col>>7) with LDS atomics; prep (x cast + W f16 cast) in tail blocks ----
__global__ __launch_bounds__(256) void k_h1(const int* __restrict__ col, int E, int B1, int B1pad,
                                            int* __restrict__ gh, int NB,
                                            const float2* __restrict__ x2, unsigned* __restrict__ xb, int n64,
                                            const float* __restrict__ W1, const float* __restrict__ W2,
                                            ushort_t* __restrict__ Wf1, ushort_t* __restrict__ Wf2) {
  int b = blockIdx.x, t = threadIdx.x;
  if (b < B1) {
    __shared__ int h[MAXNB];
    for (int i = t; i < NB; i += 256) h[i] = 0;
    __syncthreads();
    int e0 = b * EPB, e1 = min(E, e0 + EPB);
    for (int e = e0 + t; e < e1; e += 256) atomicAdd(&h[col[e] >> 7], 1);
    __syncthreads();
    for (int i = t; i < NB; i += 256) gh[i * B1pad + b] = h[i];
    return;
  }
  int idx = (b - B1) * 256 + t;
  if (idx < n64) { float2 v = x2[idx]; xb[idx] = packh2(v.x, v.y); return; }
  int j = idx - n64;
  if (j >= 2 * D * D) return;
  const float* W = (j < D * D) ? W1 : W2;
  ushort_t* Wd = (j < D * D) ? Wf1 : Wf2;
  int k = j & (D * D - 1);
  Wd[k] = f16b(W[k]);
}

// ---- per-bin scan across blocks: gh[bin][b] -> exclusive prefix; binTotal[bin] = sum ----
__global__ __launch_bounds__(512) void k_hscan(int* __restrict__ gh, int* __restrict__ binTotal,
                                               int B1, int B1pad) {
  __shared__ int wsum[8];
  int bin = blockIdx.x, t = threadIdx.x;
  int v = (t < B1) ? gh[bin * B1pad + t] : 0;
  int lane = t & 63, wid = t >> 6;
  int x = v;
  #pragma unroll
  for (int d = 1; d < 64; d <<= 1) { int y = __shfl_up(x, d, 64); if (lane >= d) x += y; }
  if (lane == 63) wsum[wid] = x;
  __syncthreads();
  int woff = 0;
  for (int w = 0; w < wid; ++w) woff += wsum[w];
  if (t < B1) gh[bin * B1pad + t] = woff + x - v;
  if (t == 511) binTotal[bin] = woff + x;   // last lane of last wave: inclusive total
}

// ---------------- block exclusive scan helper (256 threads) ----------------
__device__ __forceinline__ int block_excl_scan(int v, int t, int* wsum, int* total) {
  int lane = t & 63, wid = t >> 6;
  int x = v;
  #pragma unroll
  for (int d = 1; d < 64; d <<= 1) {
    int y = __shfl_up(x, d, 64);
    if (lane >= d) x += y;
  }
  if (lane == 63) wsum[wid] = x;
  __syncthreads();
  int woff = 0;
  for (int w = 0; w < wid; ++w) woff += wsum[w];
  if (total) { int tot = 0; for (int w = 0; w < 4; ++w) tot += wsum[w]; *total = tot; }
  return woff + x - v;
}

// ---- scan binTotal -> binBase (+ sentinel) ----
__global__ __launch_bounds__(SCAN_T) void k_hscan2(const int* __restrict__ binTotal,
                                                   int* __restrict__ binBase, int NB) {
  __shared__ int wsum[4];
  int t = threadIdx.x;
  int base = t * 4;
  int v[4]; int s = 0;
  #pragma unroll
  for (int u = 0; u < 4; ++u) { v[u] = (base + u < NB) ? binTotal[base + u] : 0; s += v[u]; }
  int tot;
  int excl = block_excl_scan(s, t, wsum, &tot);
  int run = excl;
  #pragma unroll
  for (int u = 0; u < 4; ++u) { if (base + u < NB) binBase[base + u] = run; run += v[u]; }
  if (t == 0) binBase[NB] = tot;
}

// ---- scatter: LDS counting-sort per block, coalesced packed-ull output ----
__global__ __launch_bounds__(256) void k_scatter(const int* __restrict__ row, const int* __restrict__ col,
                                                 const float* __restrict__ ew,
                                                 const int* __restrict__ gh, const int* __restrict__ binBase,
                                                 int B1pad, int NB,
                                                 ull* __restrict__ a_e, int E) {
  __shared__ ull recs[EPB];
  __shared__ int hist[MAXNB];   // becomes exclusive pfx in place
  __shared__ int cur[MAXNB];
  __shared__ int wb[MAXNB];
  __shared__ int wsum[4];
  int b = blockIdx.x, t = threadIdx.x;
  for (int i = t; i < NB; i += 256) { hist[i] = 0; cur[i] = 0; }
  __syncthreads();
  int e0 = b * EPB;
  int cnt = min(E - e0, EPB);
  ull v[16];
  #pragma unroll
  for (int k = 0; k < 16; ++k) {
    int idx = t + k * 256;
    v[k] = 0;
    if (idx < cnt) {
      int e = e0 + idx;
      int c = col[e];
      unsigned q = __float2uint_rn(ew[e] * 32767.0f);
      if (q > 32767u) q = 32767u;
      unsigned hi = ((unsigned)c << 15) | q;
      v[k] = ((ull)hi << 32) | (unsigned)row[e];
      atomicAdd(&hist[hi >> 22], 1);
    }
  }
  __syncthreads();
  int base = t * 4;
  int hv[4];
  #pragma unroll
  for (int u = 0; u < 4; ++u) hv[u] = (base + u < NB) ? hist[base + u] : 0;
  int s = hv[0] + hv[1] + hv[2] + hv[3];
  int excl = block_excl_scan(s, t, wsum, nullptr);
  int run = excl;
  #pragma unroll
  for (int u = 0; u < 4; ++u) {
    if (base + u < NB) {
      hist[base + u] = run;
      wb[base + u] = binBase[base + u] + gh[(base + u) * B1pad + b] - run;
    }
    run += hv[u];
  }
  __syncthreads();
  #pragma unroll
  for (int k = 0; k < 16; ++k) {
    if (t + k * 256 < cnt) {
      unsigned bkt = (unsigned)(v[k] >> 54);
      int idx = hist[bkt] + atomicAdd(&cur[bkt], 1);
      recs[idx] = v[k];
    }
  }
  __syncthreads();
  for (int i = t; i < cnt; i += 256) {
    ull r = recs[i];
    a_e[wb[(unsigned)(r >> 54)] + i] = r;
  }
}

// ---- level-2: per-bucket 128-bin counting sort; emits offs, deg, dest-sorted (r|ew) ----
__global__ __launch_bounds__(256) void k_bucket(const ull* __restrict__ a_e,
                                                const int* __restrict__ binBase,
                                                int* __restrict__ offs, float* __restrict__ deg,
                                                unsigned* __restrict__ sorted2, int N) {
  __shared__ int hist[128];
  __shared__ float wdeg[128];
  __shared__ int pfx[128];
  __shared__ int cur[128];
  int bin = blockIdx.x, t = threadIdx.x;
  if (t < 128) { hist[t] = 0; wdeg[t] = 0.f; cur[t] = 0; }
  __syncthreads();
  int s0 = binBase[bin], s1 = binBase[bin + 1];
  for (int i = s0 + t; i < s1; i += 256) {
    unsigned hi = (unsigned)(a_e[i] >> 32);
    int lc = (hi >> 15) & 127;
    atomicAdd(&hist[lc], 1);
    atomicAdd(&wdeg[lc], (float)(hi & 32767u) * (1.0f / 32767.0f));
  }
  __syncthreads();
  if (t == 0) { int run = 0; for (int i = 0; i < 128; ++i) { pfx[i] = run; run += hist[i]; } }
  __syncthreads();
  int c0 = bin << 7;
  if (t < 128 && c0 + t < N) { offs[c0 + t] = s0 + pfx[t]; deg[c0 + t] = wdeg[t]; }
  for (int i = s0 + t; i < s1; i += 256) {
    ull v = a_e[i];
    unsigned hi = (unsigned)(v >> 32);
    int lc = (hi >> 15) & 127;
    int pos = s0 + pfx[lc] + atomicAdd(&cur[lc], 1);
    sorted2[pos] = ((unsigned)v << 15) | (hi & 32767u);   // r<<15 | ew_q15
  }
}

// ---- dinv = rsqrt(deg+1); offs sentinel ----
__global__ void k_dinv(const float* __restrict__ deg, float* __restrict__ dinv,
                       int* __restrict__ offs, int N, int E) {
  int i = blockIdx.x * blockDim.x + threadIdx.x;
  if (i == 0) offs[N] = E;
  if (i < N) dinv[i] = rsqrtf(deg[i] + 1.0f);
}

// ---- split: rows[] u32 + normp[] (f16 norm duplicated in both halves) ----
__global__ void k_norm(const unsigned* __restrict__ el, const int* __restrict__ offs,
                       const float* __restrict__ dinv,
                       unsigned* __restrict__ rows, unsigned* __restrict__ normp, int N) {
  int c = blockIdx.x * blockDim.x + threadIdx.x;
  if (c >= N) return;
  int s0 = offs[c], s1 = offs[c + 1];
  float dc = dinv[c] * (1.0f / 32767.0f);
  for (int i = s0; i < s1; ++i) {
    unsigned v = el[i];
    unsigned r = v >> 15;
    float nrm = dinv[r] * (float)(v & 32767u) * dc;
    rows[i] = r;
    normp[i] = (unsigned)f16b(nrm) * 0x10001u;
  }
}

// ---- gather-aggregate: group(16 lanes)-per-node, f16 pk_fma, fold to f32 every 4 edges ----
__global__ __launch_bounds__(256) void k_agg(const uint4* __restrict__ H4,
                                             const unsigned* __restrict__ rows,
                                             const unsigned* __restrict__ normp,
                                             const int* __restrict__ offs, const float* __restrict__ dinv,
                                             uint4* __restrict__ out4, int N) {
  int t = threadIdx.x;
  int fl = t & 15;             // uint4 slot within 256B row
  int g = t >> 4;              // group in block (0..15)
  int sb = ((t & 63) >> 4) * 16;  // shfl base lane of this group within wave
  int c = blockIdx.x * 16 + g;
  if (c >= N) return;
  int start = offs[c];
  int m = offs[c + 1] - start;
  float a0=0.f,a1=0.f,a2=0.f,a3=0.f,a4=0.f,a5=0.f,a6=0.f,a7=0.f;
  f16x2 p0={0,0}, p1={0,0}, p2={0,0}, p3={0,0};
  for (int eb = 0; eb < m; eb += 16) {
    int chunk = min(16, m - eb);
    unsigned rr = 0, wwp = 0;
    if (fl < chunk) { rr = rows[start + eb + fl]; wwp = normp[start + eb + fl]; }
    int j = 0;
    for (; j + 4 <= chunk; j += 4) {
      unsigned r0 = __shfl(rr, sb + j, 64);     unsigned w0 = __shfl(wwp, sb + j, 64);
      unsigned r1 = __shfl(rr, sb + j + 1, 64); unsigned w1 = __shfl(wwp, sb + j + 1, 64);
      unsigned r2 = __shfl(rr, sb + j + 2, 64); unsigned w2 = __shfl(wwp, sb + j + 2, 64);
      unsigned r3 = __shfl(rr, sb + j + 3, 64); unsigned w3 = __shfl(wwp, sb + j + 3, 64);
      uint4 u0 = H4[(size_t)r0 * 16 + fl];
      uint4 u1 = H4[(size_t)r1 * 16 + fl];
      uint4 u2 = H4[(size_t)r2 * 16 + fl];
      uint4 u3 = H4[(size_t)r3 * 16 + fl];
      f16x2 wv0 = bch2(w0), wv1 = bch2(w1), wv2 = bch2(w2), wv3 = bch2(w3);
      p0 += bch2(u0.x) * wv0; p1 += bch2(u0.y) * wv0; p2 += bch2(u0.z) * wv0; p3 += bch2(u0.w) * wv0;
      p0 += bch2(u1.x) * wv1; p1 += bch2(u1.y) * wv1; p2 += bch2(u1.z) * wv1; p3 += bch2(u1.w) * wv1;
      p0 += bch2(u2.x) * wv2; p1 += bch2(u2.y) * wv2; p2 += bch2(u2.z) * wv2; p3 += bch2(u2.w) * wv2;
      p0 += bch2(u3.x) * wv3; p1 += bch2(u3.y) * wv3; p2 += bch2(u3.z) * wv3; p3 += bch2(u3.w) * wv3;
      a0 += (float)p0[0]; a1 += (float)p0[1];
      a2 += (float)p1[0]; a3 += (float)p1[1];
      a4 += (float)p2[0]; a5 += (float)p2[1];
      a6 += (float)p3[0]; a7 += (float)p3[1];
      p0 = (f16x2){0,0}; p1 = (f16x2){0,0}; p2 = (f16x2){0,0}; p3 = (f16x2){0,0};
    }
    for (; j < chunk; ++j) {
      unsigned r0 = __shfl(rr, sb + j, 64); unsigned w0 = __shfl(wwp, sb + j, 64);
      uint4 u0 = H4[(size_t)r0 * 16 + fl];
      f16x2 wv0 = bch2(w0);
      p0 += bch2(u0.x) * wv0; p1 += bch2(u0.y) * wv0; p2 += bch2(u0.z) * wv0; p3 += bch2(u0.w) * wv0;
    }
    a0 += (float)p0[0]; a1 += (float)p0[1];
    a2 += (float)p1[0]; a3 += (float)p1[1];
    a4 += (float)p2[0]; a5 += (float)p2[1];
    a6 += (float)p3[0]; a7 += (float)p3[1];
    p0 = (f16x2){0,0}; p1 = (f16x2){0,0}; p2 = (f16x2){0,0}; p3 = (f16x2){0,0};
  }
  float dv = dinv[c], sw = dv * dv;
  uint4 us = H4[(size_t)c * 16 + fl];
  f16x2 h0 = bch2(us.x), h1 = bch2(us.y), h2 = bch2(us.z), h3 = bch2(us.w);
  a0 += sw * (float)h0[0]; a1 += sw * (float)h0[1];
  a2 += sw * (float)h1[0]; a3 += sw * (float)h1[1];
  a4 += sw * (float)h2[0]; a5 += sw * (float)h2[1];
  a6 += sw * (float)h3[0]; a7 += sw * (float)h3[1];
  uint4 o;
  o.x = packh2(a0, a1); o.y = packh2(a2, a3); o.z = packh2(a4, a5); o.w = packh2(a6, a7);
  out4[(size_t)c * 16 + fl] = o;
}

// ---- MFMA GEMM (f16, single W): B in registers, rows streamed ----
template<int TANH, int SKIP>
__global__ __launch_bounds__(256) void k_mgemm(const ushort_t* __restrict__ S,
                                               const ushort_t* __restrict__ Wf,
                                               const float* __restrict__ bias,
                                               const ushort_t* __restrict__ skipb,
                                               void* __restrict__ outv, int n) {
  int wave = threadIdx.x >> 6, lane = threadIdx.x & 63;
  int cl = lane & 15;
  int kg = lane >> 4;
  int cb0 = wave * 2;

  f16x8 bfr[2][4];
  float bv[2];
  #pragma unroll
  for (int c = 0; c < 2; ++c) {
    int col = (cb0 + c) * 16 + cl;
    const ushort_t* wp = Wf + (size_t)col * D + kg * 8;
    #pragma unroll
    for (int kt = 0; kt < 4; ++kt) bfr[c][kt] = *(const f16x8*)(wp + kt * 32);
    bv[c] = bias[col];
  }

  int ntiles = (n + 15) >> 4;
  for (int t = blockIdx.x; t < ntiles; t += gridDim.x) {
    int arow = t * 16 + cl; if (arow >= n) arow = n - 1;
    const ushort_t* srow = S + (size_t)arow * D + kg * 8;
    f16x8 a[4];
    #pragma unroll
    for (int kt = 0; kt < 4; ++kt) a[kt] = *(const f16x8*)(srow + kt * 32);
    #pragma unroll
    for (int c = 0; c < 2; ++c) {
      f32x4 acc = {0.f, 0.f, 0.f, 0.f};
      #pragma unroll
      for (int kt = 0; kt < 4; ++kt)
        acc = __builtin_amdgcn_mfma_f32_16x16x32_f16(a[kt], bfr[c][kt], acc, 0, 0, 0);
      int col = (cb0 + c) * 16 + cl;
      #pragma unroll
      for (int i = 0; i < 4; ++i) {
        int r = t * 16 + kg * 4 + i;
        if (r < n) {
          float o = acc[i] + bv[c];
          if (TANH) {
            o = tanhf(o);
            ((ushort_t*)outv)[(size_t)r * D + col] = f16b(o);
          } else {
            if (SKIP) o += (float)((const f16*)skipb)[(size_t)r * D + col];
            ((float*)outv)[(size_t)r * D + col] = o;
          }
        }
      }
    }
  }
}

// ---------------- launch ----------------
extern "C" void kernel_launch(void* const* d_in, const int* in_sizes, int n_in,
                              void* d_out, int out_size, void* d_ws, size_t ws_size,
                              hipStream_t stream) {
  const int*   et = (const int*)d_in[0];
  const float* ef = (const float*)d_in[1];
  const float* x  = (const float*)d_in[2];
  const float* W1 = (const float*)d_in[3];
  const float* b1 = (const float*)d_in[4];
  const float* W2 = (const float*)d_in[5];
  const float* b2 = (const float*)d_in[6];

  int E = in_sizes[1];
  int N = in_sizes[2] / D;
  const int* row = et;
  const int* col = et + E;

  int NB = (N + 127) >> 7;            // 782 buckets of 128 nodes
  int B1 = (E + EPB - 1) / EPB;       // 391 edge blocks (<= 512 for k_hscan)
  int B1pad = (B1 + 7) & ~7;

  char* p = (char*)d_ws;
  auto alloc = [&](size_t bytes) { char* q = p; p += (bytes + 255) & ~(size_t)255; return q; };
  int*      gh       = (int*)     alloc((size_t)NB * B1pad * 4);
  int*      binTotal = (int*)     alloc((size_t)NB * 4);
  int*      binBase  = (int*)     alloc((size_t)(NB + 1) * 4);
  ull*      a_e      = (ull*)     alloc((size_t)E * 8);   // packed; reused as rows/normp
  unsigned* elist    = (unsigned*)alloc((size_t)E * 4);   // r<<15|q15 (dest-sorted)
  int*      offs     = (int*)     alloc((size_t)(N + 1) * 4);
  float*    deg      = (float*)   alloc((size_t)N * 4);
  float*    dinv     = (float*)   alloc((size_t)N * 4);
  unsigned* xb       = (unsigned*)alloc((size_t)N * 64 * 4);   // f16x2 [N,64], live till end (skip)
  unsigned* s2b      = (unsigned*)alloc((size_t)N * 64 * 4);   // s2 f16x2
  ushort_t* wf1 = (ushort_t*)alloc(D * D * 2);
  ushort_t* wf2 = (ushort_t*)alloc(D * D * 2);
  unsigned* rows  = (unsigned*)a_e;       // a_e dead after k_bucket
  unsigned* normp = rows + E;
  unsigned* doutb = (unsigned*)d_out;     // s1 / a1 (f16) live in d_out, dead before final write

  int prepBlocks = (N * 64 + 2 * D * D + 255) / 256;
  k_h1<<<B1 + prepBlocks, 256, 0, stream>>>(col, E, B1, B1pad, gh, NB,
                                            (const float2*)x, xb, N * 64,
                                            W1, W2, wf1, wf2);
  k_hscan<<<NB, 512, 0, stream>>>(gh, binTotal, B1, B1pad);
  k_hscan2<<<1, SCAN_T, 0, stream>>>(binTotal, binBase, NB);
  k_scatter<<<B1, 256, 0, stream>>>(row, col, ef, gh, binBase, B1pad, NB, a_e, E);
  k_bucket<<<NB, 256, 0, stream>>>(a_e, binBase, offs, deg, elist, N);
  k_dinv<<<(N + 255) / 256, 256, 0, stream>>>(deg, dinv, offs, N, E);
  k_norm<<<(N + 255) / 256, 256, 0, stream>>>(elist, offs, dinv, rows, normp, N);

  int ab = (N + 15) / 16;
  int gb = 1024;
  // layer 1: s1 = A~ @ xb -> d_out(f16) ; a1 = tanh(s1@W1^T + b1) in-place
  k_agg<<<ab, 256, 0, stream>>>((const uint4*)xb, rows, normp, offs, dinv, (uint4*)doutb, N);
  k_mgemm<1, 0><<<gb, 256, 0, stream>>>((const ushort_t*)doutb, wf1, b1, nullptr, doutb, N);
  // layer 2: s2 = A~ @ a1 -> s2b ; out = s2@W2^T + b2 + xb(skip) -> d_out f32
  k_agg<<<ab, 256, 0, stream>>>((const uint4*)doutb, rows, normp, offs, dinv, (uint4*)s2b, N);
  k_mgemm<0, 1><<<gb, 256, 0, stream>>>((const ushort_t*)s2b, wf2, b2,
                                        (const ushort_t*)xb, d_out, N);
}

// Round 15
// 256.661 us; speedup vs baseline: 2.3964x; 1.0053x over previous
//
#include <hip/hip_runtime.h>
#include <math.h>

#define D 128
#define SCAN_T 256
#define EPB 4096          // edges per block for hist/scatter
#define MAXNB 800         // LDS histogram capacity (NB = ceil(N/128) = 782)

typedef unsigned long long ull;
typedef unsigned short ushort_t;
typedef __attribute__((ext_vector_type(8))) short bf16x8;
typedef __attribute__((ext_vector_type(4))) float f32x4;

__device__ __forceinline__ float bf_lo(unsigned u) { return __uint_as_float(u << 16); }
__device__ __forceinline__ float bf_hi(unsigned u) { return __uint_as_float(u & 0xffff0000u); }
__device__ __forceinline__ unsigned bpack(float a, float b) {  // RNE bf16x2
  unsigned ua = __float_as_uint(a), ub = __float_as_uint(b);
  ua += 0x7fff + ((ua >> 16) & 1);
  ub += 0x7fff + ((ub >> 16) & 1);
  return (ua >> 16) | (ub & 0xffff0000u);
}
__device__ __forceinline__ ushort_t bh16(float a) {  // RNE bf16
  unsigned ua = __float_as_uint(a);
  ua += 0x7fff + ((ua >> 16) & 1);
  return (ushort_t)(ua >> 16);
}

// ---- hist level-1 (col>>7) with LDS atomics; prep (x cast + W bf16 hi/lo split) in tail blocks ----
__global__ __launch_bounds__(256) void k_h1(const int* __restrict__ col, int E, int B1, int B1pad,
                                            int* __restrict__ gh, int NB,
                                            const float2* __restrict__ x2, unsigned* __restrict__ xb, int n64,
                                            const float* __restrict__ W1, const float* __restrict__ W2,
                                            ushort_t* __restrict__ Whi1, ushort_t* __restrict__ Wlo1,
                                            ushort_t* __restrict__ Whi2, ushort_t* __restrict__ Wlo2) {
  int b = blockIdx.x, t = threadIdx.x;
  if (b < B1) {
    __shared__ int h[MAXNB];
    for (int i = t; i < NB; i += 256) h[i] = 0;
    __syncthreads();
    int e0 = b * EPB, e1 = min(E, e0 + EPB);
    for (int e = e0 + t; e < e1; e += 256) atomicAdd(&h[col[e] >> 7], 1);
    __syncthreads();
    for (int i = t; i < NB; i += 256) gh[i * B1pad + b] = h[i];
    return;
  }
  int idx = (b - B1) * 256 + t;
  if (idx < n64) { float2 v = x2[idx]; xb[idx] = bpack(v.x, v.y); return; }
  int j = idx - n64;
  if (j >= 2 * D * D) return;
  const float* W = (j < D * D) ? W1 : W2;
  ushort_t* Hh = (j < D * D) ? Whi1 : Whi2;
  ushort_t* Hl = (j < D * D) ? Wlo1 : Wlo2;
  int k = j & (D * D - 1);
  float w = W[k];
  ushort_t hh = bh16(w);
  Hh[k] = hh;
  Hl[k] = bh16(w - __uint_as_float((unsigned)hh << 16));
}

// ---- per-bin scan across blocks: gh[bin][b] -> exclusive prefix; binTotal[bin] = sum ----
__global__ __launch_bounds__(512) void k_hscan(int* __restrict__ gh, int* __restrict__ binTotal,
                                               int B1, int B1pad) {
  __shared__ int wsum[8];
  int bin = blockIdx.x, t = threadIdx.x;
  int v = (t < B1) ? gh[bin * B1pad + t] : 0;
  int lane = t & 63, wid = t >> 6;
  int x = v;
  #pragma unroll
  for (int d = 1; d < 64; d <<= 1) { int y = __shfl_up(x, d, 64); if (lane >= d) x += y; }
  if (lane == 63) wsum[wid] = x;
  __syncthreads();
  int woff = 0;
  for (int w = 0; w < wid; ++w) woff += wsum[w];
  if (t < B1) gh[bin * B1pad + t] = woff + x - v;
  if (t == 511) binTotal[bin] = woff + x;   // last lane of last wave: inclusive total
}

// ---------------- block exclusive scan helper (256 threads) ----------------
__device__ __forceinline__ int block_excl_scan(int v, int t, int* wsum, int* total) {
  int lane = t & 63, wid = t >> 6;
  int x = v;
  #pragma unroll
  for (int d = 1; d < 64; d <<= 1) {
    int y = __shfl_up(x, d, 64);
    if (lane >= d) x += y;
  }
  if (lane == 63) wsum[wid] = x;
  __syncthreads();
  int woff = 0;
  for (int w = 0; w < wid; ++w) woff += wsum[w];
  if (total) { int tot = 0; for (int w = 0; w < 4; ++w) tot += wsum[w]; *total = tot; }
  return woff + x - v;
}

// ---- scan binTotal -> binBase (+ sentinels) ----
__global__ __launch_bounds__(SCAN_T) void k_hscan2(const int* __restrict__ binTotal,
                                                   int* __restrict__ binBase,
                                                   int* __restrict__ offs, int NB, int N) {
  __shared__ int wsum[4];
  int t = threadIdx.x;
  int base = t * 4;
  int v[4]; int s = 0;
  #pragma unroll
  for (int u = 0; u < 4; ++u) { v[u] = (base + u < NB) ? binTotal[base + u] : 0; s += v[u]; }
  int tot;
  int excl = block_excl_scan(s, t, wsum, &tot);
  int run = excl;
  #pragma unroll
  for (int u = 0; u < 4; ++u) { if (base + u < NB) binBase[base + u] = run; run += v[u]; }
  if (t == 0) { binBase[NB] = tot; offs[N] = tot; }
}

// ---- scatter: LDS counting-sort per block, coalesced packed-ull output ----
__global__ __launch_bounds__(256) void k_scatter(const int* __restrict__ row, const int* __restrict__ col,
                                                 const float* __restrict__ ew,
                                                 const int* __restrict__ gh, const int* __restrict__ binBase,
                                                 int B1pad, int NB,
                                                 ull* __restrict__ a_e, int E) {
  __shared__ ull recs[EPB];
  __shared__ int hist[MAXNB];   // becomes exclusive pfx in place
  __shared__ int cur[MAXNB];
  __shared__ int wb[MAXNB];
  __shared__ int wsum[4];
  int b = blockIdx.x, t = threadIdx.x;
  for (int i = t; i < NB; i += 256) { hist[i] = 0; cur[i] = 0; }
  __syncthreads();
  int e0 = b * EPB;
  int cnt = min(E - e0, EPB);
  ull v[16];
  #pragma unroll
  for (int k = 0; k < 16; ++k) {
    int idx = t + k * 256;
    v[k] = 0;
    if (idx < cnt) {
      int e = e0 + idx;
      int c = col[e];
      unsigned q = __float2uint_rn(ew[e] * 32767.0f);
      if (q > 32767u) q = 32767u;
      unsigned hi = ((unsigned)c << 15) | q;
      v[k] = ((ull)hi << 32) | (unsigned)row[e];
      atomicAdd(&hist[hi >> 22], 1);
    }
  }
  __syncthreads();
  int base = t * 4;
  int hv[4];
  #pragma unroll
  for (int u = 0; u < 4; ++u) hv[u] = (base + u < NB) ? hist[base + u] : 0;
  int s = hv[0] + hv[1] + hv[2] + hv[3];
  int excl = block_excl_scan(s, t, wsum, nullptr);
  int run = excl;
  #pragma unroll
  for (int u = 0; u < 4; ++u) {
    if (base + u < NB) {
      hist[base + u] = run;
      wb[base + u] = binBase[base + u] + gh[(base + u) * B1pad + b] - run;
    }
    run += hv[u];
  }
  __syncthreads();
  #pragma unroll
  for (int k = 0; k < 16; ++k) {
    if (t + k * 256 < cnt) {
      unsigned bkt = (unsigned)(v[k] >> 54);
      int idx = hist[bkt] + atomicAdd(&cur[bkt], 1);
      recs[idx] = v[k];
    }
  }
  __syncthreads();
  for (int i = t; i < cnt; i += 256) {
    ull r = recs[i];
    a_e[wb[(unsigned)(r >> 54)] + i] = r;
  }
}

// ---- level-2: per-bucket 128-bin counting sort; emits offs, dinv, dest-sorted (r|ew) ----
__global__ __launch_bounds__(256) void k_bucket(const ull* __restrict__ a_e,
                                                const int* __restrict__ binBase,
                                                int* __restrict__ offs, float* __restrict__ dinv,
                                                unsigned* __restrict__ sorted2, int N) {
  __shared__ int hist[128];
  __shared__ float wdeg[128];
  __shared__ int pfx[128];
  __shared__ int cur[128];
  int bin = blockIdx.x, t = threadIdx.x;
  if (t < 128) { hist[t] = 0; wdeg[t] = 0.f; cur[t] = 0; }
  __syncthreads();
  int s0 = binBase[bin], s1 = binBase[bin + 1];
  for (int i = s0 + t; i < s1; i += 256) {
    unsigned hi = (unsigned)(a_e[i] >> 32);
    int lc = (hi >> 15) & 127;
    atomicAdd(&hist[lc], 1);
    atomicAdd(&wdeg[lc], (float)(hi & 32767u) * (1.0f / 32767.0f));
  }
  __syncthreads();
  if (t == 0) { int run = 0; for (int i = 0; i < 128; ++i) { pfx[i] = run; run += hist[i]; } }
  __syncthreads();
  int c0 = bin << 7;
  if (t < 128 && c0 + t < N) {
    offs[c0 + t] = s0 + pfx[t];
    dinv[c0 + t] = rsqrtf(wdeg[t] + 1.0f);
  }
  for (int i = s0 + t; i < s1; i += 256) {
    ull v = a_e[i];
    unsigned hi = (unsigned)(v >> 32);
    int lc = (hi >> 15) & 127;
    int pos = s0 + pfx[lc] + atomicAdd(&cur[lc], 1);
    sorted2[pos] = ((unsigned)v << 15) | (hi & 32767u);   // r<<15 | ew_q15
  }
}

// ---- rewrite ew -> norm = dinv[r]*ew*dinv[c] in place (q15) ----
__global__ void k_norm(unsigned* __restrict__ el, const int* __restrict__ offs,
                       const float* __restrict__ dinv, int N) {
  int c = blockIdx.x * blockDim.x + threadIdx.x;
  if (c >= N) return;
  int s0 = offs[c], s1 = offs[c + 1];
  float dc = dinv[c] * (1.0f / 32767.0f);
  for (int i = s0; i < s1; ++i) {
    unsigned v = el[i];
    unsigned r = v >> 15;
    float nrm = dinv[r] * (float)(v & 32767u) * dc;
    unsigned q = __float2uint_rn(nrm * 32767.0f);
    if (q > 32767u) q = 32767u;
    el[i] = (r << 15) | q;
  }
}

// ---- gather-aggregate (R8-proven): wave per node, 4 edge slots x 16 lanes, 4-deep unroll ----
__global__ __launch_bounds__(256) void k_agg(const unsigned* __restrict__ H2,
                                             const unsigned* __restrict__ elist,
                                             const int* __restrict__ offs, const float* __restrict__ dinv,
                                             unsigned* __restrict__ outb, int N) {
  int lane = threadIdx.x & 63;
  int c = blockIdx.x * 4 + (threadIdx.x >> 6);
  if (c >= N) return;
  int start = offs[c];
  int m = offs[c + 1] - start;
  int q = lane >> 4;            // edge slot 0..3
  int fi = lane & 15;           // uint4 index within row (features fi*8..fi*8+7)
  float a0 = 0.f, a1 = 0.f, a2 = 0.f, a3 = 0.f, a4 = 0.f, a5 = 0.f, a6 = 0.f, a7 = 0.f;
  for (int base = 0; base < m; base += 64) {
    int chunk = min(64, m - base);
    unsigned rec = (lane < chunk) ? elist[start + base + lane] : 0u;  // pad: row0, w=0
    int iters = (chunk + 3) >> 2;
    int i = 0;
    for (; i + 4 <= iters; i += 4) {
      unsigned e0 = __shfl(rec, 4 * i + q, 64);
      unsigned e1 = __shfl(rec, 4 * i + 4 + q, 64);
      unsigned e2 = __shfl(rec, 4 * i + 8 + q, 64);
      unsigned e3 = __shfl(rec, 4 * i + 12 + q, 64);
      uint4 u0 = *(const uint4*)&H2[(size_t)(e0 >> 15) * 64 + fi * 4];
      uint4 u1 = *(const uint4*)&H2[(size_t)(e1 >> 15) * 64 + fi * 4];
      uint4 u2 = *(const uint4*)&H2[(size_t)(e2 >> 15) * 64 + fi * 4];
      uint4 u3 = *(const uint4*)&H2[(size_t)(e3 >> 15) * 64 + fi * 4];
      float w0 = (float)(e0 & 0x7fffu) * (1.0f / 32767.0f);
      float w1 = (float)(e1 & 0x7fffu) * (1.0f / 32767.0f);
      float w2 = (float)(e2 & 0x7fffu) * (1.0f / 32767.0f);
      float w3 = (float)(e3 & 0x7fffu) * (1.0f / 32767.0f);
      a0 += w0 * bf_lo(u0.x); a1 += w0 * bf_hi(u0.x);
      a2 += w0 * bf_lo(u0.y); a3 += w0 * bf_hi(u0.y);
      a4 += w0 * bf_lo(u0.z); a5 += w0 * bf_hi(u0.z);
      a6 += w0 * bf_lo(u0.w); a7 += w0 * bf_hi(u0.w);
      a0 += w1 * bf_lo(u1.x); a1 += w1 * bf_hi(u1.x);
      a2 += w1 * bf_lo(u1.y); a3 += w1 * bf_hi(u1.y);
      a4 += w1 * bf_lo(u1.z); a5 += w1 * bf_hi(u1.z);
      a6 += w1 * bf_lo(u1.w); a7 += w1 * bf_hi(u1.w);
      a0 += w2 * bf_lo(u2.x); a1 += w2 * bf_hi(u2.x);
      a2 += w2 * bf_lo(u2.y); a3 += w2 * bf_hi(u2.y);
      a4 += w2 * bf_lo(u2.z); a5 += w2 * bf_hi(u2.z);
      a6 += w2 * bf_lo(u2.w); a7 += w2 * bf_hi(u2.w);
      a0 += w3 * bf_lo(u3.x); a1 += w3 * bf_hi(u3.x);
      a2 += w3 * bf_lo(u3.y); a3 += w3 * bf_hi(u3.y);
      a4 += w3 * bf_lo(u3.z); a5 += w3 * bf_hi(u3.z);
      a6 += w3 * bf_lo(u3.w); a7 += w3 * bf_hi(u3.w);
    }
    for (; i < iters; ++i) {
      unsigned e0 = __shfl(rec, 4 * i + q, 64);
      float w0 = (float)(e0 & 0x7fffu) * (1.0f / 32767.0f);
      uint4 u0 = *(const uint4*)&H2[(size_t)(e0 >> 15) * 64 + fi * 4];
      a0 += w0 * bf_lo(u0.x); a1 += w0 * bf_hi(u0.x);
      a2 += w0 * bf_lo(u0.y); a3 += w0 * bf_hi(u0.y);
      a4 += w0 * bf_lo(u0.z); a5 += w0 * bf_hi(u0.z);
      a6 += w0 * bf_lo(u0.w); a7 += w0 * bf_hi(u0.w);
    }
  }
  a0 += __shfl_xor(a0, 16, 64); a0 += __shfl_xor(a0, 32, 64);
  a1 += __shfl_xor(a1, 16, 64); a1 += __shfl_xor(a1, 32, 64);
  a2 += __shfl_xor(a2, 16, 64); a2 += __shfl_xor(a2, 32, 64);
  a3 += __shfl_xor(a3, 16, 64); a3 += __shfl_xor(a3, 32, 64);
  a4 += __shfl_xor(a4, 16, 64); a4 += __shfl_xor(a4, 32, 64);
  a5 += __shfl_xor(a5, 16, 64); a5 += __shfl_xor(a5, 32, 64);
  a6 += __shfl_xor(a6, 16, 64); a6 += __shfl_xor(a6, 32, 64);
  a7 += __shfl_xor(a7, 16, 64); a7 += __shfl_xor(a7, 32, 64);
  if (q == 0) {
    float dv = dinv[c], sw = dv * dv;
    uint4 us = *(const uint4*)&H2[(size_t)c * 64 + fi * 4];
    a0 += sw * bf_lo(us.x); a1 += sw * bf_hi(us.x);
    a2 += sw * bf_lo(us.y); a3 += sw * bf_hi(us.y);
    a4 += sw * bf_lo(us.z); a5 += sw * bf_hi(us.z);
    a6 += sw * bf_lo(us.w); a7 += sw * bf_hi(us.w);
    uint4 o;
    o.x = bpack(a0, a1); o.y = bpack(a2, a3); o.z = bpack(a4, a5); o.w = bpack(a6, a7);
    *(uint4*)&outb[(size_t)c * 64 + fi * 4] = o;
  }
}

// ---- MFMA GEMM (bf16 hi+lo W): B in registers, rows streamed ----
// TANH: out bf16 (out-of-place: all waves read full rows, write 32-col slices).
// else: out f32 with bf16 skip.
template<int TANH, int SKIP>
__global__ __launch_bounds__(256) void k_mgemm(const ushort_t* __restrict__ S,
                                               const ushort_t* __restrict__ Whi,
                                               const ushort_t* __restrict__ Wlo,
                                               const float* __restrict__ bias,
                                               const ushort_t* __restrict__ skipb,
                                               void* __restrict__ outv, int n) {
  int wave = threadIdx.x >> 6, lane = threadIdx.x & 63;
  int cl = lane & 15;
  int kg = lane >> 4;
  int cb0 = wave * 2;

  bf16x8 bh[2][4], bl[2][4];
  float bv[2];
  #pragma unroll
  for (int c = 0; c < 2; ++c) {
    int col = (cb0 + c) * 16 + cl;
    const ushort_t* wh = Whi + (size_t)col * D + kg * 8;
    const ushort_t* wl = Wlo + (size_t)col * D + kg * 8;
    #pragma unroll
    for (int kt = 0; kt < 4; ++kt) {
      bh[c][kt] = *(const bf16x8*)(wh + kt * 32);
      bl[c][kt] = *(const bf16x8*)(wl + kt * 32);
    }
    bv[c] = bias[col];
  }

  int ntiles = (n + 15) >> 4;
  for (int t = blockIdx.x; t < ntiles; t += gridDim.x) {
    int arow = t * 16 + cl; if (arow >= n) arow = n - 1;
    const ushort_t* srow = S + (size_t)arow * D + kg * 8;
    bf16x8 a[4];
    #pragma unroll
    for (int kt = 0; kt < 4; ++kt) a[kt] = *(const bf16x8*)(srow + kt * 32);
    #pragma unroll
    for (int c = 0; c < 2; ++c) {
      f32x4 acc = {0.f, 0.f, 0.f, 0.f};
      #pragma unroll
      for (int kt = 0; kt < 4; ++kt)
        acc = __builtin_amdgcn_mfma_f32_16x16x32_bf16(a[kt], bh[c][kt], acc, 0, 0, 0);
      #pragma unroll
      for (int kt = 0; kt < 4; ++kt)
        acc = __builtin_amdgcn_mfma_f32_16x16x32_bf16(a[kt], bl[c][kt], acc, 0, 0, 0);
      int col = (cb0 + c) * 16 + cl;
      #pragma unroll
      for (int i = 0; i < 4; ++i) {
        int r = t * 16 + kg * 4 + i;
        if (r < n) {
          float o = acc[i] + bv[c];
          if (TANH) {
            o = tanhf(o);
            ((ushort_t*)outv)[(size_t)r * D + col] = bh16(o);
          } else {
            if (SKIP) o += __uint_as_float((unsigned)skipb[(size_t)r * D + col] << 16);
            ((float*)outv)[(size_t)r * D + col] = o;
          }
        }
      }
    }
  }
}

// ---------------- launch ----------------
extern "C" void kernel_launch(void* const* d_in, const int* in_sizes, int n_in,
                              void* d_out, int out_size, void* d_ws, size_t ws_size,
                              hipStream_t stream) {
  const int*   et = (const int*)d_in[0];
  const float* ef = (const float*)d_in[1];
  const float* x  = (const float*)d_in[2];
  const float* W1 = (const float*)d_in[3];
  const float* b1 = (const float*)d_in[4];
  const float* W2 = (const float*)d_in[5];
  const float* b2 = (const float*)d_in[6];

  int E = in_sizes[1];
  int N = in_sizes[2] / D;
  const int* row = et;
  const int* col = et + E;

  int NB = (N + 127) >> 7;            // 782 buckets of 128 nodes
  int B1 = (E + EPB - 1) / EPB;       // 391 edge blocks (<= 512 for k_hscan)
  int B1pad = (B1 + 7) & ~7;

  char* p = (char*)d_ws;
  auto alloc = [&](size_t bytes) { char* q = p; p += (bytes + 255) & ~(size_t)255; return q; };
  int*      gh       = (int*)     alloc((size_t)NB * B1pad * 4);
  int*      binTotal = (int*)     alloc((size_t)NB * 4);
  int*      binBase  = (int*)     alloc((size_t)(NB + 1) * 4);
  ull*      a_e      = (ull*)     alloc((size_t)E * 8);   // packed (c<<15|q, r)
  unsigned* elist    = (unsigned*)alloc((size_t)E * 4);   // r<<15|q15, dest-sorted; q15 -> norm
  int*      offs     = (int*)     alloc((size_t)(N + 1) * 4);
  float*    dinv     = (float*)   alloc((size_t)N * 4);
  unsigned* xb       = (unsigned*)alloc((size_t)N * 64 * 4);   // bf16x2 [N,64], live till end (skip)
  unsigned* s2b      = (unsigned*)alloc((size_t)N * 64 * 4);   // s2 bf16x2
  ushort_t* whi1 = (ushort_t*)alloc(D * D * 2);
  ushort_t* wlo1 = (ushort_t*)alloc(D * D * 2);
  ushort_t* whi2 = (ushort_t*)alloc(D * D * 2);
  ushort_t* wlo2 = (ushort_t*)alloc(D * D * 2);
  // d_out (f32 [N,128]) double-buffers layer-1 activations:
  //   lower half: s1 (agg1 out) ; upper half: a1 (mgemm1 out) -- mgemm1 OUT-OF-PLACE (race-free)
  unsigned* s1b = (unsigned*)d_out;
  unsigned* a1b = s1b + (size_t)N * 64;

  int prepBlocks = (N * 64 + 2 * D * D + 255) / 256;
  k_h1<<<B1 + prepBlocks, 256, 0, stream>>>(col, E, B1, B1pad, gh, NB,
                                            (const float2*)x, xb, N * 64,
                                            W1, W2, whi1, wlo1, whi2, wlo2);
  k_hscan<<<NB, 512, 0, stream>>>(gh, binTotal, B1, B1pad);
  k_hscan2<<<1, SCAN_T, 0, stream>>>(binTotal, binBase, offs, NB, N);
  k_scatter<<<B1, 256, 0, stream>>>(row, col, ef, gh, binBase, B1pad, NB, a_e, E);
  k_bucket<<<NB, 256, 0, stream>>>(a_e, binBase, offs, dinv, elist, N);
  k_norm<<<(N + 255) / 256, 256, 0, stream>>>(elist, offs, dinv, N);

  int ab = (N + 3) / 4;
  int gb = 1024;
  // layer 1: s1 = A~ @ xb -> s1b (d_out lower) ; a1 = tanh(s1@W1^T + b1) -> a1b (d_out upper)
  k_agg<<<ab, 256, 0, stream>>>(xb, elist, offs, dinv, s1b, N);
  k_mgemm<1, 0><<<gb, 256, 0, stream>>>((const ushort_t*)s1b, whi1, wlo1, b1, nullptr, a1b, N);
  // layer 2: s2 = A~ @ a1 -> s2b ; out = s2@W2^T + b2 + xb(bf16 skip) -> d_out f32
  k_agg<<<ab, 256, 0, stream>>>(a1b, elist, offs, dinv, s2b, N);
  k_mgemm<0, 1><<<gb, 256, 0, stream>>>((const ushort_t*)s2b, whi2, wlo2, b2,
                                        (const ushort_t*)xb, d_out, N);
}

// Round 16
// 239.975 us; speedup vs baseline: 2.5630x; 1.0695x over previous
//
#include <hip/hip_runtime.h>
#include <math.h>

#define D 128
#define EPB 4096          // edges per block for hist/scatter
#define MAXNB 800         // LDS histogram capacity (NB = ceil(N/128) = 782)

typedef unsigned long long ull;
typedef unsigned short ushort_t;
typedef __attribute__((ext_vector_type(8))) short bf16x8;
typedef __attribute__((ext_vector_type(4))) float f32x4;

__device__ __forceinline__ float bf_lo(unsigned u) { return __uint_as_float(u << 16); }
__device__ __forceinline__ float bf_hi(unsigned u) { return __uint_as_float(u & 0xffff0000u); }
__device__ __forceinline__ unsigned bpack(float a, float b) {  // RNE bf16x2
  unsigned ua = __float_as_uint(a), ub = __float_as_uint(b);
  ua += 0x7fff + ((ua >> 16) & 1);
  ub += 0x7fff + ((ub >> 16) & 1);
  return (ua >> 16) | (ub & 0xffff0000u);
}
__device__ __forceinline__ ushort_t bh16(float a) {  // RNE bf16
  unsigned ua = __float_as_uint(a);
  ua += 0x7fff + ((ua >> 16) & 1);
  return (ushort_t)(ua >> 16);
}

// ---- hist level-1 (col>>7) with LDS atomics; prep (x cast + W bf16 hi/lo split) in tail blocks ----
__global__ __launch_bounds__(256) void k_h1(const int* __restrict__ col, int E, int B1, int B1pad,
                                            int* __restrict__ gh, int NB,
                                            const float2* __restrict__ x2, unsigned* __restrict__ xb, int n64,
                                            const float* __restrict__ W1, const float* __restrict__ W2,
                                            ushort_t* __restrict__ Whi1, ushort_t* __restrict__ Wlo1,
                                            ushort_t* __restrict__ Whi2, ushort_t* __restrict__ Wlo2) {
  int b = blockIdx.x, t = threadIdx.x;
  if (b < B1) {
    __shared__ int h[MAXNB];
    for (int i = t; i < NB; i += 256) h[i] = 0;
    __syncthreads();
    int e0 = b * EPB, e1 = min(E, e0 + EPB);
    for (int e = e0 + t; e < e1; e += 256) atomicAdd(&h[col[e] >> 7], 1);
    __syncthreads();
    for (int i = t; i < NB; i += 256) gh[i * B1pad + b] = h[i];
    return;
  }
  int idx = (b - B1) * 256 + t;
  if (idx < n64) { float2 v = x2[idx]; xb[idx] = bpack(v.x, v.y); return; }
  int j = idx - n64;
  if (j >= 2 * D * D) return;
  const float* W = (j < D * D) ? W1 : W2;
  ushort_t* Hh = (j < D * D) ? Whi1 : Whi2;
  ushort_t* Hl = (j < D * D) ? Wlo1 : Wlo2;
  int k = j & (D * D - 1);
  float w = W[k];
  ushort_t hh = bh16(w);
  Hh[k] = hh;
  Hl[k] = bh16(w - __uint_as_float((unsigned)hh << 16));
}

// ---- per-bin scan across blocks: gh[bin][b] -> exclusive prefix; binTotal[bin] = sum ----
__global__ __launch_bounds__(512) void k_hscan(int* __restrict__ gh, int* __restrict__ binTotal,
                                               int B1, int B1pad) {
  __shared__ int wsum[8];
  int bin = blockIdx.x, t = threadIdx.x;
  int v = (t < B1) ? gh[bin * B1pad + t] : 0;
  int lane = t & 63, wid = t >> 6;
  int x = v;
  #pragma unroll
  for (int d = 1; d < 64; d <<= 1) { int y = __shfl_up(x, d, 64); if (lane >= d) x += y; }
  if (lane == 63) wsum[wid] = x;
  __syncthreads();
  int woff = 0;
  for (int w = 0; w < wid; ++w) woff += wsum[w];
  if (t < B1) gh[bin * B1pad + t] = woff + x - v;
  if (t == 511) binTotal[bin] = woff + x;   // last lane of last wave: inclusive total
}

// ---------------- block exclusive scan helper (256 threads) ----------------
__device__ __forceinline__ int block_excl_scan(int v, int t, int* wsum, int* total) {
  int lane = t & 63, wid = t >> 6;
  int x = v;
  #pragma unroll
  for (int d = 1; d < 64; d <<= 1) {
    int y = __shfl_up(x, d, 64);
    if (lane >= d) x += y;
  }
  if (lane == 63) wsum[wid] = x;
  __syncthreads();
  int woff = 0;
  for (int w = 0; w < wid; ++w) woff += wsum[w];
  if (total) { int tot = 0; for (int w = 0; w < 4; ++w) tot += wsum[w]; *total = tot; }
  return woff + x - v;
}

// ---- scatter: LDS counting-sort per block, coalesced packed-ull output ----
// binBase computed in-block from binTotal (k_hscan2 eliminated).
__global__ __launch_bounds__(256) void k_scatter(const int* __restrict__ row, const int* __restrict__ col,
                                                 const float* __restrict__ ew,
                                                 const int* __restrict__ gh, const int* __restrict__ binTotal,
                                                 int B1pad, int NB,
                                                 ull* __restrict__ a_e, int E) {
  __shared__ ull recs[EPB];
  __shared__ int hist[MAXNB];   // becomes exclusive pfx in place
  __shared__ int cur[MAXNB];
  __shared__ int wb[MAXNB];
  __shared__ int bbase[MAXNB];
  __shared__ int wsum[4];
  int b = blockIdx.x, t = threadIdx.x;
  for (int i = t; i < NB; i += 256) { hist[i] = 0; cur[i] = 0; }
  __syncthreads();
  int e0 = b * EPB;
  int cnt = min(E - e0, EPB);
  ull v[16];
  #pragma unroll
  for (int k = 0; k < 16; ++k) {
    int idx = t + k * 256;
    v[k] = 0;
    if (idx < cnt) {
      int e = e0 + idx;
      int c = col[e];
      unsigned q = __float2uint_rn(ew[e] * 32767.0f);
      if (q > 32767u) q = 32767u;
      unsigned hi = ((unsigned)c << 15) | q;
      v[k] = ((ull)hi << 32) | (unsigned)row[e];
      atomicAdd(&hist[hi >> 22], 1);
    }
  }
  __syncthreads();
  int base = t * 4;
  // scan #A: binTotal -> bbase (exclusive bin bases)
  int bt[4]; int sb = 0;
  #pragma unroll
  for (int u = 0; u < 4; ++u) { bt[u] = (base + u < NB) ? binTotal[base + u] : 0; sb += bt[u]; }
  int exb = block_excl_scan(sb, t, wsum, nullptr);
  {
    int run = exb;
    #pragma unroll
    for (int u = 0; u < 4; ++u) { if (base + u < NB) bbase[base + u] = run; run += bt[u]; }
  }
  __syncthreads();
  // scan #B: hist -> exclusive pfx in place; wb = bbase + gh - pfx
  int hv[4];
  #pragma unroll
  for (int u = 0; u < 4; ++u) hv[u] = (base + u < NB) ? hist[base + u] : 0;
  int s = hv[0] + hv[1] + hv[2] + hv[3];
  int excl = block_excl_scan(s, t, wsum, nullptr);
  int run = excl;
  #pragma unroll
  for (int u = 0; u < 4; ++u) {
    if (base + u < NB) {
      hist[base + u] = run;
      wb[base + u] = bbase[base + u] + gh[(base + u) * B1pad + b] - run;
    }
    run += hv[u];
  }
  __syncthreads();
  #pragma unroll
  for (int k = 0; k < 16; ++k) {
    if (t + k * 256 < cnt) {
      unsigned bkt = (unsigned)(v[k] >> 54);
      int idx = hist[bkt] + atomicAdd(&cur[bkt], 1);
      recs[idx] = v[k];
    }
  }
  __syncthreads();
  for (int i = t; i < cnt; i += 256) {
    ull r = recs[i];
    a_e[wb[(unsigned)(r >> 54)] + i] = r;
  }
}

// ---- level-2: per-bucket 128-bin counting sort; emits offs, dinv, dest-sorted (r<<15|ew_q15) ----
// bin base computed in-block from binTotal; bin 0 writes offs[N]=E sentinel.
__global__ __launch_bounds__(256) void k_bucket(const ull* __restrict__ a_e,
                                                const int* __restrict__ binTotal,
                                                int* __restrict__ offs, float* __restrict__ dinv,
                                                unsigned* __restrict__ sorted2, int N, int E, int NB) {
  __shared__ int hist[128];
  __shared__ float wdeg[128];
  __shared__ int pfx[128];
  __shared__ int cur[128];
  __shared__ int wred[4];
  __shared__ int s0sh;
  int bin = blockIdx.x, t = threadIdx.x;
  if (t < 128) { hist[t] = 0; wdeg[t] = 0.f; cur[t] = 0; }
  // masked block-reduce: s0 = sum_{j<bin} binTotal[j]
  int part = 0;
  for (int j = t; j < NB; j += 256) if (j < bin) part += binTotal[j];
  #pragma unroll
  for (int d = 32; d >= 1; d >>= 1) part += __shfl_xor(part, d, 64);
  if ((t & 63) == 0) wred[t >> 6] = part;
  __syncthreads();
  if (t == 0) s0sh = wred[0] + wred[1] + wred[2] + wred[3];
  if (t == 0 && bin == 0) offs[N] = E;
  __syncthreads();
  int s0 = s0sh;
  int s1 = s0 + binTotal[bin];
  for (int i = s0 + t; i < s1; i += 256) {
    unsigned hi = (unsigned)(a_e[i] >> 32);
    int lc = (hi >> 15) & 127;
    atomicAdd(&hist[lc], 1);
    atomicAdd(&wdeg[lc], (float)(hi & 32767u) * (1.0f / 32767.0f));
  }
  __syncthreads();
  if (t == 0) { int run = 0; for (int i = 0; i < 128; ++i) { pfx[i] = run; run += hist[i]; } }
  __syncthreads();
  int c0 = bin << 7;
  if (t < 128 && c0 + t < N) {
    offs[c0 + t] = s0 + pfx[t];
    dinv[c0 + t] = rsqrtf(wdeg[t] + 1.0f);
  }
  for (int i = s0 + t; i < s1; i += 256) {
    ull v = a_e[i];
    unsigned hi = (unsigned)(v >> 32);
    int lc = (hi >> 15) & 127;
    int pos = s0 + pfx[lc] + atomicAdd(&cur[lc], 1);
    sorted2[pos] = ((unsigned)v << 15) | (hi & 32767u);   // r<<15 | ew_q15
  }
}

// ---- gather-aggregate (R8-proven structure): wave per node, 4 edge slots x 16 lanes, 4-deep ----
// norm decoded on the fly: w = ew_q15 * dinv[r] * (dinv[c]/32767)  (k_norm eliminated)
__global__ __launch_bounds__(256) void k_agg(const unsigned* __restrict__ H2,
                                             const unsigned* __restrict__ elist,
                                             const int* __restrict__ offs, const float* __restrict__ dinv,
                                             unsigned* __restrict__ outb, int N) {
  int lane = threadIdx.x & 63;
  int c = blockIdx.x * 4 + (threadIdx.x >> 6);
  if (c >= N) return;
  int start = offs[c];
  int m = offs[c + 1] - start;
  int q = lane >> 4;            // edge slot 0..3
  int fi = lane & 15;           // uint4 index within row (features fi*8..fi*8+7)
  float dv = dinv[c];
  float dcs = dv * (1.0f / 32767.0f);
  float a0 = 0.f, a1 = 0.f, a2 = 0.f, a3 = 0.f, a4 = 0.f, a5 = 0.f, a6 = 0.f, a7 = 0.f;
  for (int base = 0; base < m; base += 64) {
    int chunk = min(64, m - base);
    unsigned rec = (lane < chunk) ? elist[start + base + lane] : 0u;  // pad: row0, w=0
    int iters = (chunk + 3) >> 2;
    int i = 0;
    for (; i + 4 <= iters; i += 4) {
      unsigned e0 = __shfl(rec, 4 * i + q, 64);
      unsigned e1 = __shfl(rec, 4 * i + 4 + q, 64);
      unsigned e2 = __shfl(rec, 4 * i + 8 + q, 64);
      unsigned e3 = __shfl(rec, 4 * i + 12 + q, 64);
      uint4 u0 = *(const uint4*)&H2[(size_t)(e0 >> 15) * 64 + fi * 4];
      uint4 u1 = *(const uint4*)&H2[(size_t)(e1 >> 15) * 64 + fi * 4];
      uint4 u2 = *(const uint4*)&H2[(size_t)(e2 >> 15) * 64 + fi * 4];
      uint4 u3 = *(const uint4*)&H2[(size_t)(e3 >> 15) * 64 + fi * 4];
      float w0 = (float)(e0 & 0x7fffu) * dinv[e0 >> 15] * dcs;
      float w1 = (float)(e1 & 0x7fffu) * dinv[e1 >> 15] * dcs;
      float w2 = (float)(e2 & 0x7fffu) * dinv[e2 >> 15] * dcs;
      float w3 = (float)(e3 & 0x7fffu) * dinv[e3 >> 15] * dcs;
      a0 += w0 * bf_lo(u0.x); a1 += w0 * bf_hi(u0.x);
      a2 += w0 * bf_lo(u0.y); a3 += w0 * bf_hi(u0.y);
      a4 += w0 * bf_lo(u0.z); a5 += w0 * bf_hi(u0.z);
      a6 += w0 * bf_lo(u0.w); a7 += w0 * bf_hi(u0.w);
      a0 += w1 * bf_lo(u1.x); a1 += w1 * bf_hi(u1.x);
      a2 += w1 * bf_lo(u1.y); a3 += w1 * bf_hi(u1.y);
      a4 += w1 * bf_lo(u1.z); a5 += w1 * bf_hi(u1.z);
      a6 += w1 * bf_lo(u1.w); a7 += w1 * bf_hi(u1.w);
      a0 += w2 * bf_lo(u2.x); a1 += w2 * bf_hi(u2.x);
      a2 += w2 * bf_lo(u2.y); a3 += w2 * bf_hi(u2.y);
      a4 += w2 * bf_lo(u2.z); a5 += w2 * bf_hi(u2.z);
      a6 += w2 * bf_lo(u2.w); a7 += w2 * bf_hi(u2.w);
      a0 += w3 * bf_lo(u3.x); a1 += w3 * bf_hi(u3.x);
      a2 += w3 * bf_lo(u3.y); a3 += w3 * bf_hi(u3.y);
      a4 += w3 * bf_lo(u3.z); a5 += w3 * bf_hi(u3.z);
      a6 += w3 * bf_lo(u3.w); a7 += w3 * bf_hi(u3.w);
    }
    for (; i < iters; ++i) {
      unsigned e0 = __shfl(rec, 4 * i + q, 64);
      float w0 = (float)(e0 & 0x7fffu) * dinv[e0 >> 15] * dcs;
      uint4 u0 = *(const uint4*)&H2[(size_t)(e0 >> 15) * 64 + fi * 4];
      a0 += w0 * bf_lo(u0.x); a1 += w0 * bf_hi(u0.x);
      a2 += w0 * bf_lo(u0.y); a3 += w0 * bf_hi(u0.y);
      a4 += w0 * bf_lo(u0.z); a5 += w0 * bf_hi(u0.z);
      a6 += w0 * bf_lo(u0.w); a7 += w0 * bf_hi(u0.w);
    }
  }
  a0 += __shfl_xor(a0, 16, 64); a0 += __shfl_xor(a0, 32, 64);
  a1 += __shfl_xor(a1, 16, 64); a1 += __shfl_xor(a1, 32, 64);
  a2 += __shfl_xor(a2, 16, 64); a2 += __shfl_xor(a2, 32, 64);
  a3 += __shfl_xor(a3, 16, 64); a3 += __shfl_xor(a3, 32, 64);
  a4 += __shfl_xor(a4, 16, 64); a4 += __shfl_xor(a4, 32, 64);
  a5 += __shfl_xor(a5, 16, 64); a5 += __shfl_xor(a5, 32, 64);
  a6 += __shfl_xor(a6, 16, 64); a6 += __shfl_xor(a6, 32, 64);
  a7 += __shfl_xor(a7, 16, 64); a7 += __shfl_xor(a7, 32, 64);
  if (q == 0) {
    float sw = dv * dv;
    uint4 us = *(const uint4*)&H2[(size_t)c * 64 + fi * 4];
    a0 += sw * bf_lo(us.x); a1 += sw * bf_hi(us.x);
    a2 += sw * bf_lo(us.y); a3 += sw * bf_hi(us.y);
    a4 += sw * bf_lo(us.z); a5 += sw * bf_hi(us.z);
    a6 += sw * bf_lo(us.w); a7 += sw * bf_hi(us.w);
    uint4 o;
    o.x = bpack(a0, a1); o.y = bpack(a2, a3); o.z = bpack(a4, a5); o.w = bpack(a6, a7);
    *(uint4*)&outb[(size_t)c * 64 + fi * 4] = o;
  }
}

// ---- MFMA GEMM (bf16 hi+lo W): B in registers, rows streamed ----
// TANH: out bf16 (out-of-place: all waves read full rows, write 32-col slices).
// else: out f32 with bf16 skip.
template<int TANH, int SKIP>
__global__ __launch_bounds__(256) void k_mgemm(const ushort_t* __restrict__ S,
                                               const ushort_t* __restrict__ Whi,
                                               const ushort_t* __restrict__ Wlo,
                                               const float* __restrict__ bias,
                                               const ushort_t* __restrict__ skipb,
                                               void* __restrict__ outv, int n) {
  int wave = threadIdx.x >> 6, lane = threadIdx.x & 63;
  int cl = lane & 15;
  int kg = lane >> 4;
  int cb0 = wave * 2;

  bf16x8 bh[2][4], bl[2][4];
  float bv[2];
  #pragma unroll
  for (int c = 0; c < 2; ++c) {
    int col = (cb0 + c) * 16 + cl;
    const ushort_t* wh = Whi + (size_t)col * D + kg * 8;
    const ushort_t* wl = Wlo + (size_t)col * D + kg * 8;
    #pragma unroll
    for (int kt = 0; kt < 4; ++kt) {
      bh[c][kt] = *(const bf16x8*)(wh + kt * 32);
      bl[c][kt] = *(const bf16x8*)(wl + kt * 32);
    }
    bv[c] = bias[col];
  }

  int ntiles = (n + 15) >> 4;
  for (int t = blockIdx.x; t < ntiles; t += gridDim.x) {
    int arow = t * 16 + cl; if (arow >= n) arow = n - 1;
    const ushort_t* srow = S + (size_t)arow * D + kg * 8;
    bf16x8 a[4];
    #pragma unroll
    for (int kt = 0; kt < 4; ++kt) a[kt] = *(const bf16x8*)(srow + kt * 32);
    #pragma unroll
    for (int c = 0; c < 2; ++c) {
      f32x4 acc = {0.f, 0.f, 0.f, 0.f};
      #pragma unroll
      for (int kt = 0; kt < 4; ++kt)
        acc = __builtin_amdgcn_mfma_f32_16x16x32_bf16(a[kt], bh[c][kt], acc, 0, 0, 0);
      #pragma unroll
      for (int kt = 0; kt < 4; ++kt)
        acc = __builtin_amdgcn_mfma_f32_16x16x32_bf16(a[kt], bl[c][kt], acc, 0, 0, 0);
      int col = (cb0 + c) * 16 + cl;
      #pragma unroll
      for (int i = 0; i < 4; ++i) {
        int r = t * 16 + kg * 4 + i;
        if (r < n) {
          float o = acc[i] + bv[c];
          if (TANH) {
            o = tanhf(o);
            ((ushort_t*)outv)[(size_t)r * D + col] = bh16(o);
          } else {
            if (SKIP) o += __uint_as_float((unsigned)skipb[(size_t)r * D + col] << 16);
            ((float*)outv)[(size_t)r * D + col] = o;
          }
        }
      }
    }
  }
}

// ---------------- launch ----------------
extern "C" void kernel_launch(void* const* d_in, const int* in_sizes, int n_in,
                              void* d_out, int out_size, void* d_ws, size_t ws_size,
                              hipStream_t stream) {
  const int*   et = (const int*)d_in[0];
  const float* ef = (const float*)d_in[1];
  const float* x  = (const float*)d_in[2];
  const float* W1 = (const float*)d_in[3];
  const float* b1 = (const float*)d_in[4];
  const float* W2 = (const float*)d_in[5];
  const float* b2 = (const float*)d_in[6];

  int E = in_sizes[1];
  int N = in_sizes[2] / D;
  const int* row = et;
  const int* col = et + E;

  int NB = (N + 127) >> 7;            // 782 buckets of 128 nodes
  int B1 = (E + EPB - 1) / EPB;       // 391 edge blocks (<= 512 for k_hscan)
  int B1pad = (B1 + 7) & ~7;

  char* p = (char*)d_ws;
  auto alloc = [&](size_t bytes) { char* q = p; p += (bytes + 255) & ~(size_t)255; return q; };
  int*      gh       = (int*)     alloc((size_t)NB * B1pad * 4);
  int*      binTotal = (int*)     alloc((size_t)NB * 4);
  ull*      a_e      = (ull*)     alloc((size_t)E * 8);   // packed (c<<15|q, r)
  unsigned* elist    = (unsigned*)alloc((size_t)E * 4);   // r<<15 | ew_q15, dest-sorted
  int*      offs     = (int*)     alloc((size_t)(N + 1) * 4);
  float*    dinv     = (float*)   alloc((size_t)N * 4);
  unsigned* xb       = (unsigned*)alloc((size_t)N * 64 * 4);   // bf16x2 [N,64], live till end (skip)
  unsigned* s2b      = (unsigned*)alloc((size_t)N * 64 * 4);   // s2 bf16x2
  ushort_t* whi1 = (ushort_t*)alloc(D * D * 2);
  ushort_t* wlo1 = (ushort_t*)alloc(D * D * 2);
  ushort_t* whi2 = (ushort_t*)alloc(D * D * 2);
  ushort_t* wlo2 = (ushort_t*)alloc(D * D * 2);
  // d_out (f32 [N,128]) double-buffers layer-1 activations:
  //   lower half: s1 (agg1 out) ; upper half: a1 (mgemm1 out) -- mgemm1 OUT-OF-PLACE (race-free)
  unsigned* s1b = (unsigned*)d_out;
  unsigned* a1b = s1b + (size_t)N * 64;

  int prepBlocks = (N * 64 + 2 * D * D + 255) / 256;
  k_h1<<<B1 + prepBlocks, 256, 0, stream>>>(col, E, B1, B1pad, gh, NB,
                                            (const float2*)x, xb, N * 64,
                                            W1, W2, whi1, wlo1, whi2, wlo2);
  k_hscan<<<NB, 512, 0, stream>>>(gh, binTotal, B1, B1pad);
  k_scatter<<<B1, 256, 0, stream>>>(row, col, ef, gh, binTotal, B1pad, NB, a_e, E);
  k_bucket<<<NB, 256, 0, stream>>>(a_e, binTotal, offs, dinv, elist, N, E, NB);

  int ab = (N + 3) / 4;
  int gb = 1024;
  // layer 1: s1 = A~ @ xb -> s1b (d_out lower) ; a1 = tanh(s1@W1^T + b1) -> a1b (d_out upper)
  k_agg<<<ab, 256, 0, stream>>>(xb, elist, offs, dinv, s1b, N);
  k_mgemm<1, 0><<<gb, 256, 0, stream>>>((const ushort_t*)s1b, whi1, wlo1, b1, nullptr, a1b, N);
  // layer 2: s2 = A~ @ a1 -> s2b ; out = s2@W2^T + b2 + xb(bf16 skip) -> d_out f32
  k_agg<<<ab, 256, 0, stream>>>(a1b, elist, offs, dinv, s2b, N);
  k_mgemm<0, 1><<<gb, 256, 0, stream>>>((const ushort_t*)s2b, whi2, wlo2, b2,
                                        (const ushort_t*)xb, d_out, N);
}